// Round 21
// baseline (451.509 us; speedup 1.0000x reference)
//
#include <hip/hip_runtime.h>
#include <math.h>

static constexpr int kN   = 50000;
static constexpr int kB   = 500;
static constexpr int kNPG = 100;
static constexpr int kEPG = 1600;
static constexpr int kESG = 800;
static constexpr int kF0  = 128;
static constexpr int kH1  = 256;
static constexpr int kH2  = 128;
#define BN_EPS 1e-5f

typedef _Float16 half8 __attribute__((ext_vector_type(8)));
typedef __attribute__((ext_vector_type(4))) float f32x4;

static constexpr int kCntW = 33;
static constexpr int kAhS  = 136;   // Adh / work stride (fp16)
// enc1/enc2 LDS (bytes): Adh[112][136] @0 (30464) | work[128][136] @30464
// (34816). cnt32 overlays work during build; scr overlays Adh in epilogues.
// Total 65280 -> 2 blocks/CU (r18's 155.5KB/1-block was the 202us cause).
static constexpr unsigned kLdsEnc = 65280;

// ============ weight prep: W[K][Nc] f32 -> Wt[(kg*Nc + c)*8 + e] fp16 ============
__global__ __launch_bounds__(256)
void wprep_k(const float* __restrict__ s0, const float* __restrict__ s1,
             const float* __restrict__ s2, const float* __restrict__ s3,
             const float* __restrict__ s4, _Float16* __restrict__ d)
{
  int seg = blockIdx.x >> 7;
  int idx = (blockIdx.x & 127) * 256 + threadIdx.x;
  const float* S; int Nc;
  switch (seg) {
    case 0: S = s0; Nc = 256; break;
    case 1: S = s1; Nc = 128; break;
    case 2: S = s2; Nc = 256; break;
    case 3: S = s3; Nc = 128; break;
    default: S = s4; Nc = 256; break;
  }
  int e = idx & 7, t = idx >> 3;
  int c = t % Nc, kg = t / Nc;
  d[seg * 32768 + idx] = (_Float16)S[(size_t)(kg * 8 + e) * Nc + c];
}

// ================= phase-1 encoder: GEMM1 + agg256 (+stats | +segBN) =================
// blockIdx.y: 0=main -> raw h to hB0 + PST partials; 1=pos -> segBN'd h2 to
// hB1; 2=neg -> hB2. Layer-1 processed in two 128-col halves through one
// 34.8KB work region; NOTHING persists across halves (r19 spill lesson).
__global__ __launch_bounds__(512)
void enc1_k(const float* __restrict__ x0, const float* __restrict__ x1,
            const float* __restrict__ x2,
            const int* __restrict__ src0, const int* __restrict__ src1,
            const int* __restrict__ src2,
            const int* __restrict__ dst0, const int* __restrict__ dst1,
            const int* __restrict__ dst2,
            const _Float16* __restrict__ Wt1m, const _Float16* __restrict__ Wt1s,
            const float* __restrict__ b1m, const float* __restrict__ b1s,
            _Float16* __restrict__ hB0, _Float16* __restrict__ hB1,
            _Float16* __restrict__ hB2, float* __restrict__ PST)
{
  extern __shared__ __align__(16) char lds_c[];
  _Float16* Adh  = (_Float16*)lds_c;                // [112][136]
  _Float16* work = (_Float16*)(lds_c + 30464);      // [128][136] multi-role
  unsigned* cnt32 = (unsigned*)(lds_c + 30464);     // overlay (build only)
  __shared__ int scnt[kNPG];
  __shared__ float sdinv[kNPG];
  const int yb = blockIdx.y;
  const float* X = (yb == 0) ? x0 : (yb == 1) ? x1 : x2;
  const int* srcI = (yb == 0) ? src0 : (yb == 1) ? src1 : src2;
  const int* dstI = (yb == 0) ? dst0 : (yb == 1) ? dst1 : dst2;
  const _Float16* W1 = (yb == 0) ? Wt1m : Wt1s;
  const float* bias1 = (yb == 0) ? b1m : b1s;
  _Float16* HB = (yb == 0) ? hB0 : (yb == 1) ? hB1 : hB2;
  const int epg = (yb == 0) ? kEPG : kESG;
  const int g = blockIdx.x, tid = threadIdx.x;
  const int base = g * kNPG;
  const size_t ebase = (size_t)g * epg;
  const int lane = tid & 63, wv = tid >> 6;
  const int l15 = lane & 15, lg = lane >> 4;

  // ---- adjacency build (deterministic integer counts)
  for (int i = tid; i < 112 * kCntW; i += 512) cnt32[i] = 0u;
  if (tid < kNPG) scnt[tid] = 0;
  __syncthreads();
  for (int e = tid; e < epg; e += 512) {
    int s = srcI[ebase + e] - base;
    int d = dstI[ebase + e] - base;
    atomicAdd(&scnt[d], 1);
    atomicAdd(&cnt32[d * kCntW + (s >> 2)], 1u << (8 * (s & 3)));
  }
  __syncthreads();
  if (tid < kNPG) sdinv[tid] = rsqrtf((float)scnt[tid] + 1.f);
  __syncthreads();
  for (int i = tid; i < 112 * kAhS; i += 512) {
    int d = i / kAhS, s = i - d * kAhS;
    float v = 0.f;
    if (d < 100 && s < 100) {
      unsigned w = cnt32[d * kCntW + (s >> 2)];
      unsigned c = (w >> (8 * (s & 3))) & 0xFFu;
      c += (s == d) ? 1u : 0u;
      v = (float)c * sdinv[s] * sdinv[d];
    }
    Adh[i] = (_Float16)v;
  }
  __syncthreads();   // cnt dead; work region free

#pragma unroll
  for (int half = 0; half < 2; ++half) {
    // ---- GEMM1 for this half's 128 cols (regs only; no LDS touched)
    f32x4 a1[8];
#pragma unroll
    for (int mt = 0; mt < 8; ++mt) a1[mt] = (f32x4){0.f, 0.f, 0.f, 0.f};
    const int bc = half * 128 + wv * 16 + l15;
#pragma unroll
    for (int ks = 0; ks < 4; ++ks) {
      const int kb = ks * 32 + lg * 8;
      half8 bF = *(const half8*)&W1[((size_t)(ks * 4 + lg) * 256 + bc) * 8];
#pragma unroll
      for (int mt = 0; mt < 8; ++mt) {
        const int row = min(base + mt * 16 + l15, kN - 1);
        const float* ap = X + (size_t)row * 128 + kb;
        float4 u0 = *(const float4*)ap, u1 = *(const float4*)(ap + 4);
        half8 aF;
        aF[0] = (_Float16)u0.x; aF[1] = (_Float16)u0.y;
        aF[2] = (_Float16)u0.z; aF[3] = (_Float16)u0.w;
        aF[4] = (_Float16)u1.x; aF[5] = (_Float16)u1.y;
        aF[6] = (_Float16)u1.z; aF[7] = (_Float16)u1.w;
        a1[mt] = __builtin_amdgcn_mfma_f32_16x16x32_f16(aF, bF, a1[mt], 0, 0, 0);
      }
    }
    __syncthreads();   // prior half's work reads (or build reads) complete
    // ---- write hTh transposed [col][j]
#pragma unroll
    for (int mt = 0; mt < 8; ++mt)
#pragma unroll
      for (int q = 0; q < 4; ++q)
        work[(wv * 16 + l15) * kAhS + mt * 16 + lg * 4 + q] = (_Float16)a1[mt][q];
    __syncthreads();
    // ---- agg256 half + bias + relu
    f32x4 a2[7];
#pragma unroll
    for (int mt = 0; mt < 7; ++mt) a2[mt] = (f32x4){0.f, 0.f, 0.f, 0.f};
#pragma unroll
    for (int ks = 0; ks < 4; ++ks) {
      const int kb = ks * 32 + lg * 8;
      half8 bF = *(const half8*)&work[(wv * 16 + l15) * kAhS + kb];
#pragma unroll
      for (int mt = 0; mt < 7; ++mt) {
        half8 aF = *(const half8*)&Adh[(mt * 16 + l15) * kAhS + kb];
        a2[mt] = __builtin_amdgcn_mfma_f32_16x16x32_f16(aF, bF, a2[mt], 0, 0, 0);
      }
    }
    float bv = bias1[bc];
#pragma unroll
    for (int mt = 0; mt < 7; ++mt)
#pragma unroll
      for (int q = 0; q < 4; ++q)
        a2[mt][q] = fmaxf(a2[mt][q] + bv, 0.f);
    // ---- column sums (column-local; fixed order)
    float s0 = 0.f, s20 = 0.f;
#pragma unroll
    for (int mt = 0; mt < 7; ++mt)
#pragma unroll
      for (int q = 0; q < 4; ++q) {
        int row = mt * 16 + lg * 4 + q;
        if (row < 100) { float v = a2[mt][q]; s0 += v; s20 += v * v; }
      }
    s0 += __shfl_xor(s0, 16, 64);  s0 += __shfl_xor(s0, 32, 64);
    s20 += __shfl_xor(s20, 16, 64); s20 += __shfl_xor(s20, 32, 64);
    if (yb == 0) {
      if (lg == 0) {
        PST[(size_t)g * 512 + bc] = s0;
        PST[(size_t)g * 512 + 256 + bc] = s20;
      }
#pragma unroll
      for (int mt = 0; mt < 7; ++mt)
#pragma unroll
        for (int q = 0; q < 4; ++q) {
          int row = mt * 16 + lg * 4 + q;
          if (row < 100)
            HB[(size_t)(base + row) * 256 + bc] = (_Float16)a2[mt][q];
        }
    } else {
      float m0 = s0 / 100.f, r0 = rsqrtf(s20 / 100.f - m0 * m0 + BN_EPS);
#pragma unroll
      for (int mt = 0; mt < 7; ++mt)
#pragma unroll
        for (int q = 0; q < 4; ++q) {
          int row = mt * 16 + lg * 4 + q;
          if (row < 100)
            HB[(size_t)(base + row) * 256 + bc] = (_Float16)((a2[mt][q] - m0) * r0);
        }
    }
  }
}

// ================= phase-2 encoder (3-wide): hB -> (BN) -> GEMM2 -> agg128 =================
// blockIdx.y: 0=main (BN transform, epilogue z/z16/maxp); 1=pos, 2=neg
// (no transform, epilogue mean-pool).
__global__ __launch_bounds__(512)
void enc2_k(const _Float16* __restrict__ hB0, const _Float16* __restrict__ hB1,
            const _Float16* __restrict__ hB2, const float* __restrict__ tr,
            const _Float16* __restrict__ Wt2, const float* __restrict__ b2,
            const int* __restrict__ src0, const int* __restrict__ src1,
            const int* __restrict__ src2,
            const int* __restrict__ dst0, const int* __restrict__ dst1,
            const int* __restrict__ dst2,
            const float* __restrict__ NOI,
            float* __restrict__ OZ, _Float16* __restrict__ Z16,
            float* __restrict__ ZG, float* __restrict__ ZZ,
            float* __restrict__ OP1, float* __restrict__ OP2)
{
  extern __shared__ __align__(16) char lds_c[];
  _Float16* Adh = (_Float16*)lds_c;                 // [112][136]
  _Float16* hT2 = (_Float16*)(lds_c + 30464);       // [128][136]
  unsigned* cnt32 = (unsigned*)(lds_c + 30464);     // overlay (build only)
  float* scr = (float*)lds_c;                       // overlay (epilogue)
  __shared__ int scnt[kNPG];
  __shared__ float sdinv[kNPG];
  const int yb = blockIdx.y;
  const _Float16* HB = (yb == 0) ? hB0 : (yb == 1) ? hB1 : hB2;
  const int* srcI = (yb == 0) ? src0 : (yb == 1) ? src1 : src2;
  const int* dstI = (yb == 0) ? dst0 : (yb == 1) ? dst1 : dst2;
  const int epg = (yb == 0) ? kEPG : kESG;
  const int g = blockIdx.x, tid = threadIdx.x;
  const int base = g * kNPG;
  const size_t ebase = (size_t)g * epg;
  const int lane = tid & 63, wv = tid >> 6;
  const int l15 = lane & 15, lg = lane >> 4;

  for (int i = tid; i < 112 * kCntW; i += 512) cnt32[i] = 0u;
  if (tid < kNPG) scnt[tid] = 0;
  __syncthreads();
  for (int e = tid; e < epg; e += 512) {
    int s = srcI[ebase + e] - base;
    int d = dstI[ebase + e] - base;
    atomicAdd(&scnt[d], 1);
    atomicAdd(&cnt32[d * kCntW + (s >> 2)], 1u << (8 * (s & 3)));
  }
  __syncthreads();
  if (tid < kNPG) sdinv[tid] = rsqrtf((float)scnt[tid] + 1.f);
  __syncthreads();
  for (int i = tid; i < 112 * kAhS; i += 512) {
    int d = i / kAhS, s = i - d * kAhS;
    float v = 0.f;
    if (d < 100 && s < 100) {
      unsigned w = cnt32[d * kCntW + (s >> 2)];
      unsigned c = (w >> (8 * (s & 3))) & 0xFFu;
      c += (s == d) ? 1u : 0u;
      v = (float)c * sdinv[s] * sdinv[d];
    }
    Adh[i] = (_Float16)v;
  }
  __syncthreads();   // cnt dead -> hT2 writable

  // ---- GEMM2 from global hB (BN transform only yb==0), M=128 via wave=mt
  {
    const int mt = wv;
    const int r = min(base + mt * 16 + l15, kN - 1);
    f32x4 a3[8];
#pragma unroll
    for (int nt = 0; nt < 8; ++nt) a3[nt] = (f32x4){0.f, 0.f, 0.f, 0.f};
#pragma unroll
    for (int ks = 0; ks < 8; ++ks) {
      const int kb = ks * 32 + lg * 8;
      half8 h = *(const half8*)&HB[(size_t)r * 256 + kb];
      half8 aF;
      if (yb == 0) {
#pragma unroll
        for (int j = 0; j < 8; ++j)
          aF[j] = (_Float16)(((float)h[j] - tr[kb + j]) * tr[256 + kb + j]);
      } else {
        aF = h;
      }
#pragma unroll
      for (int nt = 0; nt < 8; ++nt) {
        half8 bF = *(const half8*)&Wt2[((size_t)(ks * 4 + lg) * 128 + nt * 16 + l15) * 8];
        a3[nt] = __builtin_amdgcn_mfma_f32_16x16x32_f16(aF, bF, a3[nt], 0, 0, 0);
      }
    }
#pragma unroll
    for (int nt = 0; nt < 8; ++nt)
#pragma unroll
      for (int q = 0; q < 4; ++q)
        hT2[(nt * 16 + l15) * kAhS + mt * 16 + lg * 4 + q] = (_Float16)a3[nt][q];
  }
  __syncthreads();

  // ---- agg128 + bias + l2norm + per-y epilogue
  {
    const int mt = wv;
    f32x4 a4[8];
#pragma unroll
    for (int nt = 0; nt < 8; ++nt) a4[nt] = (f32x4){0.f, 0.f, 0.f, 0.f};
    if (mt < 7) {
#pragma unroll
      for (int ks = 0; ks < 4; ++ks) {
        const int kb = ks * 32 + lg * 8;
        half8 aF = *(const half8*)&Adh[(mt * 16 + l15) * kAhS + kb];
#pragma unroll
        for (int nt = 0; nt < 8; ++nt) {
          half8 bF = *(const half8*)&hT2[(nt * 16 + l15) * kAhS + kb];
          a4[nt] = __builtin_amdgcn_mfma_f32_16x16x32_f16(aF, bF, a4[nt], 0, 0, 0);
        }
      }
#pragma unroll
      for (int nt = 0; nt < 8; ++nt) {
        float bvn = b2[nt * 16 + l15];
#pragma unroll
        for (int q = 0; q < 4; ++q) a4[nt][q] += bvn;
      }
#pragma unroll
      for (int q = 0; q < 4; ++q) {
        float ss = 0.f;
#pragma unroll
        for (int nt = 0; nt < 8; ++nt) ss += a4[nt][q] * a4[nt][q];
        ss += __shfl_xor(ss, 1, 64); ss += __shfl_xor(ss, 2, 64);
        ss += __shfl_xor(ss, 4, 64); ss += __shfl_xor(ss, 8, 64);
        float inv = 1.f / fmaxf(sqrtf(ss), 1e-12f);
#pragma unroll
        for (int nt = 0; nt < 8; ++nt) a4[nt][q] *= inv;
      }
    }
    if (yb == 0) {
      if (mt < 7) {
#pragma unroll
        for (int nt = 0; nt < 8; ++nt)
#pragma unroll
          for (int q = 0; q < 4; ++q) {
            int row = mt * 16 + lg * 4 + q;
            if (row < 100) {
              OZ[(size_t)(base + row) * 128 + nt * 16 + l15] = a4[nt][q];
              Z16[(size_t)(base + row) * 128 + nt * 16 + l15] = (_Float16)a4[nt][q];
            }
          }
      }
      float m1[8], m2[8];
#pragma unroll
      for (int nt = 0; nt < 8; ++nt) { m1[nt] = -INFINITY; m2[nt] = -INFINITY; }
      if (mt < 7) {
#pragma unroll
        for (int nt = 0; nt < 8; ++nt)
#pragma unroll
          for (int q = 0; q < 4; ++q) {
            int row = mt * 16 + lg * 4 + q;
            if (row < 100) {
              float zv = a4[nt][q];
              float nv = NOI[(size_t)(base + row) * 128 + nt * 16 + l15];
              m1[nt] = fmaxf(m1[nt], zv);
              m2[nt] = fmaxf(m2[nt], zv + nv);
            }
          }
#pragma unroll
        for (int nt = 0; nt < 8; ++nt) {
          m1[nt] = fmaxf(m1[nt], __shfl_xor(m1[nt], 16, 64));
          m1[nt] = fmaxf(m1[nt], __shfl_xor(m1[nt], 32, 64));
          m2[nt] = fmaxf(m2[nt], __shfl_xor(m2[nt], 16, 64));
          m2[nt] = fmaxf(m2[nt], __shfl_xor(m2[nt], 32, 64));
        }
      }
      __syncthreads();                  // Adh dead -> scr
      if (mt < 7 && lg == 0)
#pragma unroll
        for (int nt = 0; nt < 8; ++nt) {
          scr[wv * 128 + nt * 16 + l15] = m1[nt];
          scr[1024 + wv * 128 + nt * 16 + l15] = m2[nt];
        }
      __syncthreads();
      if (tid < 128) {
        float a = -INFINITY, b = -INFINITY;
        for (int w2 = 0; w2 < 7; ++w2) {
          a = fmaxf(a, scr[w2 * 128 + tid]);
          b = fmaxf(b, scr[1024 + w2 * 128 + tid]);
        }
        ZG[(size_t)g * 128 + tid] = a;
        ZZ[(size_t)g * 128 + tid] = a;
        ZZ[(size_t)(500 + g) * 128 + tid] = b;
      }
    } else {
      float ps[8];
#pragma unroll
      for (int nt = 0; nt < 8; ++nt) ps[nt] = 0.f;
      if (mt < 7) {
#pragma unroll
        for (int nt = 0; nt < 8; ++nt)
#pragma unroll
          for (int q = 0; q < 4; ++q) {
            int row = mt * 16 + lg * 4 + q;
            if (row < 100) ps[nt] += a4[nt][q];
          }
      }
#pragma unroll
      for (int nt = 0; nt < 8; ++nt) {
        ps[nt] += __shfl_xor(ps[nt], 16, 64);
        ps[nt] += __shfl_xor(ps[nt], 32, 64);
      }
      __syncthreads();                  // Adh dead -> scr
      if (mt < 7 && lg == 0)
#pragma unroll
        for (int nt = 0; nt < 8; ++nt) scr[wv * 128 + nt * 16 + l15] = ps[nt];
      __syncthreads();
      if (tid < 128) {
        float s = 0.f;
        for (int w2 = 0; w2 < 7; ++w2) s += scr[w2 * 128 + tid];
        float* OP = (yb == 1) ? OP1 : OP2;
        OP[(size_t)g * 128 + tid] = s / 100.f;
      }
    }
  }
}

// ================= fused decoder: o_xr = sigmoid(relu(z16@W1)@W2) =================
__global__ __launch_bounds__(512)
void dec_fused_k(const _Float16* __restrict__ Z, const _Float16* __restrict__ Wt1,
                 const _Float16* __restrict__ Wt2, float* __restrict__ XR, int M)
{
  __shared__ alignas(16) _Float16 Hrm[64][264];
  const int tid = threadIdx.x;
  const int lane = tid & 63;
  const int l15 = lane & 15, lg = lane >> 4;
  const int wave = tid >> 6;
  const int wm = wave >> 2;
  const int wn = wave & 3;
  const int bm = blockIdx.x * 64;

  f32x4 acc[2][4];
#pragma unroll
  for (int m = 0; m < 2; ++m)
#pragma unroll
    for (int n = 0; n < 4; ++n) acc[m][n] = (f32x4){0.f, 0.f, 0.f, 0.f};
  int arow[2];
#pragma unroll
  for (int m = 0; m < 2; ++m)
    arow[m] = min(bm + wm * 32 + m * 16 + l15, M - 1);
  const int bcol = wn * 64 + l15;
#pragma unroll
  for (int ks = 0; ks < 4; ++ks) {
    const int kb = ks * 32 + lg * 8;
    half8 bF[4];
#pragma unroll
    for (int n = 0; n < 4; ++n)
      bF[n] = *(const half8*)&Wt1[((size_t)(ks * 4 + lg) * 256 + bcol + n * 16) * 8];
    half8 aF[2];
#pragma unroll
    for (int m = 0; m < 2; ++m)
      aF[m] = *(const half8*)&Z[(size_t)arow[m] * 128 + kb];
#pragma unroll
    for (int m = 0; m < 2; ++m)
#pragma unroll
      for (int n = 0; n < 4; ++n)
        acc[m][n] = __builtin_amdgcn_mfma_f32_16x16x32_f16(aF[m], bF[n], acc[m][n], 0, 0, 0);
  }
#pragma unroll
  for (int m = 0; m < 2; ++m)
#pragma unroll
    for (int q = 0; q < 4; ++q) {
      int lrow = wm * 32 + m * 16 + lg * 4 + q;
#pragma unroll
      for (int n = 0; n < 4; ++n)
        Hrm[lrow][wn * 64 + n * 16 + l15] = (_Float16)fmaxf(acc[m][n][q], 0.f);
    }
  __syncthreads();

  const int wm2 = wave & 1, wn2 = wave >> 1;
  f32x4 acc2[2][2];
#pragma unroll
  for (int m = 0; m < 2; ++m)
#pragma unroll
    for (int n = 0; n < 2; ++n) acc2[m][n] = (f32x4){0.f, 0.f, 0.f, 0.f};
#pragma unroll
  for (int ks = 0; ks < 8; ++ks) {
    const int kb = ks * 32 + lg * 8;
    half8 aF[2];
#pragma unroll
    for (int m = 0; m < 2; ++m)
      aF[m] = *(const half8*)&Hrm[wm2 * 32 + m * 16 + l15][kb];
    half8 bF[2];
#pragma unroll
    for (int n = 0; n < 2; ++n)
      bF[n] = *(const half8*)&Wt2[((size_t)(ks * 4 + lg) * 128 + wn2 * 32 + n * 16 + l15) * 8];
#pragma unroll
    for (int m = 0; m < 2; ++m)
#pragma unroll
      for (int n = 0; n < 2; ++n)
        acc2[m][n] = __builtin_amdgcn_mfma_f32_16x16x32_f16(aF[m], bF[n], acc2[m][n], 0, 0, 0);
  }
#pragma unroll
  for (int m = 0; m < 2; ++m)
#pragma unroll
    for (int q = 0; q < 4; ++q) {
      int row = bm + wm2 * 32 + m * 16 + lg * 4 + q;
      if (row >= M) continue;
#pragma unroll
      for (int n = 0; n < 2; ++n) {
        float v = acc2[m][n][q];
        XR[(size_t)row * 128 + wn2 * 32 + n * 16 + l15] = 1.f / (1.f + expf(-v));
      }
    }
}

// ======================= small-M tiled f32 GEMM (M<=1000 paths) =======================
template<int ACT>
__global__ __launch_bounds__(256)
void gemm_k(const float* __restrict__ A, const float* __restrict__ W,
            const float* __restrict__ bias, float* __restrict__ C,
            int M, int K, int Nc)
{
  __shared__ float As[32][136];
  __shared__ float Ws[32][68];
  const int tid = threadIdx.x;
  const int bm = blockIdx.x * 128;
  const int bn = blockIdx.y * 64;
  const int tm = (tid & 15) * 8;
  const int tn = (tid >> 4) * 4;
  float acc[8][4];
#pragma unroll
  for (int i = 0; i < 8; ++i)
#pragma unroll
    for (int j = 0; j < 4; ++j) acc[i][j] = 0.f;

  for (int k0 = 0; k0 < K; k0 += 32) {
#pragma unroll
    for (int l = 0; l < 4; ++l) {
      int idx = tid + l * 256;
      int r = idx >> 3;
      int kq = (idx & 7) << 2;
      int gr = bm + r;
      float4 v = make_float4(0.f, 0.f, 0.f, 0.f);
      if (gr < M) v = *(const float4*)&A[(size_t)gr * K + k0 + kq];
      As[kq + 0][r] = v.x; As[kq + 1][r] = v.y;
      As[kq + 2][r] = v.z; As[kq + 3][r] = v.w;
    }
#pragma unroll
    for (int l = 0; l < 2; ++l) {
      int idx = tid + l * 256;
      int r = idx >> 4;
      int nq = (idx & 15) << 2;
      *(float4*)&Ws[r][nq] = *(const float4*)&W[(size_t)(k0 + r) * Nc + bn + nq];
    }
    __syncthreads();
#pragma unroll
    for (int kk = 0; kk < 32; ++kk) {
      float4 a0 = *(float4*)&As[kk][tm];
      float4 a1 = *(float4*)&As[kk][tm + 4];
      float4 w4 = *(float4*)&Ws[kk][tn];
      float am[8] = {a0.x, a0.y, a0.z, a0.w, a1.x, a1.y, a1.z, a1.w};
      float wn4[4] = {w4.x, w4.y, w4.z, w4.w};
#pragma unroll
      for (int i = 0; i < 8; ++i)
#pragma unroll
        for (int j = 0; j < 4; ++j) acc[i][j] += am[i] * wn4[j];
    }
    __syncthreads();
  }
  float4 bv = make_float4(0.f, 0.f, 0.f, 0.f);
  if (bias) bv = *(const float4*)&bias[bn + tn];
#pragma unroll
  for (int i = 0; i < 8; ++i) {
    int row = bm + tm + i;
    if (row >= M) break;
    float o0 = acc[i][0] + bv.x, o1 = acc[i][1] + bv.y;
    float o2 = acc[i][2] + bv.z, o3 = acc[i][3] + bv.w;
    if (ACT == 1) {
      o0 = fmaxf(o0, 0.f); o1 = fmaxf(o1, 0.f);
      o2 = fmaxf(o2, 0.f); o3 = fmaxf(o3, 0.f);
    } else if (ACT == 2) {
      o0 = 1.f / (1.f + expf(-o0)); o1 = 1.f / (1.f + expf(-o1));
      o2 = 1.f / (1.f + expf(-o2)); o3 = 1.f / (1.f + expf(-o3));
    }
    *(float4*)&C[(size_t)row * Nc + bn + tn] = make_float4(o0, o1, o2, o3);
  }
}

// ============ BN finalize: sum 500 per-graph partials (fixed order) ============
__global__ __launch_bounds__(256)
void bn_red_k(const float* __restrict__ P, float* __restrict__ stats)
{
  const int c = threadIdx.x;
  float s = 0.f, s2 = 0.f;
  for (int b = 0; b < 500; ++b) {
    s  += P[(size_t)b * 512 + c];
    s2 += P[(size_t)b * 512 + 256 + c];
  }
  float m = s / (float)kN;
  float v = s2 / (float)kN - m * m;
  stats[512 + c] = m;
  stats[768 + c] = rsqrtf(v + BN_EPS);
}

__global__ __launch_bounds__(64)
void bn_cols_k(float* __restrict__ X, int rows, int cols)
{
  const int c = blockIdx.x, t = threadIdx.x;
  float s = 0.f, s2 = 0.f;
  for (int r = t; r < rows; r += 64) {
    float v = X[(size_t)r * cols + c];
    s += v; s2 += v * v;
  }
#pragma unroll
  for (int o = 32; o; o >>= 1) { s += __shfl_xor(s, o, 64); s2 += __shfl_xor(s2, o, 64); }
  float m = s / (float)rows;
  float var = s2 / (float)rows - m * m;
  float rinv = rsqrtf(var + BN_EPS);
  for (int r = t; r < rows; r += 64)
    X[(size_t)r * cols + c] = (X[(size_t)r * cols + c] - m) * rinv;
}

__global__ __launch_bounds__(256)
void l2n_k(const float* __restrict__ X, float* __restrict__ Y, int rows)
{
  const int w = threadIdx.x >> 6, lane = threadIdx.x & 63;
  const int row = blockIdx.x * 4 + w;
  if (row >= rows) return;
  float2 v = *(const float2*)&X[(size_t)row * kH2 + lane * 2];
  float ss = v.x * v.x + v.y * v.y;
#pragma unroll
  for (int o = 32; o; o >>= 1) ss += __shfl_xor(ss, o, 64);
  float inv = 1.f / fmaxf(sqrtf(ss), 1e-12f);
  *(float2*)&Y[(size_t)row * kH2 + lane * 2] = make_float2(v.x * inv, v.y * inv);
}

// =========================================================================
extern "C" void kernel_launch(void* const* d_in, const int* in_sizes, int n_in,
                              void* d_out, int out_size, void* d_ws, size_t ws_size,
                              hipStream_t stream)
{
  const float* x        = (const float*)d_in[0];
  const int*   srcI     = (const int*)d_in[1];
  const int*   dstI     = (const int*)d_in[2];
  const float* pos_x    = (const float*)d_in[4];
  const int*   psrc     = (const int*)d_in[5];
  const int*   pdst     = (const int*)d_in[6];
  const float* neg_x    = (const float*)d_in[8];
  const int*   nsrc     = (const int*)d_in[9];
  const int*   ndst     = (const int*)d_in[10];
  const float* target_x = (const float*)d_in[12];
  const float* noise    = (const float*)d_in[13];
  const float* W_enc1   = (const float*)d_in[14];
  const float* b_enc1   = (const float*)d_in[15];
  const float* W_enc2   = (const float*)d_in[16];
  const float* b_enc2   = (const float*)d_in[17];
  const float* W_dec1   = (const float*)d_in[18];
  const float* W_dec2   = (const float*)d_in[19];
  const float* Wn1      = (const float*)d_in[20];
  const float* bn1      = (const float*)d_in[21];
  const float* Wn2      = (const float*)d_in[22];
  const float* bn2      = (const float*)d_in[23];
  const float* Ws1      = (const float*)d_in[24];
  const float* bs1      = (const float*)d_in[25];
  const float* Wp1      = (const float*)d_in[26];
  const float* bp1      = (const float*)d_in[27];
  const float* Wp2      = (const float*)d_in[28];
  const float* bp2      = (const float*)d_in[29];

  float* out  = (float*)d_out;
  float* o_z   = out;                 // N x 128
  float* o_zg  = out + 6400000;       // 500 x 128
  float* o_xr  = out + 6464000;       // N x 128
  float* o_pos = out + 12864000;      // 500 x 128
  float* o_neg = out + 12928000;
  float* o_zgm = out + 12992000;      // o_zgm||o_zpm contiguous 1000 x 128
  float* o_tz  = out + 13120000;

  // WORKSPACE MAP (float offsets; r2-r4 audit per launch):
  //  hB0 [0, 6.4M):        main raw h   fp16 N x 256
  //  hB1 [6.4M, 12.8M):    pos segBN'd  fp16 N x 256
  //  hB2 [12.8M, 19.2M):   neg segBN'd  fp16 N x 256
  //  z16 [19.2M, 22.4M):   fp16 N x 128
  //  pstat 22.4M (256000); zz 22.7M; t1000 22.9M; t1 23.1M; t2 23.3M;
  //  hWt 25.6M; stats 25.7M.
  float* ws = (float*)d_ws;
  _Float16* hB0 = (_Float16*)ws;
  _Float16* hB1 = (_Float16*)(ws + 6400000);
  _Float16* hB2 = (_Float16*)(ws + 12800000);
  _Float16* z16 = (_Float16*)(ws + 19200000);
  float* pstat = ws + 22400000;
  float* zz    = ws + 22700000;
  float* t1000 = ws + 22900000;
  float* t1    = ws + 23100000;
  float* t2    = ws + 23300000;
  _Float16* hWt = (_Float16*)(ws + 25600000);
  float* stats = ws + 25700000;
  if (ws_size < (size_t)(25921024) * sizeof(float)) return;

  _Float16* WtEnc1 = hWt;
  _Float16* WtEnc2 = hWt + 32768;
  _Float16* WtDec1 = hWt + 65536;
  _Float16* WtDec2 = hWt + 98304;
  _Float16* WtS1   = hWt + 131072;

  (void)hipFuncSetAttribute((const void*)enc1_k,
      hipFuncAttributeMaxDynamicSharedMemorySize, kLdsEnc);
  (void)hipFuncSetAttribute((const void*)enc2_k,
      hipFuncAttributeMaxDynamicSharedMemorySize, kLdsEnc);

  auto gg = [](int M, int Nc) {
    return dim3((unsigned)((M + 127) / 128), (unsigned)(Nc / 64), 1);
  };

  // 1. weight prep
  wprep_k<<<640, 256, 0, stream>>>(W_enc1, W_enc2, W_dec1, W_dec2, Ws1, hWt);

  // 2. phase-1 encoder (3-wide, 2 blocks/CU): x -> hB0(+pstat) / hB1 / hB2
  enc1_k<<<dim3(kB, 3), 512, kLdsEnc, stream>>>(
      x, pos_x, neg_x, srcI, psrc, nsrc, dstI, pdst, ndst,
      WtEnc1, WtS1, b_enc1, bs1, hB0, hB1, hB2, pstat);

  // 3. BN finalize
  bn_red_k<<<1, 256, 0, stream>>>(pstat, stats);

  // 4. phase-2 encoder (3-wide, 2 blocks/CU): hB* -> z/z16/zg/zz + o_pos/o_neg
  enc2_k<<<dim3(kB, 3), 512, kLdsEnc, stream>>>(
      hB0, hB1, hB2, stats + 512, WtEnc2, b_enc2,
      srcI, psrc, nsrc, dstI, pdst, ndst, noise,
      o_z, z16, o_zg, zz, o_pos, o_neg);

  // 5. fused decoder: z16 -> o_xr
  dec_fused_k<<<782, 512, 0, stream>>>(z16, WtDec1, WtDec2, o_xr, kN);

  // 6-7. merged projection heads
  gemm_k<1><<<gg(1000, kH2), 256, 0, stream>>>(zz, Wp1, bp1, t1000, 1000, kH2, kH2);
  gemm_k<0><<<gg(1000, kH2), 256, 0, stream>>>(t1000, Wp2, bp2, o_zgm, 1000, kH2, kH2);

  // 8-11. target node encoder
  gemm_k<1><<<gg(kB, kH1), 256, 0, stream>>>(target_x, Wn1, bn1, t1, kB, kF0, kH1);
  bn_cols_k<<<256, 64, 0, stream>>>(t1, kB, kH1);
  gemm_k<0><<<gg(kB, kH2), 256, 0, stream>>>(t1, Wn2, bn2, t2, kB, kH1, kH2);
  l2n_k<<<125, 256, 0, stream>>>(t2, o_tz, kB);

  (void)in_sizes; (void)n_in; (void)out_size;
}

// Round 22
// 329.007 us; speedup vs baseline: 1.3723x; 1.3723x over previous
//
#include <hip/hip_runtime.h>
#include <math.h>

static constexpr int kN   = 50000;
static constexpr int kB   = 500;
static constexpr int kNPG = 100;
static constexpr int kEPG = 1600;
static constexpr int kESG = 800;
static constexpr int kF0  = 128;
static constexpr int kH1  = 256;
static constexpr int kH2  = 128;
#define BN_EPS 1e-5f

typedef _Float16 half8 __attribute__((ext_vector_type(8)));
typedef __attribute__((ext_vector_type(4))) float f32x4;

static constexpr int kCntW = 33;
static constexpr int kAhS  = 136;     // Adh / hT / hT2 stride (fp16)
static constexpr int kH2S  = 264;     // h2 stride (fp16)
// enc1 LDS (bytes): Adh[112][136] @0 (30464) | hT[256][136] @30464 (69632)
//  | h2[112][264] @100096 (59136). cnt32 overlays hT pre-GEMM1; hT2[128][136]
//  overlays hT post-agg256; scr overlays Adh post-agg128. Total 159232.
static constexpr unsigned kLds1 = 159232;
// enc2 LDS: Adh 30464 | hT2[128][136] @30464 (34816) (cnt overlays hT2). 65280.
static constexpr unsigned kLds2 = 65280;

// ============ weight prep: W[K][Nc] f32 -> Wt[(kg*Nc + c)*8 + e] fp16 ============
__global__ __launch_bounds__(256)
void wprep_k(const float* __restrict__ s0, const float* __restrict__ s1,
             const float* __restrict__ s2, const float* __restrict__ s3,
             const float* __restrict__ s4, _Float16* __restrict__ d)
{
  int seg = blockIdx.x >> 7;
  int idx = (blockIdx.x & 127) * 256 + threadIdx.x;
  const float* S; int Nc;
  switch (seg) {
    case 0: S = s0; Nc = 256; break;
    case 1: S = s1; Nc = 128; break;
    case 2: S = s2; Nc = 256; break;
    case 3: S = s3; Nc = 128; break;
    default: S = s4; Nc = 256; break;
  }
  int e = idx & 7, t = idx >> 3;
  int c = t % Nc, kg = t / Nc;
  d[seg * 32768 + idx] = (_Float16)S[(size_t)(kg * 8 + e) * Nc + c];
}

// ============ x prep: fp32 N x 128 -> fp16 (bit-identical to in-GEMM cvt) ============
__global__ __launch_bounds__(256)
void xprep_k(const float* __restrict__ x0, const float* __restrict__ x1,
             const float* __restrict__ x2, _Float16* __restrict__ d0,
             _Float16* __restrict__ d1, _Float16* __restrict__ d2)
{
  const size_t idx = (size_t)blockIdx.x * 256 + threadIdx.x;   // 2.4M threads
  const size_t per = (size_t)kN * 16;                          // half8 groups
  const int seg = (int)(idx / per);
  const size_t off = (idx - (size_t)seg * per) * 8;
  const float* S = (seg == 0) ? x0 : (seg == 1) ? x1 : x2;
  _Float16* D = (seg == 0) ? d0 : (seg == 1) ? d1 : d2;
  float4 u0 = *(const float4*)&S[off];
  float4 u1 = *(const float4*)&S[off + 4];
  half8 h;
  h[0] = (_Float16)u0.x; h[1] = (_Float16)u0.y;
  h[2] = (_Float16)u0.z; h[3] = (_Float16)u0.w;
  h[4] = (_Float16)u1.x; h[5] = (_Float16)u1.y;
  h[6] = (_Float16)u1.z; h[7] = (_Float16)u1.w;
  *(half8*)&D[off] = h;
}

// ================= phase-1 fused encoder (per-graph blocks) =================
// blockIdx.y: 0=main (GEMM1+agg256+STATS -> hB global, stops), 1=pos, 2=neg
// (full chain GEMM1+agg256+segBN -> GEMM2+agg128+l2n+pool -> OP).
// A-operand read from precomputed fp16 X16 (one half8 load, r21 lesson:
// the fp32 double-load + cvt chain was the latency bottleneck).
__global__ __launch_bounds__(512)
void enc1_k(const _Float16* __restrict__ x0, const _Float16* __restrict__ x1,
            const _Float16* __restrict__ x2,
            const int* __restrict__ src0, const int* __restrict__ src1,
            const int* __restrict__ src2,
            const int* __restrict__ dst0, const int* __restrict__ dst1,
            const int* __restrict__ dst2,
            const _Float16* __restrict__ Wt1m, const _Float16* __restrict__ Wt1s,
            const _Float16* __restrict__ Wt2,
            const float* __restrict__ b1m, const float* __restrict__ b1s,
            const float* __restrict__ b2,
            _Float16* __restrict__ hB, float* __restrict__ PST,
            float* __restrict__ OP1, float* __restrict__ OP2)
{
  extern __shared__ __align__(16) char lds_c[];
  _Float16* Adh = (_Float16*)lds_c;                 // [112][136]
  _Float16* hT  = (_Float16*)(lds_c + 30464);       // [256][136]
  _Float16* h2  = (_Float16*)(lds_c + 100096);      // [112][264]
  unsigned* cnt32 = (unsigned*)(lds_c + 30464);     // overlay (build only)
  _Float16* hT2 = (_Float16*)(lds_c + 30464);       // overlay (stage 3+)
  float* scr = (float*)lds_c;                       // overlay (pool epilogue)
  __shared__ int scnt[kNPG];
  __shared__ float sdinv[kNPG];
  const int yb = blockIdx.y;
  const _Float16* X = (yb == 0) ? x0 : (yb == 1) ? x1 : x2;
  const int* srcI = (yb == 0) ? src0 : (yb == 1) ? src1 : src2;
  const int* dstI = (yb == 0) ? dst0 : (yb == 1) ? dst1 : dst2;
  const _Float16* W1 = (yb == 0) ? Wt1m : Wt1s;
  const float* bias1 = (yb == 0) ? b1m : b1s;
  const int epg = (yb == 0) ? kEPG : kESG;
  const int g = blockIdx.x, tid = threadIdx.x;
  const int base = g * kNPG;
  const size_t ebase = (size_t)g * epg;
  const int lane = tid & 63, wv = tid >> 6;
  const int l15 = lane & 15, lg = lane >> 4;

  // ---- build adjacency (deterministic integer counts)
  for (int i = tid; i < 112 * kCntW; i += 512) cnt32[i] = 0u;
  if (tid < kNPG) scnt[tid] = 0;
  __syncthreads();
  for (int e = tid; e < epg; e += 512) {
    int s = srcI[ebase + e] - base;
    int d = dstI[ebase + e] - base;
    atomicAdd(&scnt[d], 1);
    atomicAdd(&cnt32[d * kCntW + (s >> 2)], 1u << (8 * (s & 3)));
  }
  __syncthreads();
  if (tid < kNPG) sdinv[tid] = rsqrtf((float)scnt[tid] + 1.f);
  __syncthreads();
  for (int i = tid; i < 112 * kAhS; i += 512) {
    int d = i / kAhS, s = i - d * kAhS;
    float v = 0.f;
    if (d < 100 && s < 100) {
      unsigned w = cnt32[d * kCntW + (s >> 2)];
      unsigned c = (w >> (8 * (s & 3))) & 0xFFu;
      c += (s == d) ? 1u : 0u;
      v = (float)c * sdinv[s] * sdinv[d];
    }
    Adh[i] = (_Float16)v;
  }
  __syncthreads();   // cnt dead; hT region writable

  // ---- stage 1: GEMM1 (M=128 rows incl clamp-junk, N=256, K=128) -> hT^T
  {
    f32x4 a1[8][2];
#pragma unroll
    for (int mt = 0; mt < 8; ++mt) {
      a1[mt][0] = (f32x4){0.f, 0.f, 0.f, 0.f};
      a1[mt][1] = (f32x4){0.f, 0.f, 0.f, 0.f};
    }
    int rows[8];
#pragma unroll
    for (int mt = 0; mt < 8; ++mt) rows[mt] = min(base + mt * 16 + l15, kN - 1);
    const int bc0 = wv * 32 + l15;
#pragma unroll
    for (int ks = 0; ks < 4; ++ks) {
      const int kb = ks * 32 + lg * 8;
      half8 bF[2];
#pragma unroll
      for (int t = 0; t < 2; ++t)
        bF[t] = *(const half8*)&W1[((size_t)(ks * 4 + lg) * 256 + bc0 + t * 16) * 8];
#pragma unroll
      for (int mt = 0; mt < 8; ++mt) {
        half8 aF = *(const half8*)&X[(size_t)rows[mt] * 128 + kb];
#pragma unroll
        for (int t = 0; t < 2; ++t)
          a1[mt][t] = __builtin_amdgcn_mfma_f32_16x16x32_f16(aF, bF[t], a1[mt][t], 0, 0, 0);
      }
    }
#pragma unroll
    for (int mt = 0; mt < 8; ++mt)
#pragma unroll
      for (int t = 0; t < 2; ++t)
#pragma unroll
        for (int q = 0; q < 4; ++q) {
          int col = wv * 32 + t * 16 + l15;
          int j = mt * 16 + lg * 4 + q;
          hT[col * kAhS + j] = (_Float16)a1[mt][t][q];
        }
  }
  __syncthreads();

  // ---- stage 2: agg256 (M=112, cols wv*32..+31) + bias + relu + stats/segBN
  {
    f32x4 a2[7][2];
#pragma unroll
    for (int mt = 0; mt < 7; ++mt) {
      a2[mt][0] = (f32x4){0.f, 0.f, 0.f, 0.f};
      a2[mt][1] = (f32x4){0.f, 0.f, 0.f, 0.f};
    }
#pragma unroll
    for (int ks = 0; ks < 4; ++ks) {
      const int kb = ks * 32 + lg * 8;
      half8 bF[2];
#pragma unroll
      for (int t = 0; t < 2; ++t)
        bF[t] = *(const half8*)&hT[(wv * 32 + t * 16 + l15) * kAhS + kb];
#pragma unroll
      for (int mt = 0; mt < 7; ++mt) {
        half8 aF = *(const half8*)&Adh[(mt * 16 + l15) * kAhS + kb];
        a2[mt][0] = __builtin_amdgcn_mfma_f32_16x16x32_f16(aF, bF[0], a2[mt][0], 0, 0, 0);
        a2[mt][1] = __builtin_amdgcn_mfma_f32_16x16x32_f16(aF, bF[1], a2[mt][1], 0, 0, 0);
      }
    }
    float bv0 = bias1[wv * 32 + l15];
    float bv1 = bias1[wv * 32 + 16 + l15];
#pragma unroll
    for (int mt = 0; mt < 7; ++mt)
#pragma unroll
      for (int q = 0; q < 4; ++q) {
        a2[mt][0][q] = fmaxf(a2[mt][0][q] + bv0, 0.f);
        a2[mt][1][q] = fmaxf(a2[mt][1][q] + bv1, 0.f);
      }
    float s0 = 0.f, s20 = 0.f, s1 = 0.f, s21 = 0.f;
#pragma unroll
    for (int mt = 0; mt < 7; ++mt)
#pragma unroll
      for (int q = 0; q < 4; ++q) {
        int row = mt * 16 + lg * 4 + q;
        if (row < 100) {
          float v0 = a2[mt][0][q], v1 = a2[mt][1][q];
          s0 += v0; s20 += v0 * v0; s1 += v1; s21 += v1 * v1;
        }
      }
    s0 += __shfl_xor(s0, 16, 64);  s0 += __shfl_xor(s0, 32, 64);
    s20 += __shfl_xor(s20, 16, 64); s20 += __shfl_xor(s20, 32, 64);
    s1 += __shfl_xor(s1, 16, 64);  s1 += __shfl_xor(s1, 32, 64);
    s21 += __shfl_xor(s21, 16, 64); s21 += __shfl_xor(s21, 32, 64);
    if (yb == 0) {
      if (lg == 0) {
        PST[(size_t)g * 512 + wv * 32 + l15] = s0;
        PST[(size_t)g * 512 + 256 + wv * 32 + l15] = s20;
        PST[(size_t)g * 512 + wv * 32 + 16 + l15] = s1;
        PST[(size_t)g * 512 + 256 + wv * 32 + 16 + l15] = s21;
      }
#pragma unroll
      for (int mt = 0; mt < 7; ++mt)
#pragma unroll
        for (int q = 0; q < 4; ++q) {
          int row = mt * 16 + lg * 4 + q;
          if (row < 100) {
            hB[(size_t)(base + row) * 256 + wv * 32 + l15] = (_Float16)a2[mt][0][q];
            hB[(size_t)(base + row) * 256 + wv * 32 + 16 + l15] = (_Float16)a2[mt][1][q];
          }
        }
    } else {
      float m0 = s0 / 100.f, r0 = rsqrtf(s20 / 100.f - m0 * m0 + BN_EPS);
      float m1 = s1 / 100.f, r1 = rsqrtf(s21 / 100.f - m1 * m1 + BN_EPS);
#pragma unroll
      for (int mt = 0; mt < 7; ++mt)
#pragma unroll
        for (int q = 0; q < 4; ++q) {
          int row = mt * 16 + lg * 4 + q;
          h2[row * kH2S + wv * 32 + l15] = (_Float16)((a2[mt][0][q] - m0) * r0);
          h2[row * kH2S + wv * 32 + 16 + l15] = (_Float16)((a2[mt][1][q] - m1) * r1);
        }
    }
  }
  if (yb == 0) return;   // block-uniform exit (main phase-A done)

  __syncthreads();   // h2 complete; hT reads done -> hT2 region writable

  // ---- stage 3: GEMM2 (M=112 via wave=mt, N=128, K=256) -> hT2^T
  {
    for (int i = tid; i < 128 * 16; i += 512) {          // zero pad rows 112..127
      int c = i >> 4, j = 112 + (i & 15);
      hT2[c * kAhS + j] = (_Float16)0.f;
    }
    const int mt = wv;
    f32x4 a3[8];
#pragma unroll
    for (int nt = 0; nt < 8; ++nt) a3[nt] = (f32x4){0.f, 0.f, 0.f, 0.f};
    if (mt < 7) {
#pragma unroll
      for (int ks = 0; ks < 8; ++ks) {
        const int kb = ks * 32 + lg * 8;
        half8 aF = *(const half8*)&h2[(mt * 16 + l15) * kH2S + kb];
#pragma unroll
        for (int nt = 0; nt < 8; ++nt) {
          half8 bF = *(const half8*)&Wt2[((size_t)(ks * 4 + lg) * 128 + nt * 16 + l15) * 8];
          a3[nt] = __builtin_amdgcn_mfma_f32_16x16x32_f16(aF, bF, a3[nt], 0, 0, 0);
        }
      }
#pragma unroll
      for (int nt = 0; nt < 8; ++nt)
#pragma unroll
        for (int q = 0; q < 4; ++q) {
          int col = nt * 16 + l15;
          int j = mt * 16 + lg * 4 + q;
          hT2[col * kAhS + j] = (_Float16)a3[nt][q];
        }
    }
  }
  __syncthreads();

  // ---- stage 4: agg128 + bias + l2norm + mean-pool
  {
    const int mt = wv;
    f32x4 a4[8];
#pragma unroll
    for (int nt = 0; nt < 8; ++nt) a4[nt] = (f32x4){0.f, 0.f, 0.f, 0.f};
    if (mt < 7) {
#pragma unroll
      for (int ks = 0; ks < 4; ++ks) {
        const int kb = ks * 32 + lg * 8;
        half8 aF = *(const half8*)&Adh[(mt * 16 + l15) * kAhS + kb];
#pragma unroll
        for (int nt = 0; nt < 8; ++nt) {
          half8 bF = *(const half8*)&hT2[(nt * 16 + l15) * kAhS + kb];
          a4[nt] = __builtin_amdgcn_mfma_f32_16x16x32_f16(aF, bF, a4[nt], 0, 0, 0);
        }
      }
#pragma unroll
      for (int nt = 0; nt < 8; ++nt) {
        float bvn = b2[nt * 16 + l15];
#pragma unroll
        for (int q = 0; q < 4; ++q) a4[nt][q] += bvn;
      }
#pragma unroll
      for (int q = 0; q < 4; ++q) {
        float ss = 0.f;
#pragma unroll
        for (int nt = 0; nt < 8; ++nt) ss += a4[nt][q] * a4[nt][q];
        ss += __shfl_xor(ss, 1, 64); ss += __shfl_xor(ss, 2, 64);
        ss += __shfl_xor(ss, 4, 64); ss += __shfl_xor(ss, 8, 64);
        float inv = 1.f / fmaxf(sqrtf(ss), 1e-12f);
#pragma unroll
        for (int nt = 0; nt < 8; ++nt) a4[nt][q] *= inv;
      }
    }
    float ps[8];
#pragma unroll
    for (int nt = 0; nt < 8; ++nt) ps[nt] = 0.f;
    if (mt < 7) {
#pragma unroll
      for (int nt = 0; nt < 8; ++nt)
#pragma unroll
        for (int q = 0; q < 4; ++q) {
          int row = mt * 16 + lg * 4 + q;
          if (row < 100) ps[nt] += a4[nt][q];
        }
    }
#pragma unroll
    for (int nt = 0; nt < 8; ++nt) {
      ps[nt] += __shfl_xor(ps[nt], 16, 64);
      ps[nt] += __shfl_xor(ps[nt], 32, 64);
    }
    __syncthreads();                  // Adh dead -> scr
    if (mt < 7 && lg == 0)
#pragma unroll
      for (int nt = 0; nt < 8; ++nt) scr[wv * 128 + nt * 16 + l15] = ps[nt];
    __syncthreads();
    if (tid < 128) {
      float s = 0.f;
      for (int w2 = 0; w2 < 7; ++w2) s += scr[w2 * 128 + tid];
      float* OP = (yb == 1) ? OP1 : OP2;
      OP[(size_t)g * 128 + tid] = s / 100.f;
    }
  }
}

// ================= phase-2 fused encoder (main): hB -> BN -> GEMM2 -> agg128 =================
__global__ __launch_bounds__(512)
void enc2_k(const _Float16* __restrict__ hB, const float* __restrict__ tr,
            const _Float16* __restrict__ Wt2, const float* __restrict__ b2,
            const int* __restrict__ srcI, const int* __restrict__ dstI,
            const float* __restrict__ NOI,
            float* __restrict__ OZ, _Float16* __restrict__ Z16,
            float* __restrict__ ZG, float* __restrict__ ZZ)
{
  extern __shared__ __align__(16) char lds_c[];
  _Float16* Adh = (_Float16*)lds_c;                 // [112][136]
  _Float16* hT2 = (_Float16*)(lds_c + 30464);       // [128][136]
  unsigned* cnt32 = (unsigned*)(lds_c + 30464);     // overlay (build only)
  float* scr = (float*)lds_c;                       // overlay (epilogue)
  __shared__ int scnt[kNPG];
  __shared__ float sdinv[kNPG];
  const int g = blockIdx.x, tid = threadIdx.x;
  const int base = g * kNPG;
  const size_t ebase = (size_t)g * kEPG;
  const int lane = tid & 63, wv = tid >> 6;
  const int l15 = lane & 15, lg = lane >> 4;

  for (int i = tid; i < 112 * kCntW; i += 512) cnt32[i] = 0u;
  if (tid < kNPG) scnt[tid] = 0;
  __syncthreads();
  for (int e = tid; e < kEPG; e += 512) {
    int s = srcI[ebase + e] - base;
    int d = dstI[ebase + e] - base;
    atomicAdd(&scnt[d], 1);
    atomicAdd(&cnt32[d * kCntW + (s >> 2)], 1u << (8 * (s & 3)));
  }
  __syncthreads();
  if (tid < kNPG) sdinv[tid] = rsqrtf((float)scnt[tid] + 1.f);
  __syncthreads();
  for (int i = tid; i < 112 * kAhS; i += 512) {
    int d = i / kAhS, s = i - d * kAhS;
    float v = 0.f;
    if (d < 100 && s < 100) {
      unsigned w = cnt32[d * kCntW + (s >> 2)];
      unsigned c = (w >> (8 * (s & 3))) & 0xFFu;
      c += (s == d) ? 1u : 0u;
      v = (float)c * sdinv[s] * sdinv[d];
    }
    Adh[i] = (_Float16)v;
  }
  __syncthreads();   // cnt dead -> hT2 writable

  {
    const int mt = wv;
    const int r = min(base + mt * 16 + l15, kN - 1);
    f32x4 a3[8];
#pragma unroll
    for (int nt = 0; nt < 8; ++nt) a3[nt] = (f32x4){0.f, 0.f, 0.f, 0.f};
#pragma unroll
    for (int ks = 0; ks < 8; ++ks) {
      const int kb = ks * 32 + lg * 8;
      half8 h = *(const half8*)&hB[(size_t)r * 256 + kb];
      half8 aF;
#pragma unroll
      for (int j = 0; j < 8; ++j)
        aF[j] = (_Float16)(((float)h[j] - tr[kb + j]) * tr[256 + kb + j]);
#pragma unroll
      for (int nt = 0; nt < 8; ++nt) {
        half8 bF = *(const half8*)&Wt2[((size_t)(ks * 4 + lg) * 128 + nt * 16 + l15) * 8];
        a3[nt] = __builtin_amdgcn_mfma_f32_16x16x32_f16(aF, bF, a3[nt], 0, 0, 0);
      }
    }
#pragma unroll
    for (int nt = 0; nt < 8; ++nt)
#pragma unroll
      for (int q = 0; q < 4; ++q) {
        int col = nt * 16 + l15;
        int j = mt * 16 + lg * 4 + q;
        hT2[col * kAhS + j] = (_Float16)a3[nt][q];
      }
  }
  __syncthreads();

  {
    const int mt = wv;
    f32x4 a4[8];
#pragma unroll
    for (int nt = 0; nt < 8; ++nt) a4[nt] = (f32x4){0.f, 0.f, 0.f, 0.f};
    if (mt < 7) {
#pragma unroll
      for (int ks = 0; ks < 4; ++ks) {
        const int kb = ks * 32 + lg * 8;
        half8 aF = *(const half8*)&Adh[(mt * 16 + l15) * kAhS + kb];
#pragma unroll
        for (int nt = 0; nt < 8; ++nt) {
          half8 bF = *(const half8*)&hT2[(nt * 16 + l15) * kAhS + kb];
          a4[nt] = __builtin_amdgcn_mfma_f32_16x16x32_f16(aF, bF, a4[nt], 0, 0, 0);
        }
      }
#pragma unroll
      for (int nt = 0; nt < 8; ++nt) {
        float bvn = b2[nt * 16 + l15];
#pragma unroll
        for (int q = 0; q < 4; ++q) a4[nt][q] += bvn;
      }
#pragma unroll
      for (int q = 0; q < 4; ++q) {
        float ss = 0.f;
#pragma unroll
        for (int nt = 0; nt < 8; ++nt) ss += a4[nt][q] * a4[nt][q];
        ss += __shfl_xor(ss, 1, 64); ss += __shfl_xor(ss, 2, 64);
        ss += __shfl_xor(ss, 4, 64); ss += __shfl_xor(ss, 8, 64);
        float inv = 1.f / fmaxf(sqrtf(ss), 1e-12f);
#pragma unroll
        for (int nt = 0; nt < 8; ++nt) a4[nt][q] *= inv;
      }
#pragma unroll
      for (int nt = 0; nt < 8; ++nt)
#pragma unroll
        for (int q = 0; q < 4; ++q) {
          int row = mt * 16 + lg * 4 + q;
          if (row < 100) {
            OZ[(size_t)(base + row) * 128 + nt * 16 + l15] = a4[nt][q];
            Z16[(size_t)(base + row) * 128 + nt * 16 + l15] = (_Float16)a4[nt][q];
          }
        }
    }
    float m1[8], m2[8];
#pragma unroll
    for (int nt = 0; nt < 8; ++nt) { m1[nt] = -INFINITY; m2[nt] = -INFINITY; }
    if (mt < 7) {
#pragma unroll
      for (int nt = 0; nt < 8; ++nt)
#pragma unroll
        for (int q = 0; q < 4; ++q) {
          int row = mt * 16 + lg * 4 + q;
          if (row < 100) {
            float zv = a4[nt][q];
            float nv = NOI[(size_t)(base + row) * 128 + nt * 16 + l15];
            m1[nt] = fmaxf(m1[nt], zv);
            m2[nt] = fmaxf(m2[nt], zv + nv);
          }
        }
#pragma unroll
      for (int nt = 0; nt < 8; ++nt) {
        m1[nt] = fmaxf(m1[nt], __shfl_xor(m1[nt], 16, 64));
        m1[nt] = fmaxf(m1[nt], __shfl_xor(m1[nt], 32, 64));
        m2[nt] = fmaxf(m2[nt], __shfl_xor(m2[nt], 16, 64));
        m2[nt] = fmaxf(m2[nt], __shfl_xor(m2[nt], 32, 64));
      }
    }
    __syncthreads();                  // Adh dead -> scr
    if (mt < 7 && lg == 0)
#pragma unroll
      for (int nt = 0; nt < 8; ++nt) {
        scr[wv * 128 + nt * 16 + l15] = m1[nt];
        scr[1024 + wv * 128 + nt * 16 + l15] = m2[nt];
      }
    __syncthreads();
    if (tid < 128) {
      float a = -INFINITY, b = -INFINITY;
      for (int w2 = 0; w2 < 7; ++w2) {
        a = fmaxf(a, scr[w2 * 128 + tid]);
        b = fmaxf(b, scr[1024 + w2 * 128 + tid]);
      }
      ZG[(size_t)g * 128 + tid] = a;
      ZZ[(size_t)g * 128 + tid] = a;
      ZZ[(size_t)(500 + g) * 128 + tid] = b;
    }
  }
}

// ================= fused decoder: o_xr = sigmoid(relu(z16@W1)@W2) =================
__global__ __launch_bounds__(512)
void dec_fused_k(const _Float16* __restrict__ Z, const _Float16* __restrict__ Wt1,
                 const _Float16* __restrict__ Wt2, float* __restrict__ XR, int M)
{
  __shared__ alignas(16) _Float16 Hrm[64][264];
  const int tid = threadIdx.x;
  const int lane = tid & 63;
  const int l15 = lane & 15, lg = lane >> 4;
  const int wave = tid >> 6;
  const int wm = wave >> 2;
  const int wn = wave & 3;
  const int bm = blockIdx.x * 64;

  f32x4 acc[2][4];
#pragma unroll
  for (int m = 0; m < 2; ++m)
#pragma unroll
    for (int n = 0; n < 4; ++n) acc[m][n] = (f32x4){0.f, 0.f, 0.f, 0.f};
  int arow[2];
#pragma unroll
  for (int m = 0; m < 2; ++m)
    arow[m] = min(bm + wm * 32 + m * 16 + l15, M - 1);
  const int bcol = wn * 64 + l15;
#pragma unroll
  for (int ks = 0; ks < 4; ++ks) {
    const int kb = ks * 32 + lg * 8;
    half8 bF[4];
#pragma unroll
    for (int n = 0; n < 4; ++n)
      bF[n] = *(const half8*)&Wt1[((size_t)(ks * 4 + lg) * 256 + bcol + n * 16) * 8];
    half8 aF[2];
#pragma unroll
    for (int m = 0; m < 2; ++m)
      aF[m] = *(const half8*)&Z[(size_t)arow[m] * 128 + kb];
#pragma unroll
    for (int m = 0; m < 2; ++m)
#pragma unroll
      for (int n = 0; n < 4; ++n)
        acc[m][n] = __builtin_amdgcn_mfma_f32_16x16x32_f16(aF[m], bF[n], acc[m][n], 0, 0, 0);
  }
#pragma unroll
  for (int m = 0; m < 2; ++m)
#pragma unroll
    for (int q = 0; q < 4; ++q) {
      int lrow = wm * 32 + m * 16 + lg * 4 + q;
#pragma unroll
      for (int n = 0; n < 4; ++n)
        Hrm[lrow][wn * 64 + n * 16 + l15] = (_Float16)fmaxf(acc[m][n][q], 0.f);
    }
  __syncthreads();

  const int wm2 = wave & 1, wn2 = wave >> 1;
  f32x4 acc2[2][2];
#pragma unroll
  for (int m = 0; m < 2; ++m)
#pragma unroll
    for (int n = 0; n < 2; ++n) acc2[m][n] = (f32x4){0.f, 0.f, 0.f, 0.f};
#pragma unroll
  for (int ks = 0; ks < 8; ++ks) {
    const int kb = ks * 32 + lg * 8;
    half8 aF[2];
#pragma unroll
    for (int m = 0; m < 2; ++m)
      aF[m] = *(const half8*)&Hrm[wm2 * 32 + m * 16 + l15][kb];
    half8 bF[2];
#pragma unroll
    for (int n = 0; n < 2; ++n)
      bF[n] = *(const half8*)&Wt2[((size_t)(ks * 4 + lg) * 128 + wn2 * 32 + n * 16 + l15) * 8];
#pragma unroll
    for (int m = 0; m < 2; ++m)
#pragma unroll
      for (int n = 0; n < 2; ++n)
        acc2[m][n] = __builtin_amdgcn_mfma_f32_16x16x32_f16(aF[m], bF[n], acc2[m][n], 0, 0, 0);
  }
#pragma unroll
  for (int m = 0; m < 2; ++m)
#pragma unroll
    for (int q = 0; q < 4; ++q) {
      int row = bm + wm2 * 32 + m * 16 + lg * 4 + q;
      if (row >= M) continue;
#pragma unroll
      for (int n = 0; n < 2; ++n) {
        float v = acc2[m][n][q];
        XR[(size_t)row * 128 + wn2 * 32 + n * 16 + l15] = 1.f / (1.f + expf(-v));
      }
    }
}

// ======================= small-M tiled f32 GEMM (M<=1000 paths) =======================
template<int ACT>
__global__ __launch_bounds__(256)
void gemm_k(const float* __restrict__ A, const float* __restrict__ W,
            const float* __restrict__ bias, float* __restrict__ C,
            int M, int K, int Nc)
{
  __shared__ float As[32][136];
  __shared__ float Ws[32][68];
  const int tid = threadIdx.x;
  const int bm = blockIdx.x * 128;
  const int bn = blockIdx.y * 64;
  const int tm = (tid & 15) * 8;
  const int tn = (tid >> 4) * 4;
  float acc[8][4];
#pragma unroll
  for (int i = 0; i < 8; ++i)
#pragma unroll
    for (int j = 0; j < 4; ++j) acc[i][j] = 0.f;

  for (int k0 = 0; k0 < K; k0 += 32) {
#pragma unroll
    for (int l = 0; l < 4; ++l) {
      int idx = tid + l * 256;
      int r = idx >> 3;
      int kq = (idx & 7) << 2;
      int gr = bm + r;
      float4 v = make_float4(0.f, 0.f, 0.f, 0.f);
      if (gr < M) v = *(const float4*)&A[(size_t)gr * K + k0 + kq];
      As[kq + 0][r] = v.x; As[kq + 1][r] = v.y;
      As[kq + 2][r] = v.z; As[kq + 3][r] = v.w;
    }
#pragma unroll
    for (int l = 0; l < 2; ++l) {
      int idx = tid + l * 256;
      int r = idx >> 4;
      int nq = (idx & 15) << 2;
      *(float4*)&Ws[r][nq] = *(const float4*)&W[(size_t)(k0 + r) * Nc + bn + nq];
    }
    __syncthreads();
#pragma unroll
    for (int kk = 0; kk < 32; ++kk) {
      float4 a0 = *(float4*)&As[kk][tm];
      float4 a1 = *(float4*)&As[kk][tm + 4];
      float4 w4 = *(float4*)&Ws[kk][tn];
      float am[8] = {a0.x, a0.y, a0.z, a0.w, a1.x, a1.y, a1.z, a1.w};
      float wn4[4] = {w4.x, w4.y, w4.z, w4.w};
#pragma unroll
      for (int i = 0; i < 8; ++i)
#pragma unroll
        for (int j = 0; j < 4; ++j) acc[i][j] += am[i] * wn4[j];
    }
    __syncthreads();
  }
  float4 bv = make_float4(0.f, 0.f, 0.f, 0.f);
  if (bias) bv = *(const float4*)&bias[bn + tn];
#pragma unroll
  for (int i = 0; i < 8; ++i) {
    int row = bm + tm + i;
    if (row >= M) break;
    float o0 = acc[i][0] + bv.x, o1 = acc[i][1] + bv.y;
    float o2 = acc[i][2] + bv.z, o3 = acc[i][3] + bv.w;
    if (ACT == 1) {
      o0 = fmaxf(o0, 0.f); o1 = fmaxf(o1, 0.f);
      o2 = fmaxf(o2, 0.f); o3 = fmaxf(o3, 0.f);
    } else if (ACT == 2) {
      o0 = 1.f / (1.f + expf(-o0)); o1 = 1.f / (1.f + expf(-o1));
      o2 = 1.f / (1.f + expf(-o2)); o3 = 1.f / (1.f + expf(-o3));
    }
    *(float4*)&C[(size_t)row * Nc + bn + tn] = make_float4(o0, o1, o2, o3);
  }
}

// ============ BN finalize: sum 500 per-graph partials (fixed order) ============
__global__ __launch_bounds__(256)
void bn_red_k(const float* __restrict__ P, float* __restrict__ stats)
{
  const int c = threadIdx.x;
  float s = 0.f, s2 = 0.f;
  for (int b = 0; b < 500; ++b) {
    s  += P[(size_t)b * 512 + c];
    s2 += P[(size_t)b * 512 + 256 + c];
  }
  float m = s / (float)kN;
  float v = s2 / (float)kN - m * m;
  stats[512 + c] = m;
  stats[768 + c] = rsqrtf(v + BN_EPS);
}

__global__ __launch_bounds__(64)
void bn_cols_k(float* __restrict__ X, int rows, int cols)
{
  const int c = blockIdx.x, t = threadIdx.x;
  float s = 0.f, s2 = 0.f;
  for (int r = t; r < rows; r += 64) {
    float v = X[(size_t)r * cols + c];
    s += v; s2 += v * v;
  }
#pragma unroll
  for (int o = 32; o; o >>= 1) { s += __shfl_xor(s, o, 64); s2 += __shfl_xor(s2, o, 64); }
  float m = s / (float)rows;
  float var = s2 / (float)rows - m * m;
  float rinv = rsqrtf(var + BN_EPS);
  for (int r = t; r < rows; r += 64)
    X[(size_t)r * cols + c] = (X[(size_t)r * cols + c] - m) * rinv;
}

__global__ __launch_bounds__(256)
void l2n_k(const float* __restrict__ X, float* __restrict__ Y, int rows)
{
  const int w = threadIdx.x >> 6, lane = threadIdx.x & 63;
  const int row = blockIdx.x * 4 + w;
  if (row >= rows) return;
  float2 v = *(const float2*)&X[(size_t)row * kH2 + lane * 2];
  float ss = v.x * v.x + v.y * v.y;
#pragma unroll
  for (int o = 32; o; o >>= 1) ss += __shfl_xor(ss, o, 64);
  float inv = 1.f / fmaxf(sqrtf(ss), 1e-12f);
  *(float2*)&Y[(size_t)row * kH2 + lane * 2] = make_float2(v.x * inv, v.y * inv);
}

// =========================================================================
extern "C" void kernel_launch(void* const* d_in, const int* in_sizes, int n_in,
                              void* d_out, int out_size, void* d_ws, size_t ws_size,
                              hipStream_t stream)
{
  const float* x        = (const float*)d_in[0];
  const int*   srcI     = (const int*)d_in[1];
  const int*   dstI     = (const int*)d_in[2];
  const float* pos_x    = (const float*)d_in[4];
  const int*   psrc     = (const int*)d_in[5];
  const int*   pdst     = (const int*)d_in[6];
  const float* neg_x    = (const float*)d_in[8];
  const int*   nsrc     = (const int*)d_in[9];
  const int*   ndst     = (const int*)d_in[10];
  const float* target_x = (const float*)d_in[12];
  const float* noise    = (const float*)d_in[13];
  const float* W_enc1   = (const float*)d_in[14];
  const float* b_enc1   = (const float*)d_in[15];
  const float* W_enc2   = (const float*)d_in[16];
  const float* b_enc2   = (const float*)d_in[17];
  const float* W_dec1   = (const float*)d_in[18];
  const float* W_dec2   = (const float*)d_in[19];
  const float* Wn1      = (const float*)d_in[20];
  const float* bn1      = (const float*)d_in[21];
  const float* Wn2      = (const float*)d_in[22];
  const float* bn2      = (const float*)d_in[23];
  const float* Ws1      = (const float*)d_in[24];
  const float* bs1      = (const float*)d_in[25];
  const float* Wp1      = (const float*)d_in[26];
  const float* bp1      = (const float*)d_in[27];
  const float* Wp2      = (const float*)d_in[28];
  const float* bp2      = (const float*)d_in[29];

  float* out  = (float*)d_out;
  float* o_z   = out;                 // N x 128
  float* o_zg  = out + 6400000;       // 500 x 128
  float* o_xr  = out + 6464000;       // N x 128
  float* o_pos = out + 12864000;      // 500 x 128
  float* o_neg = out + 12928000;
  float* o_zgm = out + 12992000;      // o_zgm||o_zpm contiguous 1000 x 128
  float* o_tz  = out + 13120000;

  // WORKSPACE MAP (float offsets; r2-r4 audit per launch):
  //  hB  [0, 6.4M):        fp16 N x 256 (enc1 y0 -> enc2)
  //  pstat 6.4M (256000);  t1 6.4M / t2 6.7M (target-time, pstat dead)
  //  x16m 8.0M / x16p 11.2M / x16n 14.4M: fp16 N x 128 each (xprep -> enc1)
  //  z16 [19.2M, 22.4M):   fp16 N x 128 (enc2 -> dec)
  //  zz 22.4M; t1000 22.6M; hWt 25.6M; stats 25.7M.
  float* ws = (float*)d_ws;
  _Float16* hB  = (_Float16*)ws;
  float* pstat  = ws + 6400000;
  _Float16* x16m = (_Float16*)(ws + 8000000);
  _Float16* x16p = (_Float16*)(ws + 11200000);
  _Float16* x16n = (_Float16*)(ws + 14400000);
  _Float16* z16 = (_Float16*)(ws + 19200000);
  float* zz    = ws + 22400000;
  float* t1000 = ws + 22600000;
  float* t1    = ws + 6400000;        // target-time (pstat dead)
  float* t2    = ws + 6700000;
  _Float16* hWt = (_Float16*)(ws + 25600000);
  float* stats = ws + 25700000;
  if (ws_size < (size_t)(25921024) * sizeof(float)) return;

  _Float16* WtEnc1 = hWt;
  _Float16* WtEnc2 = hWt + 32768;
  _Float16* WtDec1 = hWt + 65536;
  _Float16* WtDec2 = hWt + 98304;
  _Float16* WtS1   = hWt + 131072;

  (void)hipFuncSetAttribute((const void*)enc1_k,
      hipFuncAttributeMaxDynamicSharedMemorySize, kLds1);
  (void)hipFuncSetAttribute((const void*)enc2_k,
      hipFuncAttributeMaxDynamicSharedMemorySize, kLds2);

  auto gg = [](int M, int Nc) {
    return dim3((unsigned)((M + 127) / 128), (unsigned)(Nc / 64), 1);
  };

  // 1. weight + x prep
  wprep_k<<<640, 256, 0, stream>>>(W_enc1, W_enc2, W_dec1, W_dec2, Ws1, hWt);
  xprep_k<<<9375, 256, 0, stream>>>(x, pos_x, neg_x, x16m, x16p, x16n);

  // 2. phase-1 fused encoder: main(y0) -> hB+pstat; pos/neg(y1,2) -> o_pos/o_neg
  enc1_k<<<dim3(kB, 3), 512, kLds1, stream>>>(
      x16m, x16p, x16n, srcI, psrc, nsrc, dstI, pdst, ndst,
      WtEnc1, WtS1, WtEnc2, b_enc1, bs1, b_enc2,
      hB, pstat, o_pos, o_neg);

  // 3. BN finalize
  bn_red_k<<<1, 256, 0, stream>>>(pstat, stats);

  // 4. phase-2 fused encoder (main): hB -> o_z, z16, o_zg, zz
  enc2_k<<<kB, 512, kLds2, stream>>>(
      hB, stats + 512, WtEnc2, b_enc2, srcI, dstI, noise, o_z, z16, o_zg, zz);

  // 5. fused decoder: z16 -> o_xr
  dec_fused_k<<<782, 512, 0, stream>>>(z16, WtDec1, WtDec2, o_xr, kN);

  // 6-7. merged projection heads
  gemm_k<1><<<gg(1000, kH2), 256, 0, stream>>>(zz, Wp1, bp1, t1000, 1000, kH2, kH2);
  gemm_k<0><<<gg(1000, kH2), 256, 0, stream>>>(t1000, Wp2, bp2, o_zgm, 1000, kH2, kH2);

  // 8-11. target node encoder
  gemm_k<1><<<gg(kB, kH1), 256, 0, stream>>>(target_x, Wn1, bn1, t1, kB, kF0, kH1);
  bn_cols_k<<<256, 64, 0, stream>>>(t1, kB, kH1);
  gemm_k<0><<<gg(kB, kH2), 256, 0, stream>>>(t1, Wn2, bn2, t2, kB, kH1, kH2);
  l2n_k<<<125, 256, 0, stream>>>(t2, o_tz, kB);

  (void)in_sizes; (void)n_in; (void)out_size;
}

// Round 23
// 323.666 us; speedup vs baseline: 1.3950x; 1.0165x over previous
//
#include <hip/hip_runtime.h>
#include <math.h>

static constexpr int kN   = 50000;
static constexpr int kB   = 500;
static constexpr int kNPG = 100;
static constexpr int kEPG = 1600;
static constexpr int kESG = 800;
static constexpr int kF0  = 128;
static constexpr int kH1  = 256;
static constexpr int kH2  = 128;
#define BN_EPS 1e-5f

typedef _Float16 half8 __attribute__((ext_vector_type(8)));
typedef __attribute__((ext_vector_type(4))) float f32x4;

static constexpr int kCntW = 33;
static constexpr int kAhS  = 136;     // Adh / hT / hT2 stride (fp16)
static constexpr int kH2S  = 264;     // h2 stride (fp16)
static constexpr int kCntN = 112 * kCntW;   // 3696 u32 per graph
// enc1 LDS (bytes): Adh[112][136] @0 (30464) | hT[256][136] @30464 (69632)
//  | h2[112][264] @100096 (59136). cnt32 overlays hT pre-GEMM1; hT2[128][136]
//  overlays hT post-agg256; scr overlays Adh post-agg128. Total 159232.
static constexpr unsigned kLds1 = 159232;
// enc2 LDS: Adh 30464 | hT2[128][136] @30464 (34816) (cnt overlays hT2). 65280.
static constexpr unsigned kLds2 = 65280;

// ============ combined prep: weights -> Wt fp16 layout; x/pos/neg -> fp16 ============
__global__ __launch_bounds__(256)
void prep_k(const float* __restrict__ s0, const float* __restrict__ s1,
            const float* __restrict__ s2, const float* __restrict__ s3,
            const float* __restrict__ s4, _Float16* __restrict__ dW,
            const float* __restrict__ x0, const float* __restrict__ x1,
            const float* __restrict__ x2, _Float16* __restrict__ d0,
            _Float16* __restrict__ d1, _Float16* __restrict__ d2)
{
  if (blockIdx.x < 640) {
    int seg = blockIdx.x >> 7;
    int idx = (blockIdx.x & 127) * 256 + threadIdx.x;
    const float* S; int Nc;
    switch (seg) {
      case 0: S = s0; Nc = 256; break;
      case 1: S = s1; Nc = 128; break;
      case 2: S = s2; Nc = 256; break;
      case 3: S = s3; Nc = 128; break;
      default: S = s4; Nc = 256; break;
    }
    int e = idx & 7, t = idx >> 3;
    int c = t % Nc, kg = t / Nc;
    dW[seg * 32768 + idx] = (_Float16)S[(size_t)(kg * 8 + e) * Nc + c];
  } else {
    const size_t idx = (size_t)(blockIdx.x - 640) * 256 + threadIdx.x;  // 2.4M
    const size_t per = (size_t)kN * 16;
    const int seg = (int)(idx / per);
    const size_t off = (idx - (size_t)seg * per) * 8;
    const float* S = (seg == 0) ? x0 : (seg == 1) ? x1 : x2;
    _Float16* D = (seg == 0) ? d0 : (seg == 1) ? d1 : d2;
    float4 u0 = *(const float4*)&S[off];
    float4 u1 = *(const float4*)&S[off + 4];
    half8 h;
    h[0] = (_Float16)u0.x; h[1] = (_Float16)u0.y;
    h[2] = (_Float16)u0.z; h[3] = (_Float16)u0.w;
    h[4] = (_Float16)u1.x; h[5] = (_Float16)u1.y;
    h[6] = (_Float16)u1.z; h[7] = (_Float16)u1.w;
    *(half8*)&D[off] = h;
  }
}

// ================= phase-1 fused encoder (per-graph blocks) =================
// blockIdx.y: 0=main (GEMM1+agg256+STATS -> hB global; also dumps cnt/scnt to
// CNTG/SCG for enc2 reuse), 1=pos, 2=neg (full chain -> mean-pool OP).
__global__ __launch_bounds__(512)
void enc1_k(const _Float16* __restrict__ x0, const _Float16* __restrict__ x1,
            const _Float16* __restrict__ x2,
            const int* __restrict__ src0, const int* __restrict__ src1,
            const int* __restrict__ src2,
            const int* __restrict__ dst0, const int* __restrict__ dst1,
            const int* __restrict__ dst2,
            const _Float16* __restrict__ Wt1m, const _Float16* __restrict__ Wt1s,
            const _Float16* __restrict__ Wt2,
            const float* __restrict__ b1m, const float* __restrict__ b1s,
            const float* __restrict__ b2,
            _Float16* __restrict__ hB, float* __restrict__ PST,
            float* __restrict__ OP1, float* __restrict__ OP2,
            unsigned* __restrict__ CNTG, int* __restrict__ SCG)
{
  extern __shared__ __align__(16) char lds_c[];
  _Float16* Adh = (_Float16*)lds_c;                 // [112][136]
  _Float16* hT  = (_Float16*)(lds_c + 30464);       // [256][136]
  _Float16* h2  = (_Float16*)(lds_c + 100096);      // [112][264]
  unsigned* cnt32 = (unsigned*)(lds_c + 30464);     // overlay (build only)
  _Float16* hT2 = (_Float16*)(lds_c + 30464);       // overlay (stage 3+)
  float* scr = (float*)lds_c;                       // overlay (pool epilogue)
  __shared__ int scnt[kNPG];
  __shared__ float sdinv[kNPG];
  const int yb = blockIdx.y;
  const _Float16* X = (yb == 0) ? x0 : (yb == 1) ? x1 : x2;
  const int* srcI = (yb == 0) ? src0 : (yb == 1) ? src1 : src2;
  const int* dstI = (yb == 0) ? dst0 : (yb == 1) ? dst1 : dst2;
  const _Float16* W1 = (yb == 0) ? Wt1m : Wt1s;
  const float* bias1 = (yb == 0) ? b1m : b1s;
  const int epg = (yb == 0) ? kEPG : kESG;
  const int g = blockIdx.x, tid = threadIdx.x;
  const int base = g * kNPG;
  const size_t ebase = (size_t)g * epg;
  const int lane = tid & 63, wv = tid >> 6;
  const int l15 = lane & 15, lg = lane >> 4;

  // ---- build adjacency (deterministic integer counts)
  for (int i = tid; i < kCntN; i += 512) cnt32[i] = 0u;
  if (tid < kNPG) scnt[tid] = 0;
  __syncthreads();
  for (int e = tid; e < epg; e += 512) {
    int s = srcI[ebase + e] - base;
    int d = dstI[ebase + e] - base;
    atomicAdd(&scnt[d], 1);
    atomicAdd(&cnt32[d * kCntW + (s >> 2)], 1u << (8 * (s & 3)));
  }
  __syncthreads();
  if (tid < kNPG) sdinv[tid] = rsqrtf((float)scnt[tid] + 1.f);
  __syncthreads();
  if (yb == 0) {   // dump counts for enc2 reuse (cnt32 still live here)
    for (int i = tid; i < kCntN; i += 512) CNTG[(size_t)g * 3712 + i] = cnt32[i];
    if (tid < kNPG) SCG[g * 128 + tid] = scnt[tid];
  }
  for (int i = tid; i < 112 * kAhS; i += 512) {
    int d = i / kAhS, s = i - d * kAhS;
    float v = 0.f;
    if (d < 100 && s < 100) {
      unsigned w = cnt32[d * kCntW + (s >> 2)];
      unsigned c = (w >> (8 * (s & 3))) & 0xFFu;
      c += (s == d) ? 1u : 0u;
      v = (float)c * sdinv[s] * sdinv[d];
    }
    Adh[i] = (_Float16)v;
  }
  __syncthreads();   // cnt dead; hT region writable

  // ---- stage 1: GEMM1 (M=128 rows incl clamp-junk, N=256, K=128) -> hT^T
  {
    f32x4 a1[8][2];
#pragma unroll
    for (int mt = 0; mt < 8; ++mt) {
      a1[mt][0] = (f32x4){0.f, 0.f, 0.f, 0.f};
      a1[mt][1] = (f32x4){0.f, 0.f, 0.f, 0.f};
    }
    int rows[8];
#pragma unroll
    for (int mt = 0; mt < 8; ++mt) rows[mt] = min(base + mt * 16 + l15, kN - 1);
    const int bc0 = wv * 32 + l15;
#pragma unroll
    for (int ks = 0; ks < 4; ++ks) {
      const int kb = ks * 32 + lg * 8;
      half8 bF[2];
#pragma unroll
      for (int t = 0; t < 2; ++t)
        bF[t] = *(const half8*)&W1[((size_t)(ks * 4 + lg) * 256 + bc0 + t * 16) * 8];
#pragma unroll
      for (int mt = 0; mt < 8; ++mt) {
        half8 aF = *(const half8*)&X[(size_t)rows[mt] * 128 + kb];
#pragma unroll
        for (int t = 0; t < 2; ++t)
          a1[mt][t] = __builtin_amdgcn_mfma_f32_16x16x32_f16(aF, bF[t], a1[mt][t], 0, 0, 0);
      }
    }
#pragma unroll
    for (int mt = 0; mt < 8; ++mt)
#pragma unroll
      for (int t = 0; t < 2; ++t)
#pragma unroll
        for (int q = 0; q < 4; ++q) {
          int col = wv * 32 + t * 16 + l15;
          int j = mt * 16 + lg * 4 + q;
          hT[col * kAhS + j] = (_Float16)a1[mt][t][q];
        }
  }
  __syncthreads();

  // ---- stage 2: agg256 (M=112, cols wv*32..+31) + bias + relu + stats/segBN
  {
    f32x4 a2[7][2];
#pragma unroll
    for (int mt = 0; mt < 7; ++mt) {
      a2[mt][0] = (f32x4){0.f, 0.f, 0.f, 0.f};
      a2[mt][1] = (f32x4){0.f, 0.f, 0.f, 0.f};
    }
#pragma unroll
    for (int ks = 0; ks < 4; ++ks) {
      const int kb = ks * 32 + lg * 8;
      half8 bF[2];
#pragma unroll
      for (int t = 0; t < 2; ++t)
        bF[t] = *(const half8*)&hT[(wv * 32 + t * 16 + l15) * kAhS + kb];
#pragma unroll
      for (int mt = 0; mt < 7; ++mt) {
        half8 aF = *(const half8*)&Adh[(mt * 16 + l15) * kAhS + kb];
        a2[mt][0] = __builtin_amdgcn_mfma_f32_16x16x32_f16(aF, bF[0], a2[mt][0], 0, 0, 0);
        a2[mt][1] = __builtin_amdgcn_mfma_f32_16x16x32_f16(aF, bF[1], a2[mt][1], 0, 0, 0);
      }
    }
    float bv0 = bias1[wv * 32 + l15];
    float bv1 = bias1[wv * 32 + 16 + l15];
#pragma unroll
    for (int mt = 0; mt < 7; ++mt)
#pragma unroll
      for (int q = 0; q < 4; ++q) {
        a2[mt][0][q] = fmaxf(a2[mt][0][q] + bv0, 0.f);
        a2[mt][1][q] = fmaxf(a2[mt][1][q] + bv1, 0.f);
      }
    float s0 = 0.f, s20 = 0.f, s1 = 0.f, s21 = 0.f;
#pragma unroll
    for (int mt = 0; mt < 7; ++mt)
#pragma unroll
      for (int q = 0; q < 4; ++q) {
        int row = mt * 16 + lg * 4 + q;
        if (row < 100) {
          float v0 = a2[mt][0][q], v1 = a2[mt][1][q];
          s0 += v0; s20 += v0 * v0; s1 += v1; s21 += v1 * v1;
        }
      }
    s0 += __shfl_xor(s0, 16, 64);  s0 += __shfl_xor(s0, 32, 64);
    s20 += __shfl_xor(s20, 16, 64); s20 += __shfl_xor(s20, 32, 64);
    s1 += __shfl_xor(s1, 16, 64);  s1 += __shfl_xor(s1, 32, 64);
    s21 += __shfl_xor(s21, 16, 64); s21 += __shfl_xor(s21, 32, 64);
    if (yb == 0) {
      if (lg == 0) {
        PST[(size_t)g * 512 + wv * 32 + l15] = s0;
        PST[(size_t)g * 512 + 256 + wv * 32 + l15] = s20;
        PST[(size_t)g * 512 + wv * 32 + 16 + l15] = s1;
        PST[(size_t)g * 512 + 256 + wv * 32 + 16 + l15] = s21;
      }
#pragma unroll
      for (int mt = 0; mt < 7; ++mt)
#pragma unroll
        for (int q = 0; q < 4; ++q) {
          int row = mt * 16 + lg * 4 + q;
          if (row < 100) {
            hB[(size_t)(base + row) * 256 + wv * 32 + l15] = (_Float16)a2[mt][0][q];
            hB[(size_t)(base + row) * 256 + wv * 32 + 16 + l15] = (_Float16)a2[mt][1][q];
          }
        }
    } else {
      float m0 = s0 / 100.f, r0 = rsqrtf(s20 / 100.f - m0 * m0 + BN_EPS);
      float m1 = s1 / 100.f, r1 = rsqrtf(s21 / 100.f - m1 * m1 + BN_EPS);
#pragma unroll
      for (int mt = 0; mt < 7; ++mt)
#pragma unroll
        for (int q = 0; q < 4; ++q) {
          int row = mt * 16 + lg * 4 + q;
          h2[row * kH2S + wv * 32 + l15] = (_Float16)((a2[mt][0][q] - m0) * r0);
          h2[row * kH2S + wv * 32 + 16 + l15] = (_Float16)((a2[mt][1][q] - m1) * r1);
        }
    }
  }
  if (yb == 0) return;   // block-uniform exit (main phase-A done)

  __syncthreads();   // h2 complete; hT reads done -> hT2 region writable

  // ---- stage 3: GEMM2 (M=112 via wave=mt, N=128, K=256) -> hT2^T
  {
    for (int i = tid; i < 128 * 16; i += 512) {          // zero pad rows 112..127
      int c = i >> 4, j = 112 + (i & 15);
      hT2[c * kAhS + j] = (_Float16)0.f;
    }
    const int mt = wv;
    f32x4 a3[8];
#pragma unroll
    for (int nt = 0; nt < 8; ++nt) a3[nt] = (f32x4){0.f, 0.f, 0.f, 0.f};
    if (mt < 7) {
#pragma unroll
      for (int ks = 0; ks < 8; ++ks) {
        const int kb = ks * 32 + lg * 8;
        half8 aF = *(const half8*)&h2[(mt * 16 + l15) * kH2S + kb];
#pragma unroll
        for (int nt = 0; nt < 8; ++nt) {
          half8 bF = *(const half8*)&Wt2[((size_t)(ks * 4 + lg) * 128 + nt * 16 + l15) * 8];
          a3[nt] = __builtin_amdgcn_mfma_f32_16x16x32_f16(aF, bF, a3[nt], 0, 0, 0);
        }
      }
#pragma unroll
      for (int nt = 0; nt < 8; ++nt)
#pragma unroll
        for (int q = 0; q < 4; ++q) {
          int col = nt * 16 + l15;
          int j = mt * 16 + lg * 4 + q;
          hT2[col * kAhS + j] = (_Float16)a3[nt][q];
        }
    }
  }
  __syncthreads();

  // ---- stage 4: agg128 + bias + l2norm + mean-pool
  {
    const int mt = wv;
    f32x4 a4[8];
#pragma unroll
    for (int nt = 0; nt < 8; ++nt) a4[nt] = (f32x4){0.f, 0.f, 0.f, 0.f};
    if (mt < 7) {
#pragma unroll
      for (int ks = 0; ks < 4; ++ks) {
        const int kb = ks * 32 + lg * 8;
        half8 aF = *(const half8*)&Adh[(mt * 16 + l15) * kAhS + kb];
#pragma unroll
        for (int nt = 0; nt < 8; ++nt) {
          half8 bF = *(const half8*)&hT2[(nt * 16 + l15) * kAhS + kb];
          a4[nt] = __builtin_amdgcn_mfma_f32_16x16x32_f16(aF, bF, a4[nt], 0, 0, 0);
        }
      }
#pragma unroll
      for (int nt = 0; nt < 8; ++nt) {
        float bvn = b2[nt * 16 + l15];
#pragma unroll
        for (int q = 0; q < 4; ++q) a4[nt][q] += bvn;
      }
#pragma unroll
      for (int q = 0; q < 4; ++q) {
        float ss = 0.f;
#pragma unroll
        for (int nt = 0; nt < 8; ++nt) ss += a4[nt][q] * a4[nt][q];
        ss += __shfl_xor(ss, 1, 64); ss += __shfl_xor(ss, 2, 64);
        ss += __shfl_xor(ss, 4, 64); ss += __shfl_xor(ss, 8, 64);
        float inv = 1.f / fmaxf(sqrtf(ss), 1e-12f);
#pragma unroll
        for (int nt = 0; nt < 8; ++nt) a4[nt][q] *= inv;
      }
    }
    float ps[8];
#pragma unroll
    for (int nt = 0; nt < 8; ++nt) ps[nt] = 0.f;
    if (mt < 7) {
#pragma unroll
      for (int nt = 0; nt < 8; ++nt)
#pragma unroll
        for (int q = 0; q < 4; ++q) {
          int row = mt * 16 + lg * 4 + q;
          if (row < 100) ps[nt] += a4[nt][q];
        }
    }
#pragma unroll
    for (int nt = 0; nt < 8; ++nt) {
      ps[nt] += __shfl_xor(ps[nt], 16, 64);
      ps[nt] += __shfl_xor(ps[nt], 32, 64);
    }
    __syncthreads();                  // Adh dead -> scr
    if (mt < 7 && lg == 0)
#pragma unroll
      for (int nt = 0; nt < 8; ++nt) scr[wv * 128 + nt * 16 + l15] = ps[nt];
    __syncthreads();
    if (tid < 128) {
      float s = 0.f;
      for (int w2 = 0; w2 < 7; ++w2) s += scr[w2 * 128 + tid];
      float* OP = (yb == 1) ? OP1 : OP2;
      OP[(size_t)g * 128 + tid] = s / 100.f;
    }
  }
}

// ================= phase-2 fused encoder (main): hB -> BN -> GEMM2 -> agg128 =================
// Adjacency counts loaded from CNTG/SCG (computed by enc1 y0) — no rebuild.
__global__ __launch_bounds__(512)
void enc2_k(const _Float16* __restrict__ hB, const float* __restrict__ tr,
            const _Float16* __restrict__ Wt2, const float* __restrict__ b2,
            const unsigned* __restrict__ CNTG, const int* __restrict__ SCG,
            const float* __restrict__ NOI,
            float* __restrict__ OZ, _Float16* __restrict__ Z16,
            float* __restrict__ ZG, float* __restrict__ ZZ)
{
  extern __shared__ __align__(16) char lds_c[];
  _Float16* Adh = (_Float16*)lds_c;                 // [112][136]
  _Float16* hT2 = (_Float16*)(lds_c + 30464);       // [128][136]
  unsigned* cnt32 = (unsigned*)(lds_c + 30464);     // overlay (build only)
  float* scr = (float*)lds_c;                       // overlay (epilogue)
  __shared__ float sdinv[kNPG];
  const int g = blockIdx.x, tid = threadIdx.x;
  const int base = g * kNPG;
  const int lane = tid & 63, wv = tid >> 6;
  const int l15 = lane & 15, lg = lane >> 4;

  for (int i = tid; i < kCntN; i += 512) cnt32[i] = CNTG[(size_t)g * 3712 + i];
  if (tid < kNPG) sdinv[tid] = rsqrtf((float)SCG[g * 128 + tid] + 1.f);
  __syncthreads();
  for (int i = tid; i < 112 * kAhS; i += 512) {
    int d = i / kAhS, s = i - d * kAhS;
    float v = 0.f;
    if (d < 100 && s < 100) {
      unsigned w = cnt32[d * kCntW + (s >> 2)];
      unsigned c = (w >> (8 * (s & 3))) & 0xFFu;
      c += (s == d) ? 1u : 0u;
      v = (float)c * sdinv[s] * sdinv[d];
    }
    Adh[i] = (_Float16)v;
  }
  __syncthreads();   // cnt dead -> hT2 writable

  {
    const int mt = wv;
    const int r = min(base + mt * 16 + l15, kN - 1);
    f32x4 a3[8];
#pragma unroll
    for (int nt = 0; nt < 8; ++nt) a3[nt] = (f32x4){0.f, 0.f, 0.f, 0.f};
#pragma unroll
    for (int ks = 0; ks < 8; ++ks) {
      const int kb = ks * 32 + lg * 8;
      half8 h = *(const half8*)&hB[(size_t)r * 256 + kb];
      half8 aF;
#pragma unroll
      for (int j = 0; j < 8; ++j)
        aF[j] = (_Float16)(((float)h[j] - tr[kb + j]) * tr[256 + kb + j]);
#pragma unroll
      for (int nt = 0; nt < 8; ++nt) {
        half8 bF = *(const half8*)&Wt2[((size_t)(ks * 4 + lg) * 128 + nt * 16 + l15) * 8];
        a3[nt] = __builtin_amdgcn_mfma_f32_16x16x32_f16(aF, bF, a3[nt], 0, 0, 0);
      }
    }
#pragma unroll
    for (int nt = 0; nt < 8; ++nt)
#pragma unroll
      for (int q = 0; q < 4; ++q) {
        int col = nt * 16 + l15;
        int j = mt * 16 + lg * 4 + q;
        hT2[col * kAhS + j] = (_Float16)a3[nt][q];
      }
  }
  __syncthreads();

  {
    const int mt = wv;
    f32x4 a4[8];
#pragma unroll
    for (int nt = 0; nt < 8; ++nt) a4[nt] = (f32x4){0.f, 0.f, 0.f, 0.f};
    if (mt < 7) {
#pragma unroll
      for (int ks = 0; ks < 4; ++ks) {
        const int kb = ks * 32 + lg * 8;
        half8 aF = *(const half8*)&Adh[(mt * 16 + l15) * kAhS + kb];
#pragma unroll
        for (int nt = 0; nt < 8; ++nt) {
          half8 bF = *(const half8*)&hT2[(nt * 16 + l15) * kAhS + kb];
          a4[nt] = __builtin_amdgcn_mfma_f32_16x16x32_f16(aF, bF, a4[nt], 0, 0, 0);
        }
      }
#pragma unroll
      for (int nt = 0; nt < 8; ++nt) {
        float bvn = b2[nt * 16 + l15];
#pragma unroll
        for (int q = 0; q < 4; ++q) a4[nt][q] += bvn;
      }
#pragma unroll
      for (int q = 0; q < 4; ++q) {
        float ss = 0.f;
#pragma unroll
        for (int nt = 0; nt < 8; ++nt) ss += a4[nt][q] * a4[nt][q];
        ss += __shfl_xor(ss, 1, 64); ss += __shfl_xor(ss, 2, 64);
        ss += __shfl_xor(ss, 4, 64); ss += __shfl_xor(ss, 8, 64);
        float inv = 1.f / fmaxf(sqrtf(ss), 1e-12f);
#pragma unroll
        for (int nt = 0; nt < 8; ++nt) a4[nt][q] *= inv;
      }
#pragma unroll
      for (int nt = 0; nt < 8; ++nt)
#pragma unroll
        for (int q = 0; q < 4; ++q) {
          int row = mt * 16 + lg * 4 + q;
          if (row < 100) {
            OZ[(size_t)(base + row) * 128 + nt * 16 + l15] = a4[nt][q];
            Z16[(size_t)(base + row) * 128 + nt * 16 + l15] = (_Float16)a4[nt][q];
          }
        }
    }
    float m1[8], m2[8];
#pragma unroll
    for (int nt = 0; nt < 8; ++nt) { m1[nt] = -INFINITY; m2[nt] = -INFINITY; }
    if (mt < 7) {
#pragma unroll
      for (int nt = 0; nt < 8; ++nt)
#pragma unroll
        for (int q = 0; q < 4; ++q) {
          int row = mt * 16 + lg * 4 + q;
          if (row < 100) {
            float zv = a4[nt][q];
            float nv = NOI[(size_t)(base + row) * 128 + nt * 16 + l15];
            m1[nt] = fmaxf(m1[nt], zv);
            m2[nt] = fmaxf(m2[nt], zv + nv);
          }
        }
#pragma unroll
      for (int nt = 0; nt < 8; ++nt) {
        m1[nt] = fmaxf(m1[nt], __shfl_xor(m1[nt], 16, 64));
        m1[nt] = fmaxf(m1[nt], __shfl_xor(m1[nt], 32, 64));
        m2[nt] = fmaxf(m2[nt], __shfl_xor(m2[nt], 16, 64));
        m2[nt] = fmaxf(m2[nt], __shfl_xor(m2[nt], 32, 64));
      }
    }
    __syncthreads();                  // Adh dead -> scr
    if (mt < 7 && lg == 0)
#pragma unroll
      for (int nt = 0; nt < 8; ++nt) {
        scr[wv * 128 + nt * 16 + l15] = m1[nt];
        scr[1024 + wv * 128 + nt * 16 + l15] = m2[nt];
      }
    __syncthreads();
    if (tid < 128) {
      float a = -INFINITY, b = -INFINITY;
      for (int w2 = 0; w2 < 7; ++w2) {
        a = fmaxf(a, scr[w2 * 128 + tid]);
        b = fmaxf(b, scr[1024 + w2 * 128 + tid]);
      }
      ZG[(size_t)g * 128 + tid] = a;
      ZZ[(size_t)g * 128 + tid] = a;
      ZZ[(size_t)(500 + g) * 128 + tid] = b;
    }
  }
}

// ================= fused decoder: o_xr = sigmoid(relu(z16@W1)@W2) =================
__global__ __launch_bounds__(512)
void dec_fused_k(const _Float16* __restrict__ Z, const _Float16* __restrict__ Wt1,
                 const _Float16* __restrict__ Wt2, float* __restrict__ XR, int M)
{
  __shared__ alignas(16) _Float16 Hrm[64][264];
  const int tid = threadIdx.x;
  const int lane = tid & 63;
  const int l15 = lane & 15, lg = lane >> 4;
  const int wave = tid >> 6;
  const int wm = wave >> 2;
  const int wn = wave & 3;
  const int bm = blockIdx.x * 64;

  f32x4 acc[2][4];
#pragma unroll
  for (int m = 0; m < 2; ++m)
#pragma unroll
    for (int n = 0; n < 4; ++n) acc[m][n] = (f32x4){0.f, 0.f, 0.f, 0.f};
  int arow[2];
#pragma unroll
  for (int m = 0; m < 2; ++m)
    arow[m] = min(bm + wm * 32 + m * 16 + l15, M - 1);
  const int bcol = wn * 64 + l15;
#pragma unroll
  for (int ks = 0; ks < 4; ++ks) {
    const int kb = ks * 32 + lg * 8;
    half8 bF[4];
#pragma unroll
    for (int n = 0; n < 4; ++n)
      bF[n] = *(const half8*)&Wt1[((size_t)(ks * 4 + lg) * 256 + bcol + n * 16) * 8];
    half8 aF[2];
#pragma unroll
    for (int m = 0; m < 2; ++m)
      aF[m] = *(const half8*)&Z[(size_t)arow[m] * 128 + kb];
#pragma unroll
    for (int m = 0; m < 2; ++m)
#pragma unroll
      for (int n = 0; n < 4; ++n)
        acc[m][n] = __builtin_amdgcn_mfma_f32_16x16x32_f16(aF[m], bF[n], acc[m][n], 0, 0, 0);
  }
#pragma unroll
  for (int m = 0; m < 2; ++m)
#pragma unroll
    for (int q = 0; q < 4; ++q) {
      int lrow = wm * 32 + m * 16 + lg * 4 + q;
#pragma unroll
      for (int n = 0; n < 4; ++n)
        Hrm[lrow][wn * 64 + n * 16 + l15] = (_Float16)fmaxf(acc[m][n][q], 0.f);
    }
  __syncthreads();

  const int wm2 = wave & 1, wn2 = wave >> 1;
  f32x4 acc2[2][2];
#pragma unroll
  for (int m = 0; m < 2; ++m)
#pragma unroll
    for (int n = 0; n < 2; ++n) acc2[m][n] = (f32x4){0.f, 0.f, 0.f, 0.f};
#pragma unroll
  for (int ks = 0; ks < 8; ++ks) {
    const int kb = ks * 32 + lg * 8;
    half8 aF[2];
#pragma unroll
    for (int m = 0; m < 2; ++m)
      aF[m] = *(const half8*)&Hrm[wm2 * 32 + m * 16 + l15][kb];
    half8 bF[2];
#pragma unroll
    for (int n = 0; n < 2; ++n)
      bF[n] = *(const half8*)&Wt2[((size_t)(ks * 4 + lg) * 128 + wn2 * 32 + n * 16 + l15) * 8];
#pragma unroll
    for (int m = 0; m < 2; ++m)
#pragma unroll
      for (int n = 0; n < 2; ++n)
        acc2[m][n] = __builtin_amdgcn_mfma_f32_16x16x32_f16(aF[m], bF[n], acc2[m][n], 0, 0, 0);
  }
#pragma unroll
  for (int m = 0; m < 2; ++m)
#pragma unroll
    for (int q = 0; q < 4; ++q) {
      int row = bm + wm2 * 32 + m * 16 + lg * 4 + q;
      if (row >= M) continue;
#pragma unroll
      for (int n = 0; n < 2; ++n) {
        float v = acc2[m][n][q];
        XR[(size_t)row * 128 + wn2 * 32 + n * 16 + l15] = 1.f / (1.f + expf(-v));
      }
    }
}

// ======================= small-M tiled f32 GEMM (M<=1000 paths) =======================
template<int ACT>
__global__ __launch_bounds__(256)
void gemm_k(const float* __restrict__ A, const float* __restrict__ W,
            const float* __restrict__ bias, float* __restrict__ C,
            int M, int K, int Nc)
{
  __shared__ float As[32][136];
  __shared__ float Ws[32][68];
  const int tid = threadIdx.x;
  const int bm = blockIdx.x * 128;
  const int bn = blockIdx.y * 64;
  const int tm = (tid & 15) * 8;
  const int tn = (tid >> 4) * 4;
  float acc[8][4];
#pragma unroll
  for (int i = 0; i < 8; ++i)
#pragma unroll
    for (int j = 0; j < 4; ++j) acc[i][j] = 0.f;

  for (int k0 = 0; k0 < K; k0 += 32) {
#pragma unroll
    for (int l = 0; l < 4; ++l) {
      int idx = tid + l * 256;
      int r = idx >> 3;
      int kq = (idx & 7) << 2;
      int gr = bm + r;
      float4 v = make_float4(0.f, 0.f, 0.f, 0.f);
      if (gr < M) v = *(const float4*)&A[(size_t)gr * K + k0 + kq];
      As[kq + 0][r] = v.x; As[kq + 1][r] = v.y;
      As[kq + 2][r] = v.z; As[kq + 3][r] = v.w;
    }
#pragma unroll
    for (int l = 0; l < 2; ++l) {
      int idx = tid + l * 256;
      int r = idx >> 4;
      int nq = (idx & 15) << 2;
      *(float4*)&Ws[r][nq] = *(const float4*)&W[(size_t)(k0 + r) * Nc + bn + nq];
    }
    __syncthreads();
#pragma unroll
    for (int kk = 0; kk < 32; ++kk) {
      float4 a0 = *(float4*)&As[kk][tm];
      float4 a1 = *(float4*)&As[kk][tm + 4];
      float4 w4 = *(float4*)&Ws[kk][tn];
      float am[8] = {a0.x, a0.y, a0.z, a0.w, a1.x, a1.y, a1.z, a1.w};
      float wn4[4] = {w4.x, w4.y, w4.z, w4.w};
#pragma unroll
      for (int i = 0; i < 8; ++i)
#pragma unroll
        for (int j = 0; j < 4; ++j) acc[i][j] += am[i] * wn4[j];
    }
    __syncthreads();
  }
  float4 bv = make_float4(0.f, 0.f, 0.f, 0.f);
  if (bias) bv = *(const float4*)&bias[bn + tn];
#pragma unroll
  for (int i = 0; i < 8; ++i) {
    int row = bm + tm + i;
    if (row >= M) break;
    float o0 = acc[i][0] + bv.x, o1 = acc[i][1] + bv.y;
    float o2 = acc[i][2] + bv.z, o3 = acc[i][3] + bv.w;
    if (ACT == 1) {
      o0 = fmaxf(o0, 0.f); o1 = fmaxf(o1, 0.f);
      o2 = fmaxf(o2, 0.f); o3 = fmaxf(o3, 0.f);
    } else if (ACT == 2) {
      o0 = 1.f / (1.f + expf(-o0)); o1 = 1.f / (1.f + expf(-o1));
      o2 = 1.f / (1.f + expf(-o2)); o3 = 1.f / (1.f + expf(-o3));
    }
    *(float4*)&C[(size_t)row * Nc + bn + tn] = make_float4(o0, o1, o2, o3);
  }
}

// ============ BN finalize: sum 500 per-graph partials (fixed order) ============
__global__ __launch_bounds__(256)
void bn_red_k(const float* __restrict__ P, float* __restrict__ stats)
{
  const int c = threadIdx.x;
  float s = 0.f, s2 = 0.f;
  for (int b = 0; b < 500; ++b) {
    s  += P[(size_t)b * 512 + c];
    s2 += P[(size_t)b * 512 + 256 + c];
  }
  float m = s / (float)kN;
  float v = s2 / (float)kN - m * m;
  stats[512 + c] = m;
  stats[768 + c] = rsqrtf(v + BN_EPS);
}

__global__ __launch_bounds__(64)
void bn_cols_k(float* __restrict__ X, int rows, int cols)
{
  const int c = blockIdx.x, t = threadIdx.x;
  float s = 0.f, s2 = 0.f;
  for (int r = t; r < rows; r += 64) {
    float v = X[(size_t)r * cols + c];
    s += v; s2 += v * v;
  }
#pragma unroll
  for (int o = 32; o; o >>= 1) { s += __shfl_xor(s, o, 64); s2 += __shfl_xor(s2, o, 64); }
  float m = s / (float)rows;
  float var = s2 / (float)rows - m * m;
  float rinv = rsqrtf(var + BN_EPS);
  for (int r = t; r < rows; r += 64)
    X[(size_t)r * cols + c] = (X[(size_t)r * cols + c] - m) * rinv;
}

__global__ __launch_bounds__(256)
void l2n_k(const float* __restrict__ X, float* __restrict__ Y, int rows)
{
  const int w = threadIdx.x >> 6, lane = threadIdx.x & 63;
  const int row = blockIdx.x * 4 + w;
  if (row >= rows) return;
  float2 v = *(const float2*)&X[(size_t)row * kH2 + lane * 2];
  float ss = v.x * v.x + v.y * v.y;
#pragma unroll
  for (int o = 32; o; o >>= 1) ss += __shfl_xor(ss, o, 64);
  float inv = 1.f / fmaxf(sqrtf(ss), 1e-12f);
  *(float2*)&Y[(size_t)row * kH2 + lane * 2] = make_float2(v.x * inv, v.y * inv);
}

// =========================================================================
extern "C" void kernel_launch(void* const* d_in, const int* in_sizes, int n_in,
                              void* d_out, int out_size, void* d_ws, size_t ws_size,
                              hipStream_t stream)
{
  const float* x        = (const float*)d_in[0];
  const int*   srcI     = (const int*)d_in[1];
  const int*   dstI     = (const int*)d_in[2];
  const float* pos_x    = (const float*)d_in[4];
  const int*   psrc     = (const int*)d_in[5];
  const int*   pdst     = (const int*)d_in[6];
  const float* neg_x    = (const float*)d_in[8];
  const int*   nsrc     = (const int*)d_in[9];
  const int*   ndst     = (const int*)d_in[10];
  const float* target_x = (const float*)d_in[12];
  const float* noise    = (const float*)d_in[13];
  const float* W_enc1   = (const float*)d_in[14];
  const float* b_enc1   = (const float*)d_in[15];
  const float* W_enc2   = (const float*)d_in[16];
  const float* b_enc2   = (const float*)d_in[17];
  const float* W_dec1   = (const float*)d_in[18];
  const float* W_dec2   = (const float*)d_in[19];
  const float* Wn1      = (const float*)d_in[20];
  const float* bn1      = (const float*)d_in[21];
  const float* Wn2      = (const float*)d_in[22];
  const float* bn2      = (const float*)d_in[23];
  const float* Ws1      = (const float*)d_in[24];
  const float* bs1      = (const float*)d_in[25];
  const float* Wp1      = (const float*)d_in[26];
  const float* bp1      = (const float*)d_in[27];
  const float* Wp2      = (const float*)d_in[28];
  const float* bp2      = (const float*)d_in[29];

  float* out  = (float*)d_out;
  float* o_z   = out;                 // N x 128
  float* o_zg  = out + 6400000;       // 500 x 128
  float* o_xr  = out + 6464000;       // N x 128
  float* o_pos = out + 12864000;      // 500 x 128
  float* o_neg = out + 12928000;
  float* o_zgm = out + 12992000;      // o_zgm||o_zpm contiguous 1000 x 128
  float* o_tz  = out + 13120000;

  // WORKSPACE MAP (float offsets; r2-r4 audit per launch):
  //  hB  [0, 6.4M):        fp16 N x 256 (enc1 y0 -> enc2)
  //  pstat 6.4M (256000);  t1 6.4M / t2 6.7M (target-time, pstat dead)
  //  x16m 8.0M / x16p 11.2M / x16n 14.4M: fp16 N x 128 each (prep -> enc1)
  //  z16 [19.2M, 22.4M):   fp16 N x 128 (enc2 -> dec)
  //  zz 22.4M; t1000 22.52M; CNTG 22.7M-24.56M (500*3712 u32, enc1y0->enc2);
  //  SCG 24.6M (500*128 int); hWt 25.6M; stats 25.7M.
  float* ws = (float*)d_ws;
  _Float16* hB  = (_Float16*)ws;
  float* pstat  = ws + 6400000;
  _Float16* x16m = (_Float16*)(ws + 8000000);
  _Float16* x16p = (_Float16*)(ws + 11200000);
  _Float16* x16n = (_Float16*)(ws + 14400000);
  _Float16* z16 = (_Float16*)(ws + 19200000);
  float* zz    = ws + 22400000;
  float* t1000 = ws + 22520000;
  unsigned* CNTG = (unsigned*)(ws + 22700000);   // 1.856M u32
  int* SCG = (int*)(ws + 24600000);              // 64000 int
  float* t1    = ws + 6400000;        // target-time (pstat dead)
  float* t2    = ws + 6700000;
  _Float16* hWt = (_Float16*)(ws + 25600000);
  float* stats = ws + 25700000;
  if (ws_size < (size_t)(25921024) * sizeof(float)) return;

  _Float16* WtEnc1 = hWt;
  _Float16* WtEnc2 = hWt + 32768;
  _Float16* WtDec1 = hWt + 65536;
  _Float16* WtDec2 = hWt + 98304;
  _Float16* WtS1   = hWt + 131072;

  (void)hipFuncSetAttribute((const void*)enc1_k,
      hipFuncAttributeMaxDynamicSharedMemorySize, kLds1);
  (void)hipFuncSetAttribute((const void*)enc2_k,
      hipFuncAttributeMaxDynamicSharedMemorySize, kLds2);

  auto gg = [](int M, int Nc) {
    return dim3((unsigned)((M + 127) / 128), (unsigned)(Nc / 64), 1);
  };

  // 1. combined weight + x prep (640 wprep blocks + 9375 xprep blocks)
  prep_k<<<10015, 256, 0, stream>>>(W_enc1, W_enc2, W_dec1, W_dec2, Ws1, hWt,
                                    x, pos_x, neg_x, x16m, x16p, x16n);

  // 2. phase-1 fused encoder: main(y0) -> hB+pstat+CNTG/SCG; pos/neg -> o_pos/o_neg
  enc1_k<<<dim3(kB, 3), 512, kLds1, stream>>>(
      x16m, x16p, x16n, srcI, psrc, nsrc, dstI, pdst, ndst,
      WtEnc1, WtS1, WtEnc2, b_enc1, bs1, b_enc2,
      hB, pstat, o_pos, o_neg, CNTG, SCG);

  // 3. BN finalize
  bn_red_k<<<1, 256, 0, stream>>>(pstat, stats);

  // 4. phase-2 fused encoder (main): hB -> o_z, z16, o_zg, zz (counts reused)
  enc2_k<<<kB, 512, kLds2, stream>>>(
      hB, stats + 512, WtEnc2, b_enc2, CNTG, SCG, noise, o_z, z16, o_zg, zz);

  // 5. fused decoder: z16 -> o_xr
  dec_fused_k<<<782, 512, 0, stream>>>(z16, WtDec1, WtDec2, o_xr, kN);

  // 6-7. merged projection heads
  gemm_k<1><<<gg(1000, kH2), 256, 0, stream>>>(zz, Wp1, bp1, t1000, 1000, kH2, kH2);
  gemm_k<0><<<gg(1000, kH2), 256, 0, stream>>>(t1000, Wp2, bp2, o_zgm, 1000, kH2, kH2);

  // 8-11. target node encoder
  gemm_k<1><<<gg(kB, kH1), 256, 0, stream>>>(target_x, Wn1, bn1, t1, kB, kF0, kH1);
  bn_cols_k<<<256, 64, 0, stream>>>(t1, kB, kH1);
  gemm_k<0><<<gg(kB, kH2), 256, 0, stream>>>(t1, Wn2, bn2, t2, kB, kH1, kH2);
  l2n_k<<<125, 256, 0, stream>>>(t2, o_tz, kB);

  (void)in_sizes; (void)n_in; (void)out_size;
}

// Round 24
// 312.280 us; speedup vs baseline: 1.4459x; 1.0365x over previous
//
#include <hip/hip_runtime.h>
#include <math.h>

static constexpr int kN   = 50000;
static constexpr int kB   = 500;
static constexpr int kNPG = 100;
static constexpr int kEPG = 1600;
static constexpr int kESG = 800;
static constexpr int kF0  = 128;
static constexpr int kH1  = 256;
static constexpr int kH2  = 128;
#define BN_EPS 1e-5f

typedef _Float16 half8 __attribute__((ext_vector_type(8)));
typedef __attribute__((ext_vector_type(4))) float f32x4;

static constexpr int kCntW = 33;
static constexpr int kAhS  = 136;     // Adh / hT / hT2 stride (fp16)
static constexpr int kH2S  = 264;     // h2 stride (fp16)
static constexpr int kCntN = 112 * kCntW;   // 3696 u32 per graph
// enc1 LDS (bytes): Adh[112][136] @0 (30464) | hT[256][136] @30464 (69632)
//  | h2[112][264] @100096 (59136). cnt32 overlays hT pre-GEMM1; hT2[128][136]
//  overlays hT post-agg256; scr overlays Adh post-agg128. Total 159232.
static constexpr unsigned kLds1 = 159232;
// enc2 LDS: Adh 30464 | hT2[128][136] @30464 (34816) (cnt overlays hT2). 65280.
static constexpr unsigned kLds2 = 65280;

// ============ combined prep: weights -> Wt fp16 layout; x/pos/neg -> fp16 ============
__global__ __launch_bounds__(256)
void prep_k(const float* __restrict__ s0, const float* __restrict__ s1,
            const float* __restrict__ s2, const float* __restrict__ s3,
            const float* __restrict__ s4, _Float16* __restrict__ dW,
            const float* __restrict__ x0, const float* __restrict__ x1,
            const float* __restrict__ x2, _Float16* __restrict__ d0,
            _Float16* __restrict__ d1, _Float16* __restrict__ d2)
{
  if (blockIdx.x < 640) {
    int seg = blockIdx.x >> 7;
    int idx = (blockIdx.x & 127) * 256 + threadIdx.x;
    const float* S; int Nc;
    switch (seg) {
      case 0: S = s0; Nc = 256; break;
      case 1: S = s1; Nc = 128; break;
      case 2: S = s2; Nc = 256; break;
      case 3: S = s3; Nc = 128; break;
      default: S = s4; Nc = 256; break;
    }
    int e = idx & 7, t = idx >> 3;
    int c = t % Nc, kg = t / Nc;
    dW[seg * 32768 + idx] = (_Float16)S[(size_t)(kg * 8 + e) * Nc + c];
  } else {
    const size_t idx = (size_t)(blockIdx.x - 640) * 256 + threadIdx.x;  // 2.4M
    const size_t per = (size_t)kN * 16;
    const int seg = (int)(idx / per);
    const size_t off = (idx - (size_t)seg * per) * 8;
    const float* S = (seg == 0) ? x0 : (seg == 1) ? x1 : x2;
    _Float16* D = (seg == 0) ? d0 : (seg == 1) ? d1 : d2;
    float4 u0 = *(const float4*)&S[off];
    float4 u1 = *(const float4*)&S[off + 4];
    half8 h;
    h[0] = (_Float16)u0.x; h[1] = (_Float16)u0.y;
    h[2] = (_Float16)u0.z; h[3] = (_Float16)u0.w;
    h[4] = (_Float16)u1.x; h[5] = (_Float16)u1.y;
    h[6] = (_Float16)u1.z; h[7] = (_Float16)u1.w;
    *(half8*)&D[off] = h;
  }
}

// ================= phase-1 fused encoder (per-graph blocks) =================
// blockIdx.y: 0=main (GEMM1+agg256+STATS -> hB global; also dumps cnt/scnt to
// CNTG/SCG for enc2 reuse), 1=pos, 2=neg (full chain -> mean-pool OP).
__global__ __launch_bounds__(512)
void enc1_k(const _Float16* __restrict__ x0, const _Float16* __restrict__ x1,
            const _Float16* __restrict__ x2,
            const int* __restrict__ src0, const int* __restrict__ src1,
            const int* __restrict__ src2,
            const int* __restrict__ dst0, const int* __restrict__ dst1,
            const int* __restrict__ dst2,
            const _Float16* __restrict__ Wt1m, const _Float16* __restrict__ Wt1s,
            const _Float16* __restrict__ Wt2,
            const float* __restrict__ b1m, const float* __restrict__ b1s,
            const float* __restrict__ b2,
            _Float16* __restrict__ hB, float* __restrict__ PST,
            float* __restrict__ OP1, float* __restrict__ OP2,
            unsigned* __restrict__ CNTG, int* __restrict__ SCG)
{
  extern __shared__ __align__(16) char lds_c[];
  _Float16* Adh = (_Float16*)lds_c;                 // [112][136]
  _Float16* hT  = (_Float16*)(lds_c + 30464);       // [256][136]
  _Float16* h2  = (_Float16*)(lds_c + 100096);      // [112][264]
  unsigned* cnt32 = (unsigned*)(lds_c + 30464);     // overlay (build only)
  _Float16* hT2 = (_Float16*)(lds_c + 30464);       // overlay (stage 3+)
  float* scr = (float*)lds_c;                       // overlay (pool epilogue)
  __shared__ int scnt[kNPG];
  __shared__ float sdinv[kNPG];
  const int yb = blockIdx.y;
  const _Float16* X = (yb == 0) ? x0 : (yb == 1) ? x1 : x2;
  const int* srcI = (yb == 0) ? src0 : (yb == 1) ? src1 : src2;
  const int* dstI = (yb == 0) ? dst0 : (yb == 1) ? dst1 : dst2;
  const _Float16* W1 = (yb == 0) ? Wt1m : Wt1s;
  const float* bias1 = (yb == 0) ? b1m : b1s;
  const int epg = (yb == 0) ? kEPG : kESG;
  const int g = blockIdx.x, tid = threadIdx.x;
  const int base = g * kNPG;
  const size_t ebase = (size_t)g * epg;
  const int lane = tid & 63, wv = tid >> 6;
  const int l15 = lane & 15, lg = lane >> 4;

  // ---- build adjacency (deterministic integer counts)
  for (int i = tid; i < kCntN; i += 512) cnt32[i] = 0u;
  if (tid < kNPG) scnt[tid] = 0;
  __syncthreads();
  for (int e = tid; e < epg; e += 512) {
    int s = srcI[ebase + e] - base;
    int d = dstI[ebase + e] - base;
    atomicAdd(&scnt[d], 1);
    atomicAdd(&cnt32[d * kCntW + (s >> 2)], 1u << (8 * (s & 3)));
  }
  __syncthreads();
  if (tid < kNPG) sdinv[tid] = rsqrtf((float)scnt[tid] + 1.f);
  __syncthreads();
  if (yb == 0) {   // dump counts for enc2 reuse (cnt32 still live here)
    for (int i = tid; i < kCntN; i += 512) CNTG[(size_t)g * 3712 + i] = cnt32[i];
    if (tid < kNPG) SCG[g * 128 + tid] = scnt[tid];
  }
  for (int i = tid; i < 112 * kAhS; i += 512) {
    int d = i / kAhS, s = i - d * kAhS;
    float v = 0.f;
    if (d < 100 && s < 100) {
      unsigned w = cnt32[d * kCntW + (s >> 2)];
      unsigned c = (w >> (8 * (s & 3))) & 0xFFu;
      c += (s == d) ? 1u : 0u;
      v = (float)c * sdinv[s] * sdinv[d];
    }
    Adh[i] = (_Float16)v;
  }
  __syncthreads();   // cnt dead; hT region writable

  // ---- stage 1: GEMM1 (7 m-tiles = 112 real rows; N=256, K=128) -> hT^T
  // Rows >=112 only multiply Adh zeros downstream, so skip the 8th tile and
  // ZERO-FILL hT[*][112..128) (stale LDS could be NaN-pattern fp16; NaNx0=NaN).
  {
    f32x4 a1[7][2];
#pragma unroll
    for (int mt = 0; mt < 7; ++mt) {
      a1[mt][0] = (f32x4){0.f, 0.f, 0.f, 0.f};
      a1[mt][1] = (f32x4){0.f, 0.f, 0.f, 0.f};
    }
    int rows[7];
#pragma unroll
    for (int mt = 0; mt < 7; ++mt) rows[mt] = min(base + mt * 16 + l15, kN - 1);
    const int bc0 = wv * 32 + l15;
#pragma unroll
    for (int ks = 0; ks < 4; ++ks) {
      const int kb = ks * 32 + lg * 8;
      half8 bF[2];
#pragma unroll
      for (int t = 0; t < 2; ++t)
        bF[t] = *(const half8*)&W1[((size_t)(ks * 4 + lg) * 256 + bc0 + t * 16) * 8];
#pragma unroll
      for (int mt = 0; mt < 7; ++mt) {
        half8 aF = *(const half8*)&X[(size_t)rows[mt] * 128 + kb];
#pragma unroll
        for (int t = 0; t < 2; ++t)
          a1[mt][t] = __builtin_amdgcn_mfma_f32_16x16x32_f16(aF, bF[t], a1[mt][t], 0, 0, 0);
      }
    }
#pragma unroll
    for (int mt = 0; mt < 7; ++mt)
#pragma unroll
      for (int t = 0; t < 2; ++t)
#pragma unroll
        for (int q = 0; q < 4; ++q) {
          int col = wv * 32 + t * 16 + l15;
          int j = mt * 16 + lg * 4 + q;             // 0..111
          hT[col * kAhS + j] = (_Float16)a1[mt][t][q];
        }
    for (int i = tid; i < 256 * 16; i += 512) {      // zero-fill j 112..127
      int c = i >> 4, j = 112 + (i & 15);
      hT[c * kAhS + j] = (_Float16)0.f;
    }
  }
  __syncthreads();

  // ---- stage 2: agg256 (M=112, cols wv*32..+31) + bias + relu + stats/segBN
  {
    f32x4 a2[7][2];
#pragma unroll
    for (int mt = 0; mt < 7; ++mt) {
      a2[mt][0] = (f32x4){0.f, 0.f, 0.f, 0.f};
      a2[mt][1] = (f32x4){0.f, 0.f, 0.f, 0.f};
    }
#pragma unroll
    for (int ks = 0; ks < 4; ++ks) {
      const int kb = ks * 32 + lg * 8;
      half8 bF[2];
#pragma unroll
      for (int t = 0; t < 2; ++t)
        bF[t] = *(const half8*)&hT[(wv * 32 + t * 16 + l15) * kAhS + kb];
#pragma unroll
      for (int mt = 0; mt < 7; ++mt) {
        half8 aF = *(const half8*)&Adh[(mt * 16 + l15) * kAhS + kb];
        a2[mt][0] = __builtin_amdgcn_mfma_f32_16x16x32_f16(aF, bF[0], a2[mt][0], 0, 0, 0);
        a2[mt][1] = __builtin_amdgcn_mfma_f32_16x16x32_f16(aF, bF[1], a2[mt][1], 0, 0, 0);
      }
    }
    float bv0 = bias1[wv * 32 + l15];
    float bv1 = bias1[wv * 32 + 16 + l15];
#pragma unroll
    for (int mt = 0; mt < 7; ++mt)
#pragma unroll
      for (int q = 0; q < 4; ++q) {
        a2[mt][0][q] = fmaxf(a2[mt][0][q] + bv0, 0.f);
        a2[mt][1][q] = fmaxf(a2[mt][1][q] + bv1, 0.f);
      }
    float s0 = 0.f, s20 = 0.f, s1 = 0.f, s21 = 0.f;
#pragma unroll
    for (int mt = 0; mt < 7; ++mt)
#pragma unroll
      for (int q = 0; q < 4; ++q) {
        int row = mt * 16 + lg * 4 + q;
        if (row < 100) {
          float v0 = a2[mt][0][q], v1 = a2[mt][1][q];
          s0 += v0; s20 += v0 * v0; s1 += v1; s21 += v1 * v1;
        }
      }
    s0 += __shfl_xor(s0, 16, 64);  s0 += __shfl_xor(s0, 32, 64);
    s20 += __shfl_xor(s20, 16, 64); s20 += __shfl_xor(s20, 32, 64);
    s1 += __shfl_xor(s1, 16, 64);  s1 += __shfl_xor(s1, 32, 64);
    s21 += __shfl_xor(s21, 16, 64); s21 += __shfl_xor(s21, 32, 64);
    if (yb == 0) {
      if (lg == 0) {
        PST[(size_t)g * 512 + wv * 32 + l15] = s0;
        PST[(size_t)g * 512 + 256 + wv * 32 + l15] = s20;
        PST[(size_t)g * 512 + wv * 32 + 16 + l15] = s1;
        PST[(size_t)g * 512 + 256 + wv * 32 + 16 + l15] = s21;
      }
#pragma unroll
      for (int mt = 0; mt < 7; ++mt)
#pragma unroll
        for (int q = 0; q < 4; ++q) {
          int row = mt * 16 + lg * 4 + q;
          if (row < 100) {
            hB[(size_t)(base + row) * 256 + wv * 32 + l15] = (_Float16)a2[mt][0][q];
            hB[(size_t)(base + row) * 256 + wv * 32 + 16 + l15] = (_Float16)a2[mt][1][q];
          }
        }
    } else {
      float m0 = s0 / 100.f, r0 = rsqrtf(s20 / 100.f - m0 * m0 + BN_EPS);
      float m1 = s1 / 100.f, r1 = rsqrtf(s21 / 100.f - m1 * m1 + BN_EPS);
#pragma unroll
      for (int mt = 0; mt < 7; ++mt)
#pragma unroll
        for (int q = 0; q < 4; ++q) {
          int row = mt * 16 + lg * 4 + q;
          h2[row * kH2S + wv * 32 + l15] = (_Float16)((a2[mt][0][q] - m0) * r0);
          h2[row * kH2S + wv * 32 + 16 + l15] = (_Float16)((a2[mt][1][q] - m1) * r1);
        }
    }
  }
  if (yb == 0) return;   // block-uniform exit (main phase-A done)

  __syncthreads();   // h2 complete; hT reads done -> hT2 region writable

  // ---- stage 3: GEMM2 (M=112 via wave=mt, N=128, K=256) -> hT2^T
  {
    for (int i = tid; i < 128 * 16; i += 512) {          // zero pad rows 112..127
      int c = i >> 4, j = 112 + (i & 15);
      hT2[c * kAhS + j] = (_Float16)0.f;
    }
    const int mt = wv;
    f32x4 a3[8];
#pragma unroll
    for (int nt = 0; nt < 8; ++nt) a3[nt] = (f32x4){0.f, 0.f, 0.f, 0.f};
    if (mt < 7) {
#pragma unroll
      for (int ks = 0; ks < 8; ++ks) {
        const int kb = ks * 32 + lg * 8;
        half8 aF = *(const half8*)&h2[(mt * 16 + l15) * kH2S + kb];
#pragma unroll
        for (int nt = 0; nt < 8; ++nt) {
          half8 bF = *(const half8*)&Wt2[((size_t)(ks * 4 + lg) * 128 + nt * 16 + l15) * 8];
          a3[nt] = __builtin_amdgcn_mfma_f32_16x16x32_f16(aF, bF, a3[nt], 0, 0, 0);
        }
      }
#pragma unroll
      for (int nt = 0; nt < 8; ++nt)
#pragma unroll
        for (int q = 0; q < 4; ++q) {
          int col = nt * 16 + l15;
          int j = mt * 16 + lg * 4 + q;
          hT2[col * kAhS + j] = (_Float16)a3[nt][q];
        }
    }
  }
  __syncthreads();

  // ---- stage 4: agg128 + bias + l2norm + mean-pool
  {
    const int mt = wv;
    f32x4 a4[8];
#pragma unroll
    for (int nt = 0; nt < 8; ++nt) a4[nt] = (f32x4){0.f, 0.f, 0.f, 0.f};
    if (mt < 7) {
#pragma unroll
      for (int ks = 0; ks < 4; ++ks) {
        const int kb = ks * 32 + lg * 8;
        half8 aF = *(const half8*)&Adh[(mt * 16 + l15) * kAhS + kb];
#pragma unroll
        for (int nt = 0; nt < 8; ++nt) {
          half8 bF = *(const half8*)&hT2[(nt * 16 + l15) * kAhS + kb];
          a4[nt] = __builtin_amdgcn_mfma_f32_16x16x32_f16(aF, bF, a4[nt], 0, 0, 0);
        }
      }
#pragma unroll
      for (int nt = 0; nt < 8; ++nt) {
        float bvn = b2[nt * 16 + l15];
#pragma unroll
        for (int q = 0; q < 4; ++q) a4[nt][q] += bvn;
      }
#pragma unroll
      for (int q = 0; q < 4; ++q) {
        float ss = 0.f;
#pragma unroll
        for (int nt = 0; nt < 8; ++nt) ss += a4[nt][q] * a4[nt][q];
        ss += __shfl_xor(ss, 1, 64); ss += __shfl_xor(ss, 2, 64);
        ss += __shfl_xor(ss, 4, 64); ss += __shfl_xor(ss, 8, 64);
        float inv = 1.f / fmaxf(sqrtf(ss), 1e-12f);
#pragma unroll
        for (int nt = 0; nt < 8; ++nt) a4[nt][q] *= inv;
      }
    }
    float ps[8];
#pragma unroll
    for (int nt = 0; nt < 8; ++nt) ps[nt] = 0.f;
    if (mt < 7) {
#pragma unroll
      for (int nt = 0; nt < 8; ++nt)
#pragma unroll
        for (int q = 0; q < 4; ++q) {
          int row = mt * 16 + lg * 4 + q;
          if (row < 100) ps[nt] += a4[nt][q];
        }
    }
#pragma unroll
    for (int nt = 0; nt < 8; ++nt) {
      ps[nt] += __shfl_xor(ps[nt], 16, 64);
      ps[nt] += __shfl_xor(ps[nt], 32, 64);
    }
    __syncthreads();                  // Adh dead -> scr
    if (mt < 7 && lg == 0)
#pragma unroll
      for (int nt = 0; nt < 8; ++nt) scr[wv * 128 + nt * 16 + l15] = ps[nt];
    __syncthreads();
    if (tid < 128) {
      float s = 0.f;
      for (int w2 = 0; w2 < 7; ++w2) s += scr[w2 * 128 + tid];
      float* OP = (yb == 1) ? OP1 : OP2;
      OP[(size_t)g * 128 + tid] = s / 100.f;
    }
  }
}

// ================= phase-2 fused encoder (main): hB -> BN -> GEMM2 -> agg128 =================
// Adjacency counts loaded from CNTG/SCG (computed by enc1 y0) — no rebuild.
__global__ __launch_bounds__(512)
void enc2_k(const _Float16* __restrict__ hB, const float* __restrict__ tr,
            const _Float16* __restrict__ Wt2, const float* __restrict__ b2,
            const unsigned* __restrict__ CNTG, const int* __restrict__ SCG,
            const float* __restrict__ NOI,
            float* __restrict__ OZ, _Float16* __restrict__ Z16,
            float* __restrict__ ZG, float* __restrict__ ZZ)
{
  extern __shared__ __align__(16) char lds_c[];
  _Float16* Adh = (_Float16*)lds_c;                 // [112][136]
  _Float16* hT2 = (_Float16*)(lds_c + 30464);       // [128][136]
  unsigned* cnt32 = (unsigned*)(lds_c + 30464);     // overlay (build only)
  float* scr = (float*)lds_c;                       // overlay (epilogue)
  __shared__ float sdinv[kNPG];
  const int g = blockIdx.x, tid = threadIdx.x;
  const int base = g * kNPG;
  const int lane = tid & 63, wv = tid >> 6;
  const int l15 = lane & 15, lg = lane >> 4;

  for (int i = tid; i < kCntN; i += 512) cnt32[i] = CNTG[(size_t)g * 3712 + i];
  if (tid < kNPG) sdinv[tid] = rsqrtf((float)SCG[g * 128 + tid] + 1.f);
  __syncthreads();
  for (int i = tid; i < 112 * kAhS; i += 512) {
    int d = i / kAhS, s = i - d * kAhS;
    float v = 0.f;
    if (d < 100 && s < 100) {
      unsigned w = cnt32[d * kCntW + (s >> 2)];
      unsigned c = (w >> (8 * (s & 3))) & 0xFFu;
      c += (s == d) ? 1u : 0u;
      v = (float)c * sdinv[s] * sdinv[d];
    }
    Adh[i] = (_Float16)v;
  }
  __syncthreads();   // cnt dead -> hT2 writable

  {
    const int mt = wv;
    const int r = min(base + mt * 16 + l15, kN - 1);
    f32x4 a3[8];
#pragma unroll
    for (int nt = 0; nt < 8; ++nt) a3[nt] = (f32x4){0.f, 0.f, 0.f, 0.f};
#pragma unroll
    for (int ks = 0; ks < 8; ++ks) {
      const int kb = ks * 32 + lg * 8;
      half8 h = *(const half8*)&hB[(size_t)r * 256 + kb];
      half8 aF;
#pragma unroll
      for (int j = 0; j < 8; ++j)
        aF[j] = (_Float16)(((float)h[j] - tr[kb + j]) * tr[256 + kb + j]);
#pragma unroll
      for (int nt = 0; nt < 8; ++nt) {
        half8 bF = *(const half8*)&Wt2[((size_t)(ks * 4 + lg) * 128 + nt * 16 + l15) * 8];
        a3[nt] = __builtin_amdgcn_mfma_f32_16x16x32_f16(aF, bF, a3[nt], 0, 0, 0);
      }
    }
#pragma unroll
    for (int nt = 0; nt < 8; ++nt)
#pragma unroll
      for (int q = 0; q < 4; ++q) {
        int col = nt * 16 + l15;
        int j = mt * 16 + lg * 4 + q;
        hT2[col * kAhS + j] = (_Float16)a3[nt][q];
      }
  }
  __syncthreads();

  {
    const int mt = wv;
    f32x4 a4[8];
#pragma unroll
    for (int nt = 0; nt < 8; ++nt) a4[nt] = (f32x4){0.f, 0.f, 0.f, 0.f};
    if (mt < 7) {
#pragma unroll
      for (int ks = 0; ks < 4; ++ks) {
        const int kb = ks * 32 + lg * 8;
        half8 aF = *(const half8*)&Adh[(mt * 16 + l15) * kAhS + kb];
#pragma unroll
        for (int nt = 0; nt < 8; ++nt) {
          half8 bF = *(const half8*)&hT2[(nt * 16 + l15) * kAhS + kb];
          a4[nt] = __builtin_amdgcn_mfma_f32_16x16x32_f16(aF, bF, a4[nt], 0, 0, 0);
        }
      }
#pragma unroll
      for (int nt = 0; nt < 8; ++nt) {
        float bvn = b2[nt * 16 + l15];
#pragma unroll
        for (int q = 0; q < 4; ++q) a4[nt][q] += bvn;
      }
#pragma unroll
      for (int q = 0; q < 4; ++q) {
        float ss = 0.f;
#pragma unroll
        for (int nt = 0; nt < 8; ++nt) ss += a4[nt][q] * a4[nt][q];
        ss += __shfl_xor(ss, 1, 64); ss += __shfl_xor(ss, 2, 64);
        ss += __shfl_xor(ss, 4, 64); ss += __shfl_xor(ss, 8, 64);
        float inv = 1.f / fmaxf(sqrtf(ss), 1e-12f);
#pragma unroll
        for (int nt = 0; nt < 8; ++nt) a4[nt][q] *= inv;
      }
#pragma unroll
      for (int nt = 0; nt < 8; ++nt)
#pragma unroll
        for (int q = 0; q < 4; ++q) {
          int row = mt * 16 + lg * 4 + q;
          if (row < 100) {
            OZ[(size_t)(base + row) * 128 + nt * 16 + l15] = a4[nt][q];
            Z16[(size_t)(base + row) * 128 + nt * 16 + l15] = (_Float16)a4[nt][q];
          }
        }
    }
    float m1[8], m2[8];
#pragma unroll
    for (int nt = 0; nt < 8; ++nt) { m1[nt] = -INFINITY; m2[nt] = -INFINITY; }
    if (mt < 7) {
#pragma unroll
      for (int nt = 0; nt < 8; ++nt)
#pragma unroll
        for (int q = 0; q < 4; ++q) {
          int row = mt * 16 + lg * 4 + q;
          if (row < 100) {
            float zv = a4[nt][q];
            float nv = NOI[(size_t)(base + row) * 128 + nt * 16 + l15];
            m1[nt] = fmaxf(m1[nt], zv);
            m2[nt] = fmaxf(m2[nt], zv + nv);
          }
        }
#pragma unroll
      for (int nt = 0; nt < 8; ++nt) {
        m1[nt] = fmaxf(m1[nt], __shfl_xor(m1[nt], 16, 64));
        m1[nt] = fmaxf(m1[nt], __shfl_xor(m1[nt], 32, 64));
        m2[nt] = fmaxf(m2[nt], __shfl_xor(m2[nt], 16, 64));
        m2[nt] = fmaxf(m2[nt], __shfl_xor(m2[nt], 32, 64));
      }
    }
    __syncthreads();                  // Adh dead -> scr
    if (mt < 7 && lg == 0)
#pragma unroll
      for (int nt = 0; nt < 8; ++nt) {
        scr[wv * 128 + nt * 16 + l15] = m1[nt];
        scr[1024 + wv * 128 + nt * 16 + l15] = m2[nt];
      }
    __syncthreads();
    if (tid < 128) {
      float a = -INFINITY, b = -INFINITY;
      for (int w2 = 0; w2 < 7; ++w2) {
        a = fmaxf(a, scr[w2 * 128 + tid]);
        b = fmaxf(b, scr[1024 + w2 * 128 + tid]);
      }
      ZG[(size_t)g * 128 + tid] = a;
      ZZ[(size_t)g * 128 + tid] = a;
      ZZ[(size_t)(500 + g) * 128 + tid] = b;
    }
  }
}

// ================= fused decoder: o_xr = sigmoid(relu(z16@W1)@W2) =================
__global__ __launch_bounds__(512)
void dec_fused_k(const _Float16* __restrict__ Z, const _Float16* __restrict__ Wt1,
                 const _Float16* __restrict__ Wt2, float* __restrict__ XR, int M)
{
  __shared__ alignas(16) _Float16 Hrm[64][264];
  const int tid = threadIdx.x;
  const int lane = tid & 63;
  const int l15 = lane & 15, lg = lane >> 4;
  const int wave = tid >> 6;
  const int wm = wave >> 2;
  const int wn = wave & 3;
  const int bm = blockIdx.x * 64;

  f32x4 acc[2][4];
#pragma unroll
  for (int m = 0; m < 2; ++m)
#pragma unroll
    for (int n = 0; n < 4; ++n) acc[m][n] = (f32x4){0.f, 0.f, 0.f, 0.f};
  int arow[2];
#pragma unroll
  for (int m = 0; m < 2; ++m)
    arow[m] = min(bm + wm * 32 + m * 16 + l15, M - 1);
  const int bcol = wn * 64 + l15;
#pragma unroll
  for (int ks = 0; ks < 4; ++ks) {
    const int kb = ks * 32 + lg * 8;
    half8 bF[4];
#pragma unroll
    for (int n = 0; n < 4; ++n)
      bF[n] = *(const half8*)&Wt1[((size_t)(ks * 4 + lg) * 256 + bcol + n * 16) * 8];
    half8 aF[2];
#pragma unroll
    for (int m = 0; m < 2; ++m)
      aF[m] = *(const half8*)&Z[(size_t)arow[m] * 128 + kb];
#pragma unroll
    for (int m = 0; m < 2; ++m)
#pragma unroll
      for (int n = 0; n < 4; ++n)
        acc[m][n] = __builtin_amdgcn_mfma_f32_16x16x32_f16(aF[m], bF[n], acc[m][n], 0, 0, 0);
  }
#pragma unroll
  for (int m = 0; m < 2; ++m)
#pragma unroll
    for (int q = 0; q < 4; ++q) {
      int lrow = wm * 32 + m * 16 + lg * 4 + q;
#pragma unroll
      for (int n = 0; n < 4; ++n)
        Hrm[lrow][wn * 64 + n * 16 + l15] = (_Float16)fmaxf(acc[m][n][q], 0.f);
    }
  __syncthreads();

  const int wm2 = wave & 1, wn2 = wave >> 1;
  f32x4 acc2[2][2];
#pragma unroll
  for (int m = 0; m < 2; ++m)
#pragma unroll
    for (int n = 0; n < 2; ++n) acc2[m][n] = (f32x4){0.f, 0.f, 0.f, 0.f};
#pragma unroll
  for (int ks = 0; ks < 8; ++ks) {
    const int kb = ks * 32 + lg * 8;
    half8 aF[2];
#pragma unroll
    for (int m = 0; m < 2; ++m)
      aF[m] = *(const half8*)&Hrm[wm2 * 32 + m * 16 + l15][kb];
    half8 bF[2];
#pragma unroll
    for (int n = 0; n < 2; ++n)
      bF[n] = *(const half8*)&Wt2[((size_t)(ks * 4 + lg) * 128 + wn2 * 32 + n * 16 + l15) * 8];
#pragma unroll
    for (int m = 0; m < 2; ++m)
#pragma unroll
      for (int n = 0; n < 2; ++n)
        acc2[m][n] = __builtin_amdgcn_mfma_f32_16x16x32_f16(aF[m], bF[n], acc2[m][n], 0, 0, 0);
  }
#pragma unroll
  for (int m = 0; m < 2; ++m)
#pragma unroll
    for (int q = 0; q < 4; ++q) {
      int row = bm + wm2 * 32 + m * 16 + lg * 4 + q;
      if (row >= M) continue;
#pragma unroll
      for (int n = 0; n < 2; ++n) {
        float v = acc2[m][n][q];
        XR[(size_t)row * 128 + wn2 * 32 + n * 16 + l15] = 1.f / (1.f + expf(-v));
      }
    }
}

// ======================= small-M tiled f32 GEMM (M<=1000 paths) =======================
template<int ACT>
__global__ __launch_bounds__(256)
void gemm_k(const float* __restrict__ A, const float* __restrict__ W,
            const float* __restrict__ bias, float* __restrict__ C,
            int M, int K, int Nc)
{
  __shared__ float As[32][136];
  __shared__ float Ws[32][68];
  const int tid = threadIdx.x;
  const int bm = blockIdx.x * 128;
  const int bn = blockIdx.y * 64;
  const int tm = (tid & 15) * 8;
  const int tn = (tid >> 4) * 4;
  float acc[8][4];
#pragma unroll
  for (int i = 0; i < 8; ++i)
#pragma unroll
    for (int j = 0; j < 4; ++j) acc[i][j] = 0.f;

  for (int k0 = 0; k0 < K; k0 += 32) {
#pragma unroll
    for (int l = 0; l < 4; ++l) {
      int idx = tid + l * 256;
      int r = idx >> 3;
      int kq = (idx & 7) << 2;
      int gr = bm + r;
      float4 v = make_float4(0.f, 0.f, 0.f, 0.f);
      if (gr < M) v = *(const float4*)&A[(size_t)gr * K + k0 + kq];
      As[kq + 0][r] = v.x; As[kq + 1][r] = v.y;
      As[kq + 2][r] = v.z; As[kq + 3][r] = v.w;
    }
#pragma unroll
    for (int l = 0; l < 2; ++l) {
      int idx = tid + l * 256;
      int r = idx >> 4;
      int nq = (idx & 15) << 2;
      *(float4*)&Ws[r][nq] = *(const float4*)&W[(size_t)(k0 + r) * Nc + bn + nq];
    }
    __syncthreads();
#pragma unroll
    for (int kk = 0; kk < 32; ++kk) {
      float4 a0 = *(float4*)&As[kk][tm];
      float4 a1 = *(float4*)&As[kk][tm + 4];
      float4 w4 = *(float4*)&Ws[kk][tn];
      float am[8] = {a0.x, a0.y, a0.z, a0.w, a1.x, a1.y, a1.z, a1.w};
      float wn4[4] = {w4.x, w4.y, w4.z, w4.w};
#pragma unroll
      for (int i = 0; i < 8; ++i)
#pragma unroll
        for (int j = 0; j < 4; ++j) acc[i][j] += am[i] * wn4[j];
    }
    __syncthreads();
  }
  float4 bv = make_float4(0.f, 0.f, 0.f, 0.f);
  if (bias) bv = *(const float4*)&bias[bn + tn];
#pragma unroll
  for (int i = 0; i < 8; ++i) {
    int row = bm + tm + i;
    if (row >= M) break;
    float o0 = acc[i][0] + bv.x, o1 = acc[i][1] + bv.y;
    float o2 = acc[i][2] + bv.z, o3 = acc[i][3] + bv.w;
    if (ACT == 1) {
      o0 = fmaxf(o0, 0.f); o1 = fmaxf(o1, 0.f);
      o2 = fmaxf(o2, 0.f); o3 = fmaxf(o3, 0.f);
    } else if (ACT == 2) {
      o0 = 1.f / (1.f + expf(-o0)); o1 = 1.f / (1.f + expf(-o1));
      o2 = 1.f / (1.f + expf(-o2)); o3 = 1.f / (1.f + expf(-o3));
    }
    *(float4*)&C[(size_t)row * Nc + bn + tn] = make_float4(o0, o1, o2, o3);
  }
}

// ============ BN finalize: 4-way parallel fixed-order sum of 500 partials ============
__global__ __launch_bounds__(1024)
void bn_red_k(const float* __restrict__ P, float* __restrict__ stats)
{
  __shared__ float ls[4][512];
  const int col = threadIdx.x & 255;
  const int part = threadIdx.x >> 8;      // 0..3, 125 graphs each
  float s = 0.f, s2 = 0.f;
  for (int b = part * 125; b < part * 125 + 125; ++b) {
    s  += P[(size_t)b * 512 + col];
    s2 += P[(size_t)b * 512 + 256 + col];
  }
  ls[part][col] = s;
  ls[part][256 + col] = s2;
  __syncthreads();
  if (part == 0) {
    float S  = ls[0][col] + ls[1][col] + ls[2][col] + ls[3][col];
    float S2 = ls[0][256 + col] + ls[1][256 + col] + ls[2][256 + col] + ls[3][256 + col];
    float m = S / (float)kN;
    float v = S2 / (float)kN - m * m;
    stats[512 + col] = m;
    stats[768 + col] = rsqrtf(v + BN_EPS);
  }
}

__global__ __launch_bounds__(64)
void bn_cols_k(float* __restrict__ X, int rows, int cols)
{
  const int c = blockIdx.x, t = threadIdx.x;
  float s = 0.f, s2 = 0.f;
  for (int r = t; r < rows; r += 64) {
    float v = X[(size_t)r * cols + c];
    s += v; s2 += v * v;
  }
#pragma unroll
  for (int o = 32; o; o >>= 1) { s += __shfl_xor(s, o, 64); s2 += __shfl_xor(s2, o, 64); }
  float m = s / (float)rows;
  float var = s2 / (float)rows - m * m;
  float rinv = rsqrtf(var + BN_EPS);
  for (int r = t; r < rows; r += 64)
    X[(size_t)r * cols + c] = (X[(size_t)r * cols + c] - m) * rinv;
}

__global__ __launch_bounds__(256)
void l2n_k(const float* __restrict__ X, float* __restrict__ Y, int rows)
{
  const int w = threadIdx.x >> 6, lane = threadIdx.x & 63;
  const int row = blockIdx.x * 4 + w;
  if (row >= rows) return;
  float2 v = *(const float2*)&X[(size_t)row * kH2 + lane * 2];
  float ss = v.x * v.x + v.y * v.y;
#pragma unroll
  for (int o = 32; o; o >>= 1) ss += __shfl_xor(ss, o, 64);
  float inv = 1.f / fmaxf(sqrtf(ss), 1e-12f);
  *(float2*)&Y[(size_t)row * kH2 + lane * 2] = make_float2(v.x * inv, v.y * inv);
}

// =========================================================================
extern "C" void kernel_launch(void* const* d_in, const int* in_sizes, int n_in,
                              void* d_out, int out_size, void* d_ws, size_t ws_size,
                              hipStream_t stream)
{
  const float* x        = (const float*)d_in[0];
  const int*   srcI     = (const int*)d_in[1];
  const int*   dstI     = (const int*)d_in[2];
  const float* pos_x    = (const float*)d_in[4];
  const int*   psrc     = (const int*)d_in[5];
  const int*   pdst     = (const int*)d_in[6];
  const float* neg_x    = (const float*)d_in[8];
  const int*   nsrc     = (const int*)d_in[9];
  const int*   ndst     = (const int*)d_in[10];
  const float* target_x = (const float*)d_in[12];
  const float* noise    = (const float*)d_in[13];
  const float* W_enc1   = (const float*)d_in[14];
  const float* b_enc1   = (const float*)d_in[15];
  const float* W_enc2   = (const float*)d_in[16];
  const float* b_enc2   = (const float*)d_in[17];
  const float* W_dec1   = (const float*)d_in[18];
  const float* W_dec2   = (const float*)d_in[19];
  const float* Wn1      = (const float*)d_in[20];
  const float* bn1      = (const float*)d_in[21];
  const float* Wn2      = (const float*)d_in[22];
  const float* bn2      = (const float*)d_in[23];
  const float* Ws1      = (const float*)d_in[24];
  const float* bs1      = (const float*)d_in[25];
  const float* Wp1      = (const float*)d_in[26];
  const float* bp1      = (const float*)d_in[27];
  const float* Wp2      = (const float*)d_in[28];
  const float* bp2      = (const float*)d_in[29];

  float* out  = (float*)d_out;
  float* o_z   = out;                 // N x 128
  float* o_zg  = out + 6400000;       // 500 x 128
  float* o_xr  = out + 6464000;       // N x 128
  float* o_pos = out + 12864000;      // 500 x 128
  float* o_neg = out + 12928000;
  float* o_zgm = out + 12992000;      // o_zgm||o_zpm contiguous 1000 x 128
  float* o_tz  = out + 13120000;

  // WORKSPACE MAP — identical to r23 (audited).
  float* ws = (float*)d_ws;
  _Float16* hB  = (_Float16*)ws;
  float* pstat  = ws + 6400000;
  _Float16* x16m = (_Float16*)(ws + 8000000);
  _Float16* x16p = (_Float16*)(ws + 11200000);
  _Float16* x16n = (_Float16*)(ws + 14400000);
  _Float16* z16 = (_Float16*)(ws + 19200000);
  float* zz    = ws + 22400000;
  float* t1000 = ws + 22520000;
  unsigned* CNTG = (unsigned*)(ws + 22700000);   // 1.856M u32
  int* SCG = (int*)(ws + 24600000);              // 64000 int
  float* t1    = ws + 6400000;        // target-time (pstat dead)
  float* t2    = ws + 6700000;
  _Float16* hWt = (_Float16*)(ws + 25600000);
  float* stats = ws + 25700000;
  if (ws_size < (size_t)(25921024) * sizeof(float)) return;

  _Float16* WtEnc1 = hWt;
  _Float16* WtEnc2 = hWt + 32768;
  _Float16* WtDec1 = hWt + 65536;
  _Float16* WtDec2 = hWt + 98304;
  _Float16* WtS1   = hWt + 131072;

  (void)hipFuncSetAttribute((const void*)enc1_k,
      hipFuncAttributeMaxDynamicSharedMemorySize, kLds1);
  (void)hipFuncSetAttribute((const void*)enc2_k,
      hipFuncAttributeMaxDynamicSharedMemorySize, kLds2);

  auto gg = [](int M, int Nc) {
    return dim3((unsigned)((M + 127) / 128), (unsigned)(Nc / 64), 1);
  };

  // 1. combined weight + x prep
  prep_k<<<10015, 256, 0, stream>>>(W_enc1, W_enc2, W_dec1, W_dec2, Ws1, hWt,
                                    x, pos_x, neg_x, x16m, x16p, x16n);

  // 2. phase-1 fused encoder
  enc1_k<<<dim3(kB, 3), 512, kLds1, stream>>>(
      x16m, x16p, x16n, srcI, psrc, nsrc, dstI, pdst, ndst,
      WtEnc1, WtS1, WtEnc2, b_enc1, bs1, b_enc2,
      hB, pstat, o_pos, o_neg, CNTG, SCG);

  // 3. BN finalize (4-way parallel)
  bn_red_k<<<1, 1024, 0, stream>>>(pstat, stats);

  // 4. phase-2 fused encoder (main)
  enc2_k<<<kB, 512, kLds2, stream>>>(
      hB, stats + 512, WtEnc2, b_enc2, CNTG, SCG, noise, o_z, z16, o_zg, zz);

  // 5. fused decoder
  dec_fused_k<<<782, 512, 0, stream>>>(z16, WtDec1, WtDec2, o_xr, kN);

  // 6-7. merged projection heads
  gemm_k<1><<<gg(1000, kH2), 256, 0, stream>>>(zz, Wp1, bp1, t1000, 1000, kH2, kH2);
  gemm_k<0><<<gg(1000, kH2), 256, 0, stream>>>(t1000, Wp2, bp2, o_zgm, 1000, kH2, kH2);

  // 8-11. target node encoder
  gemm_k<1><<<gg(kB, kH1), 256, 0, stream>>>(target_x, Wn1, bn1, t1, kB, kF0, kH1);
  bn_cols_k<<<256, 64, 0, stream>>>(t1, kB, kH1);
  gemm_k<0><<<gg(kB, kH2), 256, 0, stream>>>(t1, Wn2, bn2, t2, kB, kH1, kH2);
  l2n_k<<<125, 256, 0, stream>>>(t2, o_tz, kB);

  (void)in_sizes; (void)n_in; (void)out_size;
}

// Round 25
// 282.247 us; speedup vs baseline: 1.5997x; 1.1064x over previous
//
#include <hip/hip_runtime.h>
#include <math.h>

static constexpr int kN   = 50000;
static constexpr int kB   = 500;
static constexpr int kNPG = 100;
static constexpr int kEPG = 1600;
static constexpr int kESG = 800;
static constexpr int kF0  = 128;
static constexpr int kH1  = 256;
static constexpr int kH2  = 128;
#define BN_EPS 1e-5f

typedef _Float16 half8 __attribute__((ext_vector_type(8)));
typedef __attribute__((ext_vector_type(4))) float f32x4;

static constexpr int kCntW = 33;
static constexpr int kAhS  = 136;     // Adh / hT / hT2 / Xs stride (fp16)
static constexpr int kH2S  = 264;     // h2 stride (fp16)
static constexpr int kCntN = 112 * kCntW;   // 3696 u32 per graph
// enc1 LDS (bytes): Adh[112][136] @0 (30464) | hT[256][136] @30464 (69632)
//  | h2[112][264] @100096 (59136). cnt32 overlays hT pre-GEMM1; Xs[112][136]
//  overlays h2 pre-stage2 (dead by h2 write); hT2 overlays hT post-agg256;
//  scr overlays Adh post-agg128. Total 159232.
static constexpr unsigned kLds1 = 159232;
// enc2 LDS: Adh 30464 | hT2[128][136] @30464 (34816) (cnt overlays hT2). 65280.
static constexpr unsigned kLds2 = 65280;

// ============ combined prep: weights -> Wt fp16 layout; x/pos/neg -> fp16 ============
__global__ __launch_bounds__(256)
void prep_k(const float* __restrict__ s0, const float* __restrict__ s1,
            const float* __restrict__ s2, const float* __restrict__ s3,
            const float* __restrict__ s4, _Float16* __restrict__ dW,
            const float* __restrict__ x0, const float* __restrict__ x1,
            const float* __restrict__ x2, _Float16* __restrict__ d0,
            _Float16* __restrict__ d1, _Float16* __restrict__ d2)
{
  if (blockIdx.x < 640) {
    int seg = blockIdx.x >> 7;
    int idx = (blockIdx.x & 127) * 256 + threadIdx.x;
    const float* S; int Nc;
    switch (seg) {
      case 0: S = s0; Nc = 256; break;
      case 1: S = s1; Nc = 128; break;
      case 2: S = s2; Nc = 256; break;
      case 3: S = s3; Nc = 128; break;
      default: S = s4; Nc = 256; break;
    }
    int e = idx & 7, t = idx >> 3;
    int c = t % Nc, kg = t / Nc;
    dW[seg * 32768 + idx] = (_Float16)S[(size_t)(kg * 8 + e) * Nc + c];
  } else {
    const size_t idx = (size_t)(blockIdx.x - 640) * 256 + threadIdx.x;  // 2.4M
    const size_t per = (size_t)kN * 16;
    const int seg = (int)(idx / per);
    const size_t off = (idx - (size_t)seg * per) * 8;
    const float* S = (seg == 0) ? x0 : (seg == 1) ? x1 : x2;
    _Float16* D = (seg == 0) ? d0 : (seg == 1) ? d1 : d2;
    float4 u0 = *(const float4*)&S[off];
    float4 u1 = *(const float4*)&S[off + 4];
    half8 h;
    h[0] = (_Float16)u0.x; h[1] = (_Float16)u0.y;
    h[2] = (_Float16)u0.z; h[3] = (_Float16)u0.w;
    h[4] = (_Float16)u1.x; h[5] = (_Float16)u1.y;
    h[6] = (_Float16)u1.z; h[7] = (_Float16)u1.w;
    *(half8*)&D[off] = h;
  }
}

// ================= phase-1 fused encoder (per-graph blocks) =================
// blockIdx.y: 0=main (GEMM1+agg256+STATS -> hB global; also dumps cnt/scnt to
// CNTG/SCG for enc2 reuse), 1=pos, 2=neg (full chain -> mean-pool OP).
// r24 lesson: all 8 waves read the SAME 112x128 X tile -> stage it ONCE in
// LDS (Xs, coalesced, 3.5 loads/thread) instead of 28 global half8/lane.
__global__ __launch_bounds__(512)
void enc1_k(const _Float16* __restrict__ x0, const _Float16* __restrict__ x1,
            const _Float16* __restrict__ x2,
            const int* __restrict__ src0, const int* __restrict__ src1,
            const int* __restrict__ src2,
            const int* __restrict__ dst0, const int* __restrict__ dst1,
            const int* __restrict__ dst2,
            const _Float16* __restrict__ Wt1m, const _Float16* __restrict__ Wt1s,
            const _Float16* __restrict__ Wt2,
            const float* __restrict__ b1m, const float* __restrict__ b1s,
            const float* __restrict__ b2,
            _Float16* __restrict__ hB, float* __restrict__ PST,
            float* __restrict__ OP1, float* __restrict__ OP2,
            unsigned* __restrict__ CNTG, int* __restrict__ SCG)
{
  extern __shared__ __align__(16) char lds_c[];
  _Float16* Adh = (_Float16*)lds_c;                 // [112][136]
  _Float16* hT  = (_Float16*)(lds_c + 30464);       // [256][136]
  _Float16* h2  = (_Float16*)(lds_c + 100096);      // [112][264]
  unsigned* cnt32 = (unsigned*)(lds_c + 30464);     // overlay (build only)
  _Float16* Xs  = (_Float16*)(lds_c + 100096);      // overlay (pre-stage2)
  _Float16* hT2 = (_Float16*)(lds_c + 30464);       // overlay (stage 3+)
  float* scr = (float*)lds_c;                       // overlay (pool epilogue)
  __shared__ int scnt[kNPG];
  __shared__ float sdinv[kNPG];
  const int yb = blockIdx.y;
  const _Float16* X = (yb == 0) ? x0 : (yb == 1) ? x1 : x2;
  const int* srcI = (yb == 0) ? src0 : (yb == 1) ? src1 : src2;
  const int* dstI = (yb == 0) ? dst0 : (yb == 1) ? dst1 : dst2;
  const _Float16* W1 = (yb == 0) ? Wt1m : Wt1s;
  const float* bias1 = (yb == 0) ? b1m : b1s;
  const int epg = (yb == 0) ? kEPG : kESG;
  const int g = blockIdx.x, tid = threadIdx.x;
  const int base = g * kNPG;
  const size_t ebase = (size_t)g * epg;
  const int lane = tid & 63, wv = tid >> 6;
  const int l15 = lane & 15, lg = lane >> 4;

  // ---- build adjacency (deterministic integer counts)
  for (int i = tid; i < kCntN; i += 512) cnt32[i] = 0u;
  if (tid < kNPG) scnt[tid] = 0;
  __syncthreads();
  for (int e = tid; e < epg; e += 512) {
    int s = srcI[ebase + e] - base;
    int d = dstI[ebase + e] - base;
    atomicAdd(&scnt[d], 1);
    atomicAdd(&cnt32[d * kCntW + (s >> 2)], 1u << (8 * (s & 3)));
  }
  __syncthreads();
  if (tid < kNPG) sdinv[tid] = rsqrtf((float)scnt[tid] + 1.f);
  __syncthreads();
  if (yb == 0) {   // dump counts for enc2 reuse (cnt32 still live here)
    for (int i = tid; i < kCntN; i += 512) CNTG[(size_t)g * 3712 + i] = cnt32[i];
    if (tid < kNPG) SCG[g * 128 + tid] = scnt[tid];
  }
  // Adh (region 0) + Xs staging (region 100096) — disjoint, one barrier after
  for (int i = tid; i < 112 * kAhS; i += 512) {
    int d = i / kAhS, s = i - d * kAhS;
    float v = 0.f;
    if (d < 100 && s < 100) {
      unsigned w = cnt32[d * kCntW + (s >> 2)];
      unsigned c = (w >> (8 * (s & 3))) & 0xFFu;
      c += (s == d) ? 1u : 0u;
      v = (float)c * sdinv[s] * sdinv[d];
    }
    Adh[i] = (_Float16)v;
  }
  for (int i = tid; i < 112 * 16; i += 512) {   // Xs[r][c], coalesced
    int r = i >> 4, cq = (i & 15) * 8;
    int row = min(base + r, kN - 1);
    *(half8*)&Xs[r * kAhS + cq] = *(const half8*)&X[(size_t)row * 128 + cq];
  }
  __syncthreads();   // cnt dead; hT region writable; Xs ready

  // ---- stage 1: GEMM1 (7 m-tiles = 112 rows; N=256, K=128), A from LDS -> hT^T
  {
    f32x4 a1[7][2];
#pragma unroll
    for (int mt = 0; mt < 7; ++mt) {
      a1[mt][0] = (f32x4){0.f, 0.f, 0.f, 0.f};
      a1[mt][1] = (f32x4){0.f, 0.f, 0.f, 0.f};
    }
    const int bc0 = wv * 32 + l15;
#pragma unroll
    for (int ks = 0; ks < 4; ++ks) {
      const int kb = ks * 32 + lg * 8;
      half8 bF[2];
#pragma unroll
      for (int t = 0; t < 2; ++t)
        bF[t] = *(const half8*)&W1[((size_t)(ks * 4 + lg) * 256 + bc0 + t * 16) * 8];
#pragma unroll
      for (int mt = 0; mt < 7; ++mt) {
        half8 aF = *(const half8*)&Xs[(mt * 16 + l15) * kAhS + kb];
#pragma unroll
        for (int t = 0; t < 2; ++t)
          a1[mt][t] = __builtin_amdgcn_mfma_f32_16x16x32_f16(aF, bF[t], a1[mt][t], 0, 0, 0);
      }
    }
#pragma unroll
    for (int mt = 0; mt < 7; ++mt)
#pragma unroll
      for (int t = 0; t < 2; ++t)
#pragma unroll
        for (int q = 0; q < 4; ++q) {
          int col = wv * 32 + t * 16 + l15;
          int j = mt * 16 + lg * 4 + q;             // 0..111
          hT[col * kAhS + j] = (_Float16)a1[mt][t][q];
        }
    for (int i = tid; i < 256 * 16; i += 512) {      // zero-fill j 112..127
      int c = i >> 4, j = 112 + (i & 15);
      hT[c * kAhS + j] = (_Float16)0.f;
    }
  }
  __syncthreads();

  // ---- stage 2: agg256 (M=112, cols wv*32..+31) + bias + relu + stats/segBN
  {
    f32x4 a2[7][2];
#pragma unroll
    for (int mt = 0; mt < 7; ++mt) {
      a2[mt][0] = (f32x4){0.f, 0.f, 0.f, 0.f};
      a2[mt][1] = (f32x4){0.f, 0.f, 0.f, 0.f};
    }
#pragma unroll
    for (int ks = 0; ks < 4; ++ks) {
      const int kb = ks * 32 + lg * 8;
      half8 bF[2];
#pragma unroll
      for (int t = 0; t < 2; ++t)
        bF[t] = *(const half8*)&hT[(wv * 32 + t * 16 + l15) * kAhS + kb];
#pragma unroll
      for (int mt = 0; mt < 7; ++mt) {
        half8 aF = *(const half8*)&Adh[(mt * 16 + l15) * kAhS + kb];
        a2[mt][0] = __builtin_amdgcn_mfma_f32_16x16x32_f16(aF, bF[0], a2[mt][0], 0, 0, 0);
        a2[mt][1] = __builtin_amdgcn_mfma_f32_16x16x32_f16(aF, bF[1], a2[mt][1], 0, 0, 0);
      }
    }
    float bv0 = bias1[wv * 32 + l15];
    float bv1 = bias1[wv * 32 + 16 + l15];
#pragma unroll
    for (int mt = 0; mt < 7; ++mt)
#pragma unroll
      for (int q = 0; q < 4; ++q) {
        a2[mt][0][q] = fmaxf(a2[mt][0][q] + bv0, 0.f);
        a2[mt][1][q] = fmaxf(a2[mt][1][q] + bv1, 0.f);
      }
    float s0 = 0.f, s20 = 0.f, s1 = 0.f, s21 = 0.f;
#pragma unroll
    for (int mt = 0; mt < 7; ++mt)
#pragma unroll
      for (int q = 0; q < 4; ++q) {
        int row = mt * 16 + lg * 4 + q;
        if (row < 100) {
          float v0 = a2[mt][0][q], v1 = a2[mt][1][q];
          s0 += v0; s20 += v0 * v0; s1 += v1; s21 += v1 * v1;
        }
      }
    s0 += __shfl_xor(s0, 16, 64);  s0 += __shfl_xor(s0, 32, 64);
    s20 += __shfl_xor(s20, 16, 64); s20 += __shfl_xor(s20, 32, 64);
    s1 += __shfl_xor(s1, 16, 64);  s1 += __shfl_xor(s1, 32, 64);
    s21 += __shfl_xor(s21, 16, 64); s21 += __shfl_xor(s21, 32, 64);
    if (yb == 0) {
      if (lg == 0) {
        PST[(size_t)g * 512 + wv * 32 + l15] = s0;
        PST[(size_t)g * 512 + 256 + wv * 32 + l15] = s20;
        PST[(size_t)g * 512 + wv * 32 + 16 + l15] = s1;
        PST[(size_t)g * 512 + 256 + wv * 32 + 16 + l15] = s21;
      }
#pragma unroll
      for (int mt = 0; mt < 7; ++mt)
#pragma unroll
        for (int q = 0; q < 4; ++q) {
          int row = mt * 16 + lg * 4 + q;
          if (row < 100) {
            hB[(size_t)(base + row) * 256 + wv * 32 + l15] = (_Float16)a2[mt][0][q];
            hB[(size_t)(base + row) * 256 + wv * 32 + 16 + l15] = (_Float16)a2[mt][1][q];
          }
        }
    } else {
      float m0 = s0 / 100.f, r0 = rsqrtf(s20 / 100.f - m0 * m0 + BN_EPS);
      float m1 = s1 / 100.f, r1 = rsqrtf(s21 / 100.f - m1 * m1 + BN_EPS);
      __syncthreads();                 // Xs reads done (stage 1) -> h2 writable
#pragma unroll
      for (int mt = 0; mt < 7; ++mt)
#pragma unroll
        for (int q = 0; q < 4; ++q) {
          int row = mt * 16 + lg * 4 + q;
          h2[row * kH2S + wv * 32 + l15] = (_Float16)((a2[mt][0][q] - m0) * r0);
          h2[row * kH2S + wv * 32 + 16 + l15] = (_Float16)((a2[mt][1][q] - m1) * r1);
        }
    }
  }
  if (yb == 0) return;   // block-uniform exit (main phase-A done)

  __syncthreads();   // h2 complete; hT reads done -> hT2 region writable

  // ---- stage 3: GEMM2 (M=112 via wave=mt, N=128, K=256) -> hT2^T
  {
    for (int i = tid; i < 128 * 16; i += 512) {          // zero pad rows 112..127
      int c = i >> 4, j = 112 + (i & 15);
      hT2[c * kAhS + j] = (_Float16)0.f;
    }
    const int mt = wv;
    f32x4 a3[8];
#pragma unroll
    for (int nt = 0; nt < 8; ++nt) a3[nt] = (f32x4){0.f, 0.f, 0.f, 0.f};
    if (mt < 7) {
#pragma unroll
      for (int ks = 0; ks < 8; ++ks) {
        const int kb = ks * 32 + lg * 8;
        half8 aF = *(const half8*)&h2[(mt * 16 + l15) * kH2S + kb];
#pragma unroll
        for (int nt = 0; nt < 8; ++nt) {
          half8 bF = *(const half8*)&Wt2[((size_t)(ks * 4 + lg) * 128 + nt * 16 + l15) * 8];
          a3[nt] = __builtin_amdgcn_mfma_f32_16x16x32_f16(aF, bF, a3[nt], 0, 0, 0);
        }
      }
#pragma unroll
      for (int nt = 0; nt < 8; ++nt)
#pragma unroll
        for (int q = 0; q < 4; ++q) {
          int col = nt * 16 + l15;
          int j = mt * 16 + lg * 4 + q;
          hT2[col * kAhS + j] = (_Float16)a3[nt][q];
        }
    }
  }
  __syncthreads();

  // ---- stage 4: agg128 + bias + l2norm + mean-pool
  {
    const int mt = wv;
    f32x4 a4[8];
#pragma unroll
    for (int nt = 0; nt < 8; ++nt) a4[nt] = (f32x4){0.f, 0.f, 0.f, 0.f};
    if (mt < 7) {
#pragma unroll
      for (int ks = 0; ks < 4; ++ks) {
        const int kb = ks * 32 + lg * 8;
        half8 aF = *(const half8*)&Adh[(mt * 16 + l15) * kAhS + kb];
#pragma unroll
        for (int nt = 0; nt < 8; ++nt) {
          half8 bF = *(const half8*)&hT2[(nt * 16 + l15) * kAhS + kb];
          a4[nt] = __builtin_amdgcn_mfma_f32_16x16x32_f16(aF, bF, a4[nt], 0, 0, 0);
        }
      }
#pragma unroll
      for (int nt = 0; nt < 8; ++nt) {
        float bvn = b2[nt * 16 + l15];
#pragma unroll
        for (int q = 0; q < 4; ++q) a4[nt][q] += bvn;
      }
#pragma unroll
      for (int q = 0; q < 4; ++q) {
        float ss = 0.f;
#pragma unroll
        for (int nt = 0; nt < 8; ++nt) ss += a4[nt][q] * a4[nt][q];
        ss += __shfl_xor(ss, 1, 64); ss += __shfl_xor(ss, 2, 64);
        ss += __shfl_xor(ss, 4, 64); ss += __shfl_xor(ss, 8, 64);
        float inv = 1.f / fmaxf(sqrtf(ss), 1e-12f);
#pragma unroll
        for (int nt = 0; nt < 8; ++nt) a4[nt][q] *= inv;
      }
    }
    float ps[8];
#pragma unroll
    for (int nt = 0; nt < 8; ++nt) ps[nt] = 0.f;
    if (mt < 7) {
#pragma unroll
      for (int nt = 0; nt < 8; ++nt)
#pragma unroll
        for (int q = 0; q < 4; ++q) {
          int row = mt * 16 + lg * 4 + q;
          if (row < 100) ps[nt] += a4[nt][q];
        }
    }
#pragma unroll
    for (int nt = 0; nt < 8; ++nt) {
      ps[nt] += __shfl_xor(ps[nt], 16, 64);
      ps[nt] += __shfl_xor(ps[nt], 32, 64);
    }
    __syncthreads();                  // Adh dead -> scr
    if (mt < 7 && lg == 0)
#pragma unroll
      for (int nt = 0; nt < 8; ++nt) scr[wv * 128 + nt * 16 + l15] = ps[nt];
    __syncthreads();
    if (tid < 128) {
      float s = 0.f;
      for (int w2 = 0; w2 < 7; ++w2) s += scr[w2 * 128 + tid];
      float* OP = (yb == 1) ? OP1 : OP2;
      OP[(size_t)g * 128 + tid] = s / 100.f;
    }
  }
}

// ================= phase-2 fused encoder (main): hB -> BN -> GEMM2 -> agg128 =================
__global__ __launch_bounds__(512)
void enc2_k(const _Float16* __restrict__ hB, const float* __restrict__ tr,
            const _Float16* __restrict__ Wt2, const float* __restrict__ b2,
            const unsigned* __restrict__ CNTG, const int* __restrict__ SCG,
            const float* __restrict__ NOI,
            float* __restrict__ OZ, _Float16* __restrict__ Z16,
            float* __restrict__ ZG, float* __restrict__ ZZ)
{
  extern __shared__ __align__(16) char lds_c[];
  _Float16* Adh = (_Float16*)lds_c;                 // [112][136]
  _Float16* hT2 = (_Float16*)(lds_c + 30464);       // [128][136]
  unsigned* cnt32 = (unsigned*)(lds_c + 30464);     // overlay (build only)
  float* scr = (float*)lds_c;                       // overlay (epilogue)
  __shared__ float sdinv[kNPG];
  const int g = blockIdx.x, tid = threadIdx.x;
  const int base = g * kNPG;
  const int lane = tid & 63, wv = tid >> 6;
  const int l15 = lane & 15, lg = lane >> 4;

  for (int i = tid; i < kCntN; i += 512) cnt32[i] = CNTG[(size_t)g * 3712 + i];
  if (tid < kNPG) sdinv[tid] = rsqrtf((float)SCG[g * 128 + tid] + 1.f);
  __syncthreads();
  for (int i = tid; i < 112 * kAhS; i += 512) {
    int d = i / kAhS, s = i - d * kAhS;
    float v = 0.f;
    if (d < 100 && s < 100) {
      unsigned w = cnt32[d * kCntW + (s >> 2)];
      unsigned c = (w >> (8 * (s & 3))) & 0xFFu;
      c += (s == d) ? 1u : 0u;
      v = (float)c * sdinv[s] * sdinv[d];
    }
    Adh[i] = (_Float16)v;
  }
  __syncthreads();   // cnt dead -> hT2 writable

  {
    const int mt = wv;
    const int r = min(base + mt * 16 + l15, kN - 1);
    f32x4 a3[8];
#pragma unroll
    for (int nt = 0; nt < 8; ++nt) a3[nt] = (f32x4){0.f, 0.f, 0.f, 0.f};
#pragma unroll
    for (int ks = 0; ks < 8; ++ks) {
      const int kb = ks * 32 + lg * 8;
      half8 h = *(const half8*)&hB[(size_t)r * 256 + kb];
      half8 aF;
#pragma unroll
      for (int j = 0; j < 8; ++j)
        aF[j] = (_Float16)(((float)h[j] - tr[kb + j]) * tr[256 + kb + j]);
#pragma unroll
      for (int nt = 0; nt < 8; ++nt) {
        half8 bF = *(const half8*)&Wt2[((size_t)(ks * 4 + lg) * 128 + nt * 16 + l15) * 8];
        a3[nt] = __builtin_amdgcn_mfma_f32_16x16x32_f16(aF, bF, a3[nt], 0, 0, 0);
      }
    }
#pragma unroll
    for (int nt = 0; nt < 8; ++nt)
#pragma unroll
      for (int q = 0; q < 4; ++q) {
        int col = nt * 16 + l15;
        int j = mt * 16 + lg * 4 + q;
        hT2[col * kAhS + j] = (_Float16)a3[nt][q];
      }
  }
  __syncthreads();

  {
    const int mt = wv;
    f32x4 a4[8];
#pragma unroll
    for (int nt = 0; nt < 8; ++nt) a4[nt] = (f32x4){0.f, 0.f, 0.f, 0.f};
    if (mt < 7) {
#pragma unroll
      for (int ks = 0; ks < 4; ++ks) {
        const int kb = ks * 32 + lg * 8;
        half8 aF = *(const half8*)&Adh[(mt * 16 + l15) * kAhS + kb];
#pragma unroll
        for (int nt = 0; nt < 8; ++nt) {
          half8 bF = *(const half8*)&hT2[(nt * 16 + l15) * kAhS + kb];
          a4[nt] = __builtin_amdgcn_mfma_f32_16x16x32_f16(aF, bF, a4[nt], 0, 0, 0);
        }
      }
#pragma unroll
      for (int nt = 0; nt < 8; ++nt) {
        float bvn = b2[nt * 16 + l15];
#pragma unroll
        for (int q = 0; q < 4; ++q) a4[nt][q] += bvn;
      }
#pragma unroll
      for (int q = 0; q < 4; ++q) {
        float ss = 0.f;
#pragma unroll
        for (int nt = 0; nt < 8; ++nt) ss += a4[nt][q] * a4[nt][q];
        ss += __shfl_xor(ss, 1, 64); ss += __shfl_xor(ss, 2, 64);
        ss += __shfl_xor(ss, 4, 64); ss += __shfl_xor(ss, 8, 64);
        float inv = 1.f / fmaxf(sqrtf(ss), 1e-12f);
#pragma unroll
        for (int nt = 0; nt < 8; ++nt) a4[nt][q] *= inv;
      }
#pragma unroll
      for (int nt = 0; nt < 8; ++nt)
#pragma unroll
        for (int q = 0; q < 4; ++q) {
          int row = mt * 16 + lg * 4 + q;
          if (row < 100) {
            OZ[(size_t)(base + row) * 128 + nt * 16 + l15] = a4[nt][q];
            Z16[(size_t)(base + row) * 128 + nt * 16 + l15] = (_Float16)a4[nt][q];
          }
        }
    }
    float m1[8], m2[8];
#pragma unroll
    for (int nt = 0; nt < 8; ++nt) { m1[nt] = -INFINITY; m2[nt] = -INFINITY; }
    if (mt < 7) {
#pragma unroll
      for (int nt = 0; nt < 8; ++nt)
#pragma unroll
        for (int q = 0; q < 4; ++q) {
          int row = mt * 16 + lg * 4 + q;
          if (row < 100) {
            float zv = a4[nt][q];
            float nv = NOI[(size_t)(base + row) * 128 + nt * 16 + l15];
            m1[nt] = fmaxf(m1[nt], zv);
            m2[nt] = fmaxf(m2[nt], zv + nv);
          }
        }
#pragma unroll
      for (int nt = 0; nt < 8; ++nt) {
        m1[nt] = fmaxf(m1[nt], __shfl_xor(m1[nt], 16, 64));
        m1[nt] = fmaxf(m1[nt], __shfl_xor(m1[nt], 32, 64));
        m2[nt] = fmaxf(m2[nt], __shfl_xor(m2[nt], 16, 64));
        m2[nt] = fmaxf(m2[nt], __shfl_xor(m2[nt], 32, 64));
      }
    }
    __syncthreads();                  // Adh dead -> scr
    if (mt < 7 && lg == 0)
#pragma unroll
      for (int nt = 0; nt < 8; ++nt) {
        scr[wv * 128 + nt * 16 + l15] = m1[nt];
        scr[1024 + wv * 128 + nt * 16 + l15] = m2[nt];
      }
    __syncthreads();
    if (tid < 128) {
      float a = -INFINITY, b = -INFINITY;
      for (int w2 = 0; w2 < 7; ++w2) {
        a = fmaxf(a, scr[w2 * 128 + tid]);
        b = fmaxf(b, scr[1024 + w2 * 128 + tid]);
      }
      ZG[(size_t)g * 128 + tid] = a;
      ZZ[(size_t)g * 128 + tid] = a;
      ZZ[(size_t)(500 + g) * 128 + tid] = b;
    }
  }
}

// ================= fused decoder: o_xr = sigmoid(relu(z16@W1)@W2) =================
__global__ __launch_bounds__(512)
void dec_fused_k(const _Float16* __restrict__ Z, const _Float16* __restrict__ Wt1,
                 const _Float16* __restrict__ Wt2, float* __restrict__ XR, int M)
{
  __shared__ alignas(16) _Float16 Hrm[64][264];
  const int tid = threadIdx.x;
  const int lane = tid & 63;
  const int l15 = lane & 15, lg = lane >> 4;
  const int wave = tid >> 6;
  const int wm = wave >> 2;
  const int wn = wave & 3;
  const int bm = blockIdx.x * 64;

  f32x4 acc[2][4];
#pragma unroll
  for (int m = 0; m < 2; ++m)
#pragma unroll
    for (int n = 0; n < 4; ++n) acc[m][n] = (f32x4){0.f, 0.f, 0.f, 0.f};
  int arow[2];
#pragma unroll
  for (int m = 0; m < 2; ++m)
    arow[m] = min(bm + wm * 32 + m * 16 + l15, M - 1);
  const int bcol = wn * 64 + l15;
#pragma unroll
  for (int ks = 0; ks < 4; ++ks) {
    const int kb = ks * 32 + lg * 8;
    half8 bF[4];
#pragma unroll
    for (int n = 0; n < 4; ++n)
      bF[n] = *(const half8*)&Wt1[((size_t)(ks * 4 + lg) * 256 + bcol + n * 16) * 8];
    half8 aF[2];
#pragma unroll
    for (int m = 0; m < 2; ++m)
      aF[m] = *(const half8*)&Z[(size_t)arow[m] * 128 + kb];
#pragma unroll
    for (int m = 0; m < 2; ++m)
#pragma unroll
      for (int n = 0; n < 4; ++n)
        acc[m][n] = __builtin_amdgcn_mfma_f32_16x16x32_f16(aF[m], bF[n], acc[m][n], 0, 0, 0);
  }
#pragma unroll
  for (int m = 0; m < 2; ++m)
#pragma unroll
    for (int q = 0; q < 4; ++q) {
      int lrow = wm * 32 + m * 16 + lg * 4 + q;
#pragma unroll
      for (int n = 0; n < 4; ++n)
        Hrm[lrow][wn * 64 + n * 16 + l15] = (_Float16)fmaxf(acc[m][n][q], 0.f);
    }
  __syncthreads();

  const int wm2 = wave & 1, wn2 = wave >> 1;
  f32x4 acc2[2][2];
#pragma unroll
  for (int m = 0; m < 2; ++m)
#pragma unroll
    for (int n = 0; n < 2; ++n) acc2[m][n] = (f32x4){0.f, 0.f, 0.f, 0.f};
#pragma unroll
  for (int ks = 0; ks < 8; ++ks) {
    const int kb = ks * 32 + lg * 8;
    half8 aF[2];
#pragma unroll
    for (int m = 0; m < 2; ++m)
      aF[m] = *(const half8*)&Hrm[wm2 * 32 + m * 16 + l15][kb];
    half8 bF[2];
#pragma unroll
    for (int n = 0; n < 2; ++n)
      bF[n] = *(const half8*)&Wt2[((size_t)(ks * 4 + lg) * 128 + wn2 * 32 + n * 16 + l15) * 8];
#pragma unroll
    for (int m = 0; m < 2; ++m)
#pragma unroll
      for (int n = 0; n < 2; ++n)
        acc2[m][n] = __builtin_amdgcn_mfma_f32_16x16x32_f16(aF[m], bF[n], acc2[m][n], 0, 0, 0);
  }
#pragma unroll
  for (int m = 0; m < 2; ++m)
#pragma unroll
    for (int q = 0; q < 4; ++q) {
      int row = bm + wm2 * 32 + m * 16 + lg * 4 + q;
      if (row >= M) continue;
#pragma unroll
      for (int n = 0; n < 2; ++n) {
        float v = acc2[m][n][q];
        XR[(size_t)row * 128 + wn2 * 32 + n * 16 + l15] = 1.f / (1.f + expf(-v));
      }
    }
}

// ======================= small-M tiled f32 GEMM (M<=1000 paths) =======================
template<int ACT>
__global__ __launch_bounds__(256)
void gemm_k(const float* __restrict__ A, const float* __restrict__ W,
            const float* __restrict__ bias, float* __restrict__ C,
            int M, int K, int Nc)
{
  __shared__ float As[32][136];
  __shared__ float Ws[32][68];
  const int tid = threadIdx.x;
  const int bm = blockIdx.x * 128;
  const int bn = blockIdx.y * 64;
  const int tm = (tid & 15) * 8;
  const int tn = (tid >> 4) * 4;
  float acc[8][4];
#pragma unroll
  for (int i = 0; i < 8; ++i)
#pragma unroll
    for (int j = 0; j < 4; ++j) acc[i][j] = 0.f;

  for (int k0 = 0; k0 < K; k0 += 32) {
#pragma unroll
    for (int l = 0; l < 4; ++l) {
      int idx = tid + l * 256;
      int r = idx >> 3;
      int kq = (idx & 7) << 2;
      int gr = bm + r;
      float4 v = make_float4(0.f, 0.f, 0.f, 0.f);
      if (gr < M) v = *(const float4*)&A[(size_t)gr * K + k0 + kq];
      As[kq + 0][r] = v.x; As[kq + 1][r] = v.y;
      As[kq + 2][r] = v.z; As[kq + 3][r] = v.w;
    }
#pragma unroll
    for (int l = 0; l < 2; ++l) {
      int idx = tid + l * 256;
      int r = idx >> 4;
      int nq = (idx & 15) << 2;
      *(float4*)&Ws[r][nq] = *(const float4*)&W[(size_t)(k0 + r) * Nc + bn + nq];
    }
    __syncthreads();
#pragma unroll
    for (int kk = 0; kk < 32; ++kk) {
      float4 a0 = *(float4*)&As[kk][tm];
      float4 a1 = *(float4*)&As[kk][tm + 4];
      float4 w4 = *(float4*)&Ws[kk][tn];
      float am[8] = {a0.x, a0.y, a0.z, a0.w, a1.x, a1.y, a1.z, a1.w};
      float wn4[4] = {w4.x, w4.y, w4.z, w4.w};
#pragma unroll
      for (int i = 0; i < 8; ++i)
#pragma unroll
        for (int j = 0; j < 4; ++j) acc[i][j] += am[i] * wn4[j];
    }
    __syncthreads();
  }
  float4 bv = make_float4(0.f, 0.f, 0.f, 0.f);
  if (bias) bv = *(const float4*)&bias[bn + tn];
#pragma unroll
  for (int i = 0; i < 8; ++i) {
    int row = bm + tm + i;
    if (row >= M) break;
    float o0 = acc[i][0] + bv.x, o1 = acc[i][1] + bv.y;
    float o2 = acc[i][2] + bv.z, o3 = acc[i][3] + bv.w;
    if (ACT == 1) {
      o0 = fmaxf(o0, 0.f); o1 = fmaxf(o1, 0.f);
      o2 = fmaxf(o2, 0.f); o3 = fmaxf(o3, 0.f);
    } else if (ACT == 2) {
      o0 = 1.f / (1.f + expf(-o0)); o1 = 1.f / (1.f + expf(-o1));
      o2 = 1.f / (1.f + expf(-o2)); o3 = 1.f / (1.f + expf(-o3));
    }
    *(float4*)&C[(size_t)row * Nc + bn + tn] = make_float4(o0, o1, o2, o3);
  }
}

// ============ BN finalize: 4-way parallel fixed-order sum of 500 partials ============
__global__ __launch_bounds__(1024)
void bn_red_k(const float* __restrict__ P, float* __restrict__ stats)
{
  __shared__ float ls[4][512];
  const int col = threadIdx.x & 255;
  const int part = threadIdx.x >> 8;      // 0..3, 125 graphs each
  float s = 0.f, s2 = 0.f;
  for (int b = part * 125; b < part * 125 + 125; ++b) {
    s  += P[(size_t)b * 512 + col];
    s2 += P[(size_t)b * 512 + 256 + col];
  }
  ls[part][col] = s;
  ls[part][256 + col] = s2;
  __syncthreads();
  if (part == 0) {
    float S  = ls[0][col] + ls[1][col] + ls[2][col] + ls[3][col];
    float S2 = ls[0][256 + col] + ls[1][256 + col] + ls[2][256 + col] + ls[3][256 + col];
    float m = S / (float)kN;
    float v = S2 / (float)kN - m * m;
    stats[512 + col] = m;
    stats[768 + col] = rsqrtf(v + BN_EPS);
  }
}

__global__ __launch_bounds__(64)
void bn_cols_k(float* __restrict__ X, int rows, int cols)
{
  const int c = blockIdx.x, t = threadIdx.x;
  float s = 0.f, s2 = 0.f;
  for (int r = t; r < rows; r += 64) {
    float v = X[(size_t)r * cols + c];
    s += v; s2 += v * v;
  }
#pragma unroll
  for (int o = 32; o; o >>= 1) { s += __shfl_xor(s, o, 64); s2 += __shfl_xor(s2, o, 64); }
  float m = s / (float)rows;
  float var = s2 / (float)rows - m * m;
  float rinv = rsqrtf(var + BN_EPS);
  for (int r = t; r < rows; r += 64)
    X[(size_t)r * cols + c] = (X[(size_t)r * cols + c] - m) * rinv;
}

__global__ __launch_bounds__(256)
void l2n_k(const float* __restrict__ X, float* __restrict__ Y, int rows)
{
  const int w = threadIdx.x >> 6, lane = threadIdx.x & 63;
  const int row = blockIdx.x * 4 + w;
  if (row >= rows) return;
  float2 v = *(const float2*)&X[(size_t)row * kH2 + lane * 2];
  float ss = v.x * v.x + v.y * v.y;
#pragma unroll
  for (int o = 32; o; o >>= 1) ss += __shfl_xor(ss, o, 64);
  float inv = 1.f / fmaxf(sqrtf(ss), 1e-12f);
  *(float2*)&Y[(size_t)row * kH2 + lane * 2] = make_float2(v.x * inv, v.y * inv);
}

// =========================================================================
extern "C" void kernel_launch(void* const* d_in, const int* in_sizes, int n_in,
                              void* d_out, int out_size, void* d_ws, size_t ws_size,
                              hipStream_t stream)
{
  const float* x        = (const float*)d_in[0];
  const int*   srcI     = (const int*)d_in[1];
  const int*   dstI     = (const int*)d_in[2];
  const float* pos_x    = (const float*)d_in[4];
  const int*   psrc     = (const int*)d_in[5];
  const int*   pdst     = (const int*)d_in[6];
  const float* neg_x    = (const float*)d_in[8];
  const int*   nsrc     = (const int*)d_in[9];
  const int*   ndst     = (const int*)d_in[10];
  const float* target_x = (const float*)d_in[12];
  const float* noise    = (const float*)d_in[13];
  const float* W_enc1   = (const float*)d_in[14];
  const float* b_enc1   = (const float*)d_in[15];
  const float* W_enc2   = (const float*)d_in[16];
  const float* b_enc2   = (const float*)d_in[17];
  const float* W_dec1   = (const float*)d_in[18];
  const float* W_dec2   = (const float*)d_in[19];
  const float* Wn1      = (const float*)d_in[20];
  const float* bn1      = (const float*)d_in[21];
  const float* Wn2      = (const float*)d_in[22];
  const float* bn2      = (const float*)d_in[23];
  const float* Ws1      = (const float*)d_in[24];
  const float* bs1      = (const float*)d_in[25];
  const float* Wp1      = (const float*)d_in[26];
  const float* bp1      = (const float*)d_in[27];
  const float* Wp2      = (const float*)d_in[28];
  const float* bp2      = (const float*)d_in[29];

  float* out  = (float*)d_out;
  float* o_z   = out;                 // N x 128
  float* o_zg  = out + 6400000;       // 500 x 128
  float* o_xr  = out + 6464000;       // N x 128
  float* o_pos = out + 12864000;      // 500 x 128
  float* o_neg = out + 12928000;
  float* o_zgm = out + 12992000;      // o_zgm||o_zpm contiguous 1000 x 128
  float* o_tz  = out + 13120000;

  // WORKSPACE MAP — identical to r24 (audited).
  float* ws = (float*)d_ws;
  _Float16* hB  = (_Float16*)ws;
  float* pstat  = ws + 6400000;
  _Float16* x16m = (_Float16*)(ws + 8000000);
  _Float16* x16p = (_Float16*)(ws + 11200000);
  _Float16* x16n = (_Float16*)(ws + 14400000);
  _Float16* z16 = (_Float16*)(ws + 19200000);
  float* zz    = ws + 22400000;
  float* t1000 = ws + 22520000;
  unsigned* CNTG = (unsigned*)(ws + 22700000);   // 1.856M u32
  int* SCG = (int*)(ws + 24600000);              // 64000 int
  float* t1    = ws + 6400000;        // target-time (pstat dead)
  float* t2    = ws + 6700000;
  _Float16* hWt = (_Float16*)(ws + 25600000);
  float* stats = ws + 25700000;
  if (ws_size < (size_t)(25921024) * sizeof(float)) return;

  _Float16* WtEnc1 = hWt;
  _Float16* WtEnc2 = hWt + 32768;
  _Float16* WtDec1 = hWt + 65536;
  _Float16* WtDec2 = hWt + 98304;
  _Float16* WtS1   = hWt + 131072;

  (void)hipFuncSetAttribute((const void*)enc1_k,
      hipFuncAttributeMaxDynamicSharedMemorySize, kLds1);
  (void)hipFuncSetAttribute((const void*)enc2_k,
      hipFuncAttributeMaxDynamicSharedMemorySize, kLds2);

  auto gg = [](int M, int Nc) {
    return dim3((unsigned)((M + 127) / 128), (unsigned)(Nc / 64), 1);
  };

  // 1. combined weight + x prep
  prep_k<<<10015, 256, 0, stream>>>(W_enc1, W_enc2, W_dec1, W_dec2, Ws1, hWt,
                                    x, pos_x, neg_x, x16m, x16p, x16n);

  // 2. phase-1 fused encoder (X staged once in LDS)
  enc1_k<<<dim3(kB, 3), 512, kLds1, stream>>>(
      x16m, x16p, x16n, srcI, psrc, nsrc, dstI, pdst, ndst,
      WtEnc1, WtS1, WtEnc2, b_enc1, bs1, b_enc2,
      hB, pstat, o_pos, o_neg, CNTG, SCG);

  // 3. BN finalize (4-way parallel)
  bn_red_k<<<1, 1024, 0, stream>>>(pstat, stats);

  // 4. phase-2 fused encoder (main)
  enc2_k<<<kB, 512, kLds2, stream>>>(
      hB, stats + 512, WtEnc2, b_enc2, CNTG, SCG, noise, o_z, z16, o_zg, zz);

  // 5. fused decoder
  dec_fused_k<<<782, 512, 0, stream>>>(z16, WtDec1, WtDec2, o_xr, kN);

  // 6-7. merged projection heads
  gemm_k<1><<<gg(1000, kH2), 256, 0, stream>>>(zz, Wp1, bp1, t1000, 1000, kH2, kH2);
  gemm_k<0><<<gg(1000, kH2), 256, 0, stream>>>(t1000, Wp2, bp2, o_zgm, 1000, kH2, kH2);

  // 8-11. target node encoder
  gemm_k<1><<<gg(kB, kH1), 256, 0, stream>>>(target_x, Wn1, bn1, t1, kB, kF0, kH1);
  bn_cols_k<<<256, 64, 0, stream>>>(t1, kB, kH1);
  gemm_k<0><<<gg(kB, kH2), 256, 0, stream>>>(t1, Wn2, bn2, t2, kB, kH1, kH2);
  l2n_k<<<125, 256, 0, stream>>>(t2, o_tz, kB);

  (void)in_sizes; (void)n_in; (void)out_size;
}

// Round 26
// 268.110 us; speedup vs baseline: 1.6840x; 1.0527x over previous
//
#include <hip/hip_runtime.h>
#include <math.h>

static constexpr int kN   = 50000;
static constexpr int kB   = 500;
static constexpr int kNPG = 100;
static constexpr int kEPG = 1600;
static constexpr int kESG = 800;
static constexpr int kF0  = 128;
static constexpr int kH1  = 256;
static constexpr int kH2  = 128;
#define BN_EPS 1e-5f

typedef _Float16 half8 __attribute__((ext_vector_type(8)));
typedef _Float16 half4v __attribute__((ext_vector_type(4)));
typedef __attribute__((ext_vector_type(4))) float f32x4;

static constexpr int kCntW = 33;
static constexpr int kAhS  = 136;     // Adh / hT / hT2 / Xs stride (fp16)
static constexpr int kH2S  = 264;     // h2 stride (fp16)
static constexpr int kCntN = 112 * kCntW;   // 3696 u32 per graph
// enc1 LDS (bytes): Adh[112][136] @0 (30464) | hT[256][136] @30464 (69632)
//  | h2[112][264] @100096 (59136). cnt32 overlays hT pre-GEMM1; Xs[112][136]
//  overlays h2 pre-stage2 (dead by h2 write); hT2 overlays hT post-agg256;
//  scr overlays Adh post-agg128. Total 159232.
static constexpr unsigned kLds1 = 159232;
// enc2 LDS: Adh 30464 | hT2[128][136] @30464 (34816) (cnt overlays hT2). 65280.
static constexpr unsigned kLds2 = 65280;

// ============ weight prep: W[K][Nc] f32 -> Wt[(kg*Nc + c)*8 + e] fp16 ============
// r26: x-conversion dropped — enc1 stages+converts X from f32 directly (same
// RNE cast, bit-identical), saving prep's ~115MB x round-trip.
__global__ __launch_bounds__(256)
void prep_k(const float* __restrict__ s0, const float* __restrict__ s1,
            const float* __restrict__ s2, const float* __restrict__ s3,
            const float* __restrict__ s4, _Float16* __restrict__ dW)
{
  int seg = blockIdx.x >> 7;
  int idx = (blockIdx.x & 127) * 256 + threadIdx.x;
  const float* S; int Nc;
  switch (seg) {
    case 0: S = s0; Nc = 256; break;
    case 1: S = s1; Nc = 128; break;
    case 2: S = s2; Nc = 256; break;
    case 3: S = s3; Nc = 128; break;
    default: S = s4; Nc = 256; break;
  }
  int e = idx & 7, t = idx >> 3;
  int c = t % Nc, kg = t / Nc;
  dW[seg * 32768 + idx] = (_Float16)S[(size_t)(kg * 8 + e) * Nc + c];
}

// ================= phase-1 fused encoder (per-graph blocks) =================
// blockIdx.y: 0=main (GEMM1+agg256+STATS -> hB global; also dumps cnt/scnt to
// CNTG/SCG for enc2 reuse), 1=pos, 2=neg (full chain -> mean-pool OP).
// Xs staged once per block from f32 X (coalesced, 7 float4/thread, converted
// in-flight; latency covered by the Adh-build VALU window).
__global__ __launch_bounds__(512)
void enc1_k(const float* __restrict__ x0, const float* __restrict__ x1,
            const float* __restrict__ x2,
            const int* __restrict__ src0, const int* __restrict__ src1,
            const int* __restrict__ src2,
            const int* __restrict__ dst0, const int* __restrict__ dst1,
            const int* __restrict__ dst2,
            const _Float16* __restrict__ Wt1m, const _Float16* __restrict__ Wt1s,
            const _Float16* __restrict__ Wt2,
            const float* __restrict__ b1m, const float* __restrict__ b1s,
            const float* __restrict__ b2,
            _Float16* __restrict__ hB, float* __restrict__ PST,
            float* __restrict__ OP1, float* __restrict__ OP2,
            unsigned* __restrict__ CNTG, int* __restrict__ SCG)
{
  extern __shared__ __align__(16) char lds_c[];
  _Float16* Adh = (_Float16*)lds_c;                 // [112][136]
  _Float16* hT  = (_Float16*)(lds_c + 30464);       // [256][136]
  _Float16* h2  = (_Float16*)(lds_c + 100096);      // [112][264]
  unsigned* cnt32 = (unsigned*)(lds_c + 30464);     // overlay (build only)
  _Float16* Xs  = (_Float16*)(lds_c + 100096);      // overlay (pre-stage2)
  _Float16* hT2 = (_Float16*)(lds_c + 30464);       // overlay (stage 3+)
  float* scr = (float*)lds_c;                       // overlay (pool epilogue)
  __shared__ int scnt[kNPG];
  __shared__ float sdinv[kNPG];
  const int yb = blockIdx.y;
  const float* X = (yb == 0) ? x0 : (yb == 1) ? x1 : x2;
  const int* srcI = (yb == 0) ? src0 : (yb == 1) ? src1 : src2;
  const int* dstI = (yb == 0) ? dst0 : (yb == 1) ? dst1 : dst2;
  const _Float16* W1 = (yb == 0) ? Wt1m : Wt1s;
  const float* bias1 = (yb == 0) ? b1m : b1s;
  const int epg = (yb == 0) ? kEPG : kESG;
  const int g = blockIdx.x, tid = threadIdx.x;
  const int base = g * kNPG;
  const size_t ebase = (size_t)g * epg;
  const int lane = tid & 63, wv = tid >> 6;
  const int l15 = lane & 15, lg = lane >> 4;

  // ---- build adjacency (deterministic integer counts)
  for (int i = tid; i < kCntN; i += 512) cnt32[i] = 0u;
  if (tid < kNPG) scnt[tid] = 0;
  __syncthreads();
  for (int e = tid; e < epg; e += 512) {
    int s = srcI[ebase + e] - base;
    int d = dstI[ebase + e] - base;
    atomicAdd(&scnt[d], 1);
    atomicAdd(&cnt32[d * kCntW + (s >> 2)], 1u << (8 * (s & 3)));
  }
  __syncthreads();
  if (tid < kNPG) sdinv[tid] = rsqrtf((float)scnt[tid] + 1.f);
  __syncthreads();
  if (yb == 0) {   // dump counts for enc2 reuse (cnt32 still live here)
    for (int i = tid; i < kCntN; i += 512) CNTG[(size_t)g * 3712 + i] = cnt32[i];
    if (tid < kNPG) SCG[g * 128 + tid] = scnt[tid];
  }
  // Adh (region 0) + Xs staging (region 100096) — disjoint, one barrier after.
  // Xs loads f32 and converts in-flight (RNE, identical to old prep path).
  for (int i = tid; i < 112 * kAhS; i += 512) {
    int d = i / kAhS, s = i - d * kAhS;
    float v = 0.f;
    if (d < 100 && s < 100) {
      unsigned w = cnt32[d * kCntW + (s >> 2)];
      unsigned c = (w >> (8 * (s & 3))) & 0xFFu;
      c += (s == d) ? 1u : 0u;
      v = (float)c * sdinv[s] * sdinv[d];
    }
    Adh[i] = (_Float16)v;
  }
  for (int i = tid; i < 112 * 32; i += 512) {   // Xs[r][c], coalesced float4
    int r = i >> 5, cq = (i & 31) * 4;
    int row = min(base + r, kN - 1);
    float4 u = *(const float4*)&X[(size_t)row * 128 + cq];
    half4v hv;
    hv[0] = (_Float16)u.x; hv[1] = (_Float16)u.y;
    hv[2] = (_Float16)u.z; hv[3] = (_Float16)u.w;
    *(half4v*)&Xs[r * kAhS + cq] = hv;
  }
  __syncthreads();   // cnt dead; hT region writable; Xs ready

  // ---- stage 1: GEMM1 (7 m-tiles = 112 rows; N=256, K=128), A from LDS -> hT^T
  {
    f32x4 a1[7][2];
#pragma unroll
    for (int mt = 0; mt < 7; ++mt) {
      a1[mt][0] = (f32x4){0.f, 0.f, 0.f, 0.f};
      a1[mt][1] = (f32x4){0.f, 0.f, 0.f, 0.f};
    }
    const int bc0 = wv * 32 + l15;
#pragma unroll
    for (int ks = 0; ks < 4; ++ks) {
      const int kb = ks * 32 + lg * 8;
      half8 bF[2];
#pragma unroll
      for (int t = 0; t < 2; ++t)
        bF[t] = *(const half8*)&W1[((size_t)(ks * 4 + lg) * 256 + bc0 + t * 16) * 8];
#pragma unroll
      for (int mt = 0; mt < 7; ++mt) {
        half8 aF = *(const half8*)&Xs[(mt * 16 + l15) * kAhS + kb];
#pragma unroll
        for (int t = 0; t < 2; ++t)
          a1[mt][t] = __builtin_amdgcn_mfma_f32_16x16x32_f16(aF, bF[t], a1[mt][t], 0, 0, 0);
      }
    }
#pragma unroll
    for (int mt = 0; mt < 7; ++mt)
#pragma unroll
      for (int t = 0; t < 2; ++t)
#pragma unroll
        for (int q = 0; q < 4; ++q) {
          int col = wv * 32 + t * 16 + l15;
          int j = mt * 16 + lg * 4 + q;             // 0..111
          hT[col * kAhS + j] = (_Float16)a1[mt][t][q];
        }
    for (int i = tid; i < 256 * 16; i += 512) {      // zero-fill j 112..127
      int c = i >> 4, j = 112 + (i & 15);
      hT[c * kAhS + j] = (_Float16)0.f;
    }
  }
  __syncthreads();

  // ---- stage 2: agg256 (M=112, cols wv*32..+31) + bias + relu + stats/segBN
  {
    f32x4 a2[7][2];
#pragma unroll
    for (int mt = 0; mt < 7; ++mt) {
      a2[mt][0] = (f32x4){0.f, 0.f, 0.f, 0.f};
      a2[mt][1] = (f32x4){0.f, 0.f, 0.f, 0.f};
    }
#pragma unroll
    for (int ks = 0; ks < 4; ++ks) {
      const int kb = ks * 32 + lg * 8;
      half8 bF[2];
#pragma unroll
      for (int t = 0; t < 2; ++t)
        bF[t] = *(const half8*)&hT[(wv * 32 + t * 16 + l15) * kAhS + kb];
#pragma unroll
      for (int mt = 0; mt < 7; ++mt) {
        half8 aF = *(const half8*)&Adh[(mt * 16 + l15) * kAhS + kb];
        a2[mt][0] = __builtin_amdgcn_mfma_f32_16x16x32_f16(aF, bF[0], a2[mt][0], 0, 0, 0);
        a2[mt][1] = __builtin_amdgcn_mfma_f32_16x16x32_f16(aF, bF[1], a2[mt][1], 0, 0, 0);
      }
    }
    float bv0 = bias1[wv * 32 + l15];
    float bv1 = bias1[wv * 32 + 16 + l15];
#pragma unroll
    for (int mt = 0; mt < 7; ++mt)
#pragma unroll
      for (int q = 0; q < 4; ++q) {
        a2[mt][0][q] = fmaxf(a2[mt][0][q] + bv0, 0.f);
        a2[mt][1][q] = fmaxf(a2[mt][1][q] + bv1, 0.f);
      }
    float s0 = 0.f, s20 = 0.f, s1 = 0.f, s21 = 0.f;
#pragma unroll
    for (int mt = 0; mt < 7; ++mt)
#pragma unroll
      for (int q = 0; q < 4; ++q) {
        int row = mt * 16 + lg * 4 + q;
        if (row < 100) {
          float v0 = a2[mt][0][q], v1 = a2[mt][1][q];
          s0 += v0; s20 += v0 * v0; s1 += v1; s21 += v1 * v1;
        }
      }
    s0 += __shfl_xor(s0, 16, 64);  s0 += __shfl_xor(s0, 32, 64);
    s20 += __shfl_xor(s20, 16, 64); s20 += __shfl_xor(s20, 32, 64);
    s1 += __shfl_xor(s1, 16, 64);  s1 += __shfl_xor(s1, 32, 64);
    s21 += __shfl_xor(s21, 16, 64); s21 += __shfl_xor(s21, 32, 64);
    if (yb == 0) {
      if (lg == 0) {
        PST[(size_t)g * 512 + wv * 32 + l15] = s0;
        PST[(size_t)g * 512 + 256 + wv * 32 + l15] = s20;
        PST[(size_t)g * 512 + wv * 32 + 16 + l15] = s1;
        PST[(size_t)g * 512 + 256 + wv * 32 + 16 + l15] = s21;
      }
#pragma unroll
      for (int mt = 0; mt < 7; ++mt)
#pragma unroll
        for (int q = 0; q < 4; ++q) {
          int row = mt * 16 + lg * 4 + q;
          if (row < 100) {
            hB[(size_t)(base + row) * 256 + wv * 32 + l15] = (_Float16)a2[mt][0][q];
            hB[(size_t)(base + row) * 256 + wv * 32 + 16 + l15] = (_Float16)a2[mt][1][q];
          }
        }
    } else {
      float m0 = s0 / 100.f, r0 = rsqrtf(s20 / 100.f - m0 * m0 + BN_EPS);
      float m1 = s1 / 100.f, r1 = rsqrtf(s21 / 100.f - m1 * m1 + BN_EPS);
      __syncthreads();                 // Xs reads done (stage 1) -> h2 writable
#pragma unroll
      for (int mt = 0; mt < 7; ++mt)
#pragma unroll
        for (int q = 0; q < 4; ++q) {
          int row = mt * 16 + lg * 4 + q;
          h2[row * kH2S + wv * 32 + l15] = (_Float16)((a2[mt][0][q] - m0) * r0);
          h2[row * kH2S + wv * 32 + 16 + l15] = (_Float16)((a2[mt][1][q] - m1) * r1);
        }
    }
  }
  if (yb == 0) return;   // block-uniform exit (main phase-A done)

  __syncthreads();   // h2 complete; hT reads done -> hT2 region writable

  // ---- stage 3: GEMM2 (M=112 via wave=mt, N=128, K=256) -> hT2^T
  {
    for (int i = tid; i < 128 * 16; i += 512) {          // zero pad rows 112..127
      int c = i >> 4, j = 112 + (i & 15);
      hT2[c * kAhS + j] = (_Float16)0.f;
    }
    const int mt = wv;
    f32x4 a3[8];
#pragma unroll
    for (int nt = 0; nt < 8; ++nt) a3[nt] = (f32x4){0.f, 0.f, 0.f, 0.f};
    if (mt < 7) {
#pragma unroll
      for (int ks = 0; ks < 8; ++ks) {
        const int kb = ks * 32 + lg * 8;
        half8 aF = *(const half8*)&h2[(mt * 16 + l15) * kH2S + kb];
#pragma unroll
        for (int nt = 0; nt < 8; ++nt) {
          half8 bF = *(const half8*)&Wt2[((size_t)(ks * 4 + lg) * 128 + nt * 16 + l15) * 8];
          a3[nt] = __builtin_amdgcn_mfma_f32_16x16x32_f16(aF, bF, a3[nt], 0, 0, 0);
        }
      }
#pragma unroll
      for (int nt = 0; nt < 8; ++nt)
#pragma unroll
        for (int q = 0; q < 4; ++q) {
          int col = nt * 16 + l15;
          int j = mt * 16 + lg * 4 + q;
          hT2[col * kAhS + j] = (_Float16)a3[nt][q];
        }
    }
  }
  __syncthreads();

  // ---- stage 4: agg128 + bias + l2norm + mean-pool
  {
    const int mt = wv;
    f32x4 a4[8];
#pragma unroll
    for (int nt = 0; nt < 8; ++nt) a4[nt] = (f32x4){0.f, 0.f, 0.f, 0.f};
    if (mt < 7) {
#pragma unroll
      for (int ks = 0; ks < 4; ++ks) {
        const int kb = ks * 32 + lg * 8;
        half8 aF = *(const half8*)&Adh[(mt * 16 + l15) * kAhS + kb];
#pragma unroll
        for (int nt = 0; nt < 8; ++nt) {
          half8 bF = *(const half8*)&hT2[(nt * 16 + l15) * kAhS + kb];
          a4[nt] = __builtin_amdgcn_mfma_f32_16x16x32_f16(aF, bF, a4[nt], 0, 0, 0);
        }
      }
#pragma unroll
      for (int nt = 0; nt < 8; ++nt) {
        float bvn = b2[nt * 16 + l15];
#pragma unroll
        for (int q = 0; q < 4; ++q) a4[nt][q] += bvn;
      }
#pragma unroll
      for (int q = 0; q < 4; ++q) {
        float ss = 0.f;
#pragma unroll
        for (int nt = 0; nt < 8; ++nt) ss += a4[nt][q] * a4[nt][q];
        ss += __shfl_xor(ss, 1, 64); ss += __shfl_xor(ss, 2, 64);
        ss += __shfl_xor(ss, 4, 64); ss += __shfl_xor(ss, 8, 64);
        float inv = 1.f / fmaxf(sqrtf(ss), 1e-12f);
#pragma unroll
        for (int nt = 0; nt < 8; ++nt) a4[nt][q] *= inv;
      }
    }
    float ps[8];
#pragma unroll
    for (int nt = 0; nt < 8; ++nt) ps[nt] = 0.f;
    if (mt < 7) {
#pragma unroll
      for (int nt = 0; nt < 8; ++nt)
#pragma unroll
        for (int q = 0; q < 4; ++q) {
          int row = mt * 16 + lg * 4 + q;
          if (row < 100) ps[nt] += a4[nt][q];
        }
    }
#pragma unroll
    for (int nt = 0; nt < 8; ++nt) {
      ps[nt] += __shfl_xor(ps[nt], 16, 64);
      ps[nt] += __shfl_xor(ps[nt], 32, 64);
    }
    __syncthreads();                  // Adh dead -> scr
    if (mt < 7 && lg == 0)
#pragma unroll
      for (int nt = 0; nt < 8; ++nt) scr[wv * 128 + nt * 16 + l15] = ps[nt];
    __syncthreads();
    if (tid < 128) {
      float s = 0.f;
      for (int w2 = 0; w2 < 7; ++w2) s += scr[w2 * 128 + tid];
      float* OP = (yb == 1) ? OP1 : OP2;
      OP[(size_t)g * 128 + tid] = s / 100.f;
    }
  }
}

// ================= phase-2 fused encoder (main): hB -> BN -> GEMM2 -> agg128 =================
__global__ __launch_bounds__(512)
void enc2_k(const _Float16* __restrict__ hB, const float* __restrict__ tr,
            const _Float16* __restrict__ Wt2, const float* __restrict__ b2,
            const unsigned* __restrict__ CNTG, const int* __restrict__ SCG,
            const float* __restrict__ NOI,
            float* __restrict__ OZ, _Float16* __restrict__ Z16,
            float* __restrict__ ZG, float* __restrict__ ZZ)
{
  extern __shared__ __align__(16) char lds_c[];
  _Float16* Adh = (_Float16*)lds_c;                 // [112][136]
  _Float16* hT2 = (_Float16*)(lds_c + 30464);       // [128][136]
  unsigned* cnt32 = (unsigned*)(lds_c + 30464);     // overlay (build only)
  float* scr = (float*)lds_c;                       // overlay (epilogue)
  __shared__ float sdinv[kNPG];
  const int g = blockIdx.x, tid = threadIdx.x;
  const int base = g * kNPG;
  const int lane = tid & 63, wv = tid >> 6;
  const int l15 = lane & 15, lg = lane >> 4;

  for (int i = tid; i < kCntN; i += 512) cnt32[i] = CNTG[(size_t)g * 3712 + i];
  if (tid < kNPG) sdinv[tid] = rsqrtf((float)SCG[g * 128 + tid] + 1.f);
  __syncthreads();
  for (int i = tid; i < 112 * kAhS; i += 512) {
    int d = i / kAhS, s = i - d * kAhS;
    float v = 0.f;
    if (d < 100 && s < 100) {
      unsigned w = cnt32[d * kCntW + (s >> 2)];
      unsigned c = (w >> (8 * (s & 3))) & 0xFFu;
      c += (s == d) ? 1u : 0u;
      v = (float)c * sdinv[s] * sdinv[d];
    }
    Adh[i] = (_Float16)v;
  }
  __syncthreads();   // cnt dead -> hT2 writable

  {
    const int mt = wv;
    const int r = min(base + mt * 16 + l15, kN - 1);
    f32x4 a3[8];
#pragma unroll
    for (int nt = 0; nt < 8; ++nt) a3[nt] = (f32x4){0.f, 0.f, 0.f, 0.f};
#pragma unroll
    for (int ks = 0; ks < 8; ++ks) {
      const int kb = ks * 32 + lg * 8;
      half8 h = *(const half8*)&hB[(size_t)r * 256 + kb];
      half8 aF;
#pragma unroll
      for (int j = 0; j < 8; ++j)
        aF[j] = (_Float16)(((float)h[j] - tr[kb + j]) * tr[256 + kb + j]);
#pragma unroll
      for (int nt = 0; nt < 8; ++nt) {
        half8 bF = *(const half8*)&Wt2[((size_t)(ks * 4 + lg) * 128 + nt * 16 + l15) * 8];
        a3[nt] = __builtin_amdgcn_mfma_f32_16x16x32_f16(aF, bF, a3[nt], 0, 0, 0);
      }
    }
#pragma unroll
    for (int nt = 0; nt < 8; ++nt)
#pragma unroll
      for (int q = 0; q < 4; ++q) {
        int col = nt * 16 + l15;
        int j = mt * 16 + lg * 4 + q;
        hT2[col * kAhS + j] = (_Float16)a3[nt][q];
      }
  }
  __syncthreads();

  {
    const int mt = wv;
    f32x4 a4[8];
#pragma unroll
    for (int nt = 0; nt < 8; ++nt) a4[nt] = (f32x4){0.f, 0.f, 0.f, 0.f};
    if (mt < 7) {
#pragma unroll
      for (int ks = 0; ks < 4; ++ks) {
        const int kb = ks * 32 + lg * 8;
        half8 aF = *(const half8*)&Adh[(mt * 16 + l15) * kAhS + kb];
#pragma unroll
        for (int nt = 0; nt < 8; ++nt) {
          half8 bF = *(const half8*)&hT2[(nt * 16 + l15) * kAhS + kb];
          a4[nt] = __builtin_amdgcn_mfma_f32_16x16x32_f16(aF, bF, a4[nt], 0, 0, 0);
        }
      }
#pragma unroll
      for (int nt = 0; nt < 8; ++nt) {
        float bvn = b2[nt * 16 + l15];
#pragma unroll
        for (int q = 0; q < 4; ++q) a4[nt][q] += bvn;
      }
#pragma unroll
      for (int q = 0; q < 4; ++q) {
        float ss = 0.f;
#pragma unroll
        for (int nt = 0; nt < 8; ++nt) ss += a4[nt][q] * a4[nt][q];
        ss += __shfl_xor(ss, 1, 64); ss += __shfl_xor(ss, 2, 64);
        ss += __shfl_xor(ss, 4, 64); ss += __shfl_xor(ss, 8, 64);
        float inv = 1.f / fmaxf(sqrtf(ss), 1e-12f);
#pragma unroll
        for (int nt = 0; nt < 8; ++nt) a4[nt][q] *= inv;
      }
#pragma unroll
      for (int nt = 0; nt < 8; ++nt)
#pragma unroll
        for (int q = 0; q < 4; ++q) {
          int row = mt * 16 + lg * 4 + q;
          if (row < 100) {
            OZ[(size_t)(base + row) * 128 + nt * 16 + l15] = a4[nt][q];
            Z16[(size_t)(base + row) * 128 + nt * 16 + l15] = (_Float16)a4[nt][q];
          }
        }
    }
    float m1[8], m2[8];
#pragma unroll
    for (int nt = 0; nt < 8; ++nt) { m1[nt] = -INFINITY; m2[nt] = -INFINITY; }
    if (mt < 7) {
#pragma unroll
      for (int nt = 0; nt < 8; ++nt)
#pragma unroll
        for (int q = 0; q < 4; ++q) {
          int row = mt * 16 + lg * 4 + q;
          if (row < 100) {
            float zv = a4[nt][q];
            float nv = NOI[(size_t)(base + row) * 128 + nt * 16 + l15];
            m1[nt] = fmaxf(m1[nt], zv);
            m2[nt] = fmaxf(m2[nt], zv + nv);
          }
        }
#pragma unroll
      for (int nt = 0; nt < 8; ++nt) {
        m1[nt] = fmaxf(m1[nt], __shfl_xor(m1[nt], 16, 64));
        m1[nt] = fmaxf(m1[nt], __shfl_xor(m1[nt], 32, 64));
        m2[nt] = fmaxf(m2[nt], __shfl_xor(m2[nt], 16, 64));
        m2[nt] = fmaxf(m2[nt], __shfl_xor(m2[nt], 32, 64));
      }
    }
    __syncthreads();                  // Adh dead -> scr
    if (mt < 7 && lg == 0)
#pragma unroll
      for (int nt = 0; nt < 8; ++nt) {
        scr[wv * 128 + nt * 16 + l15] = m1[nt];
        scr[1024 + wv * 128 + nt * 16 + l15] = m2[nt];
      }
    __syncthreads();
    if (tid < 128) {
      float a = -INFINITY, b = -INFINITY;
      for (int w2 = 0; w2 < 7; ++w2) {
        a = fmaxf(a, scr[w2 * 128 + tid]);
        b = fmaxf(b, scr[1024 + w2 * 128 + tid]);
      }
      ZG[(size_t)g * 128 + tid] = a;
      ZZ[(size_t)g * 128 + tid] = a;
      ZZ[(size_t)(500 + g) * 128 + tid] = b;
    }
  }
}

// ================= fused decoder: o_xr = sigmoid(relu(z16@W1)@W2) =================
__global__ __launch_bounds__(512)
void dec_fused_k(const _Float16* __restrict__ Z, const _Float16* __restrict__ Wt1,
                 const _Float16* __restrict__ Wt2, float* __restrict__ XR, int M)
{
  __shared__ alignas(16) _Float16 Hrm[64][264];
  const int tid = threadIdx.x;
  const int lane = tid & 63;
  const int l15 = lane & 15, lg = lane >> 4;
  const int wave = tid >> 6;
  const int wm = wave >> 2;
  const int wn = wave & 3;
  const int bm = blockIdx.x * 64;

  f32x4 acc[2][4];
#pragma unroll
  for (int m = 0; m < 2; ++m)
#pragma unroll
    for (int n = 0; n < 4; ++n) acc[m][n] = (f32x4){0.f, 0.f, 0.f, 0.f};
  int arow[2];
#pragma unroll
  for (int m = 0; m < 2; ++m)
    arow[m] = min(bm + wm * 32 + m * 16 + l15, M - 1);
  const int bcol = wn * 64 + l15;
#pragma unroll
  for (int ks = 0; ks < 4; ++ks) {
    const int kb = ks * 32 + lg * 8;
    half8 bF[4];
#pragma unroll
    for (int n = 0; n < 4; ++n)
      bF[n] = *(const half8*)&Wt1[((size_t)(ks * 4 + lg) * 256 + bcol + n * 16) * 8];
    half8 aF[2];
#pragma unroll
    for (int m = 0; m < 2; ++m)
      aF[m] = *(const half8*)&Z[(size_t)arow[m] * 128 + kb];
#pragma unroll
    for (int m = 0; m < 2; ++m)
#pragma unroll
      for (int n = 0; n < 4; ++n)
        acc[m][n] = __builtin_amdgcn_mfma_f32_16x16x32_f16(aF[m], bF[n], acc[m][n], 0, 0, 0);
  }
#pragma unroll
  for (int m = 0; m < 2; ++m)
#pragma unroll
    for (int q = 0; q < 4; ++q) {
      int lrow = wm * 32 + m * 16 + lg * 4 + q;
#pragma unroll
      for (int n = 0; n < 4; ++n)
        Hrm[lrow][wn * 64 + n * 16 + l15] = (_Float16)fmaxf(acc[m][n][q], 0.f);
    }
  __syncthreads();

  const int wm2 = wave & 1, wn2 = wave >> 1;
  f32x4 acc2[2][2];
#pragma unroll
  for (int m = 0; m < 2; ++m)
#pragma unroll
    for (int n = 0; n < 2; ++n) acc2[m][n] = (f32x4){0.f, 0.f, 0.f, 0.f};
#pragma unroll
  for (int ks = 0; ks < 8; ++ks) {
    const int kb = ks * 32 + lg * 8;
    half8 aF[2];
#pragma unroll
    for (int m = 0; m < 2; ++m)
      aF[m] = *(const half8*)&Hrm[wm2 * 32 + m * 16 + l15][kb];
    half8 bF[2];
#pragma unroll
    for (int n = 0; n < 2; ++n)
      bF[n] = *(const half8*)&Wt2[((size_t)(ks * 4 + lg) * 128 + wn2 * 32 + n * 16 + l15) * 8];
#pragma unroll
    for (int m = 0; m < 2; ++m)
#pragma unroll
      for (int n = 0; n < 2; ++n)
        acc2[m][n] = __builtin_amdgcn_mfma_f32_16x16x32_f16(aF[m], bF[n], acc2[m][n], 0, 0, 0);
  }
#pragma unroll
  for (int m = 0; m < 2; ++m)
#pragma unroll
    for (int q = 0; q < 4; ++q) {
      int row = bm + wm2 * 32 + m * 16 + lg * 4 + q;
      if (row >= M) continue;
#pragma unroll
      for (int n = 0; n < 2; ++n) {
        float v = acc2[m][n][q];
        XR[(size_t)row * 128 + wn2 * 32 + n * 16 + l15] = 1.f / (1.f + expf(-v));
      }
    }
}

// ======================= small-M tiled f32 GEMM (M<=1000 paths) =======================
template<int ACT>
__global__ __launch_bounds__(256)
void gemm_k(const float* __restrict__ A, const float* __restrict__ W,
            const float* __restrict__ bias, float* __restrict__ C,
            int M, int K, int Nc)
{
  __shared__ float As[32][136];
  __shared__ float Ws[32][68];
  const int tid = threadIdx.x;
  const int bm = blockIdx.x * 128;
  const int bn = blockIdx.y * 64;
  const int tm = (tid & 15) * 8;
  const int tn = (tid >> 4) * 4;
  float acc[8][4];
#pragma unroll
  for (int i = 0; i < 8; ++i)
#pragma unroll
    for (int j = 0; j < 4; ++j) acc[i][j] = 0.f;

  for (int k0 = 0; k0 < K; k0 += 32) {
#pragma unroll
    for (int l = 0; l < 4; ++l) {
      int idx = tid + l * 256;
      int r = idx >> 3;
      int kq = (idx & 7) << 2;
      int gr = bm + r;
      float4 v = make_float4(0.f, 0.f, 0.f, 0.f);
      if (gr < M) v = *(const float4*)&A[(size_t)gr * K + k0 + kq];
      As[kq + 0][r] = v.x; As[kq + 1][r] = v.y;
      As[kq + 2][r] = v.z; As[kq + 3][r] = v.w;
    }
#pragma unroll
    for (int l = 0; l < 2; ++l) {
      int idx = tid + l * 256;
      int r = idx >> 4;
      int nq = (idx & 15) << 2;
      *(float4*)&Ws[r][nq] = *(const float4*)&W[(size_t)(k0 + r) * Nc + bn + nq];
    }
    __syncthreads();
#pragma unroll
    for (int kk = 0; kk < 32; ++kk) {
      float4 a0 = *(float4*)&As[kk][tm];
      float4 a1 = *(float4*)&As[kk][tm + 4];
      float4 w4 = *(float4*)&Ws[kk][tn];
      float am[8] = {a0.x, a0.y, a0.z, a0.w, a1.x, a1.y, a1.z, a1.w};
      float wn4[4] = {w4.x, w4.y, w4.z, w4.w};
#pragma unroll
      for (int i = 0; i < 8; ++i)
#pragma unroll
        for (int j = 0; j < 4; ++j) acc[i][j] += am[i] * wn4[j];
    }
    __syncthreads();
  }
  float4 bv = make_float4(0.f, 0.f, 0.f, 0.f);
  if (bias) bv = *(const float4*)&bias[bn + tn];
#pragma unroll
  for (int i = 0; i < 8; ++i) {
    int row = bm + tm + i;
    if (row >= M) break;
    float o0 = acc[i][0] + bv.x, o1 = acc[i][1] + bv.y;
    float o2 = acc[i][2] + bv.z, o3 = acc[i][3] + bv.w;
    if (ACT == 1) {
      o0 = fmaxf(o0, 0.f); o1 = fmaxf(o1, 0.f);
      o2 = fmaxf(o2, 0.f); o3 = fmaxf(o3, 0.f);
    } else if (ACT == 2) {
      o0 = 1.f / (1.f + expf(-o0)); o1 = 1.f / (1.f + expf(-o1));
      o2 = 1.f / (1.f + expf(-o2)); o3 = 1.f / (1.f + expf(-o3));
    }
    *(float4*)&C[(size_t)row * Nc + bn + tn] = make_float4(o0, o1, o2, o3);
  }
}

// ============ BN finalize: 4-way parallel fixed-order sum of 500 partials ============
__global__ __launch_bounds__(1024)
void bn_red_k(const float* __restrict__ P, float* __restrict__ stats)
{
  __shared__ float ls[4][512];
  const int col = threadIdx.x & 255;
  const int part = threadIdx.x >> 8;      // 0..3, 125 graphs each
  float s = 0.f, s2 = 0.f;
  for (int b = part * 125; b < part * 125 + 125; ++b) {
    s  += P[(size_t)b * 512 + col];
    s2 += P[(size_t)b * 512 + 256 + col];
  }
  ls[part][col] = s;
  ls[part][256 + col] = s2;
  __syncthreads();
  if (part == 0) {
    float S  = ls[0][col] + ls[1][col] + ls[2][col] + ls[3][col];
    float S2 = ls[0][256 + col] + ls[1][256 + col] + ls[2][256 + col] + ls[3][256 + col];
    float m = S / (float)kN;
    float v = S2 / (float)kN - m * m;
    stats[512 + col] = m;
    stats[768 + col] = rsqrtf(v + BN_EPS);
  }
}

__global__ __launch_bounds__(64)
void bn_cols_k(float* __restrict__ X, int rows, int cols)
{
  const int c = blockIdx.x, t = threadIdx.x;
  float s = 0.f, s2 = 0.f;
  for (int r = t; r < rows; r += 64) {
    float v = X[(size_t)r * cols + c];
    s += v; s2 += v * v;
  }
#pragma unroll
  for (int o = 32; o; o >>= 1) { s += __shfl_xor(s, o, 64); s2 += __shfl_xor(s2, o, 64); }
  float m = s / (float)rows;
  float var = s2 / (float)rows - m * m;
  float rinv = rsqrtf(var + BN_EPS);
  for (int r = t; r < rows; r += 64)
    X[(size_t)r * cols + c] = (X[(size_t)r * cols + c] - m) * rinv;
}

__global__ __launch_bounds__(256)
void l2n_k(const float* __restrict__ X, float* __restrict__ Y, int rows)
{
  const int w = threadIdx.x >> 6, lane = threadIdx.x & 63;
  const int row = blockIdx.x * 4 + w;
  if (row >= rows) return;
  float2 v = *(const float2*)&X[(size_t)row * kH2 + lane * 2];
  float ss = v.x * v.x + v.y * v.y;
#pragma unroll
  for (int o = 32; o; o >>= 1) ss += __shfl_xor(ss, o, 64);
  float inv = 1.f / fmaxf(sqrtf(ss), 1e-12f);
  *(float2*)&Y[(size_t)row * kH2 + lane * 2] = make_float2(v.x * inv, v.y * inv);
}

// =========================================================================
extern "C" void kernel_launch(void* const* d_in, const int* in_sizes, int n_in,
                              void* d_out, int out_size, void* d_ws, size_t ws_size,
                              hipStream_t stream)
{
  const float* x        = (const float*)d_in[0];
  const int*   srcI     = (const int*)d_in[1];
  const int*   dstI     = (const int*)d_in[2];
  const float* pos_x    = (const float*)d_in[4];
  const int*   psrc     = (const int*)d_in[5];
  const int*   pdst     = (const int*)d_in[6];
  const float* neg_x    = (const float*)d_in[8];
  const int*   nsrc     = (const int*)d_in[9];
  const int*   ndst     = (const int*)d_in[10];
  const float* target_x = (const float*)d_in[12];
  const float* noise    = (const float*)d_in[13];
  const float* W_enc1   = (const float*)d_in[14];
  const float* b_enc1   = (const float*)d_in[15];
  const float* W_enc2   = (const float*)d_in[16];
  const float* b_enc2   = (const float*)d_in[17];
  const float* W_dec1   = (const float*)d_in[18];
  const float* W_dec2   = (const float*)d_in[19];
  const float* Wn1      = (const float*)d_in[20];
  const float* bn1      = (const float*)d_in[21];
  const float* Wn2      = (const float*)d_in[22];
  const float* bn2      = (const float*)d_in[23];
  const float* Ws1      = (const float*)d_in[24];
  const float* bs1      = (const float*)d_in[25];
  const float* Wp1      = (const float*)d_in[26];
  const float* bp1      = (const float*)d_in[27];
  const float* Wp2      = (const float*)d_in[28];
  const float* bp2      = (const float*)d_in[29];

  float* out  = (float*)d_out;
  float* o_z   = out;                 // N x 128
  float* o_zg  = out + 6400000;       // 500 x 128
  float* o_xr  = out + 6464000;       // N x 128
  float* o_pos = out + 12864000;      // 500 x 128
  float* o_neg = out + 12928000;
  float* o_zgm = out + 12992000;      // o_zgm||o_zpm contiguous 1000 x 128
  float* o_tz  = out + 13120000;

  // WORKSPACE MAP — r25 layout, x16 slots now unused (enc1 reads f32 x).
  float* ws = (float*)d_ws;
  _Float16* hB  = (_Float16*)ws;
  float* pstat  = ws + 6400000;
  _Float16* z16 = (_Float16*)(ws + 19200000);
  float* zz    = ws + 22400000;
  float* t1000 = ws + 22520000;
  unsigned* CNTG = (unsigned*)(ws + 22700000);   // 1.856M u32
  int* SCG = (int*)(ws + 24600000);              // 64000 int
  float* t1    = ws + 6400000;        // target-time (pstat dead)
  float* t2    = ws + 6700000;
  _Float16* hWt = (_Float16*)(ws + 25600000);
  float* stats = ws + 25700000;
  if (ws_size < (size_t)(25921024) * sizeof(float)) return;

  _Float16* WtEnc1 = hWt;
  _Float16* WtEnc2 = hWt + 32768;
  _Float16* WtDec1 = hWt + 65536;
  _Float16* WtDec2 = hWt + 98304;
  _Float16* WtS1   = hWt + 131072;

  (void)hipFuncSetAttribute((const void*)enc1_k,
      hipFuncAttributeMaxDynamicSharedMemorySize, kLds1);
  (void)hipFuncSetAttribute((const void*)enc2_k,
      hipFuncAttributeMaxDynamicSharedMemorySize, kLds2);

  auto gg = [](int M, int Nc) {
    return dim3((unsigned)((M + 127) / 128), (unsigned)(Nc / 64), 1);
  };

  // 1. weight prep only (x conversion folded into enc1 staging)
  prep_k<<<640, 256, 0, stream>>>(W_enc1, W_enc2, W_dec1, W_dec2, Ws1, hWt);

  // 2. phase-1 fused encoder (X staged+converted from f32 in LDS)
  enc1_k<<<dim3(kB, 3), 512, kLds1, stream>>>(
      x, pos_x, neg_x, srcI, psrc, nsrc, dstI, pdst, ndst,
      WtEnc1, WtS1, WtEnc2, b_enc1, bs1, b_enc2,
      hB, pstat, o_pos, o_neg, CNTG, SCG);

  // 3. BN finalize (4-way parallel)
  bn_red_k<<<1, 1024, 0, stream>>>(pstat, stats);

  // 4. phase-2 fused encoder (main)
  enc2_k<<<kB, 512, kLds2, stream>>>(
      hB, stats + 512, WtEnc2, b_enc2, CNTG, SCG, noise, o_z, z16, o_zg, zz);

  // 5. fused decoder
  dec_fused_k<<<782, 512, 0, stream>>>(z16, WtDec1, WtDec2, o_xr, kN);

  // 6-7. merged projection heads
  gemm_k<1><<<gg(1000, kH2), 256, 0, stream>>>(zz, Wp1, bp1, t1000, 1000, kH2, kH2);
  gemm_k<0><<<gg(1000, kH2), 256, 0, stream>>>(t1000, Wp2, bp2, o_zgm, 1000, kH2, kH2);

  // 8-11. target node encoder
  gemm_k<1><<<gg(kB, kH1), 256, 0, stream>>>(target_x, Wn1, bn1, t1, kB, kF0, kH1);
  bn_cols_k<<<256, 64, 0, stream>>>(t1, kB, kH1);
  gemm_k<0><<<gg(kB, kH2), 256, 0, stream>>>(t1, Wn2, bn2, t2, kB, kH1, kH2);
  l2n_k<<<125, 256, 0, stream>>>(t2, o_tz, kB);

  (void)in_sizes; (void)n_in; (void)out_size;
}

// Round 27
// 263.844 us; speedup vs baseline: 1.7113x; 1.0162x over previous
//
#include <hip/hip_runtime.h>
#include <math.h>

static constexpr int kN   = 50000;
static constexpr int kB   = 500;
static constexpr int kNPG = 100;
static constexpr int kEPG = 1600;
static constexpr int kESG = 800;
static constexpr int kF0  = 128;
static constexpr int kH1  = 256;
static constexpr int kH2  = 128;
#define BN_EPS 1e-5f

typedef _Float16 half8 __attribute__((ext_vector_type(8)));
typedef _Float16 half4v __attribute__((ext_vector_type(4)));
typedef __attribute__((ext_vector_type(4))) float f32x4;

static constexpr int kCntW = 33;
static constexpr int kAhS  = 136;     // Adh / hT / hT2 / Xs stride (fp16)
static constexpr int kH2S  = 264;     // h2 stride (fp16)
static constexpr int kCntN = 112 * kCntW;   // 3696 u32 per graph
// enc1 LDS (bytes): Adh[112][136] @0 (30464) | hT[256][136] @30464 (69632)
//  | h2[112][264] @100096 (59136). cnt32 overlays hT pre-GEMM1; Xs[112][136]
//  overlays h2 pre-stage2 (dead by h2 write); hT2 overlays hT post-agg256;
//  scr overlays Adh post-agg128. Total 159232.
static constexpr unsigned kLds1 = 159232;
// enc2 LDS: Adh 30464 | hT2[128][136] @30464 (34816) (cnt overlays hT2). 65280.
static constexpr unsigned kLds2 = 65280;

// ============ weight prep: W[K][Nc] f32 -> Wt[(kg*Nc + c)*8 + e] fp16 ============
__global__ __launch_bounds__(256)
void prep_k(const float* __restrict__ s0, const float* __restrict__ s1,
            const float* __restrict__ s2, const float* __restrict__ s3,
            const float* __restrict__ s4, _Float16* __restrict__ dW)
{
  int seg = blockIdx.x >> 7;
  int idx = (blockIdx.x & 127) * 256 + threadIdx.x;
  const float* S; int Nc;
  switch (seg) {
    case 0: S = s0; Nc = 256; break;
    case 1: S = s1; Nc = 128; break;
    case 2: S = s2; Nc = 256; break;
    case 3: S = s3; Nc = 128; break;
    default: S = s4; Nc = 256; break;
  }
  int e = idx & 7, t = idx >> 3;
  int c = t % Nc, kg = t / Nc;
  dW[seg * 32768 + idx] = (_Float16)S[(size_t)(kg * 8 + e) * Nc + c];
}

// ================= phase-1 fused encoder (per-graph blocks) =================
// blockIdx.y: 0=main (GEMM1+agg256+STATS -> hB global; also dumps cnt/scnt to
// CNTG/SCG for enc2 reuse), 1=pos, 2=neg (full chain -> mean-pool OP).
// r26 lesson: f32 staging AFTER Adh-build exposed its latency (+22us). Fix:
// T14 async-split — issue the 7 float4 X loads FIRST (into regs, +28 VGPR,
// free at 1 block/CU), let edge-build+Adh cover ~900cy HBM latency, then
// convert+write to LDS late.
__global__ __launch_bounds__(512)
void enc1_k(const float* __restrict__ x0, const float* __restrict__ x1,
            const float* __restrict__ x2,
            const int* __restrict__ src0, const int* __restrict__ src1,
            const int* __restrict__ src2,
            const int* __restrict__ dst0, const int* __restrict__ dst1,
            const int* __restrict__ dst2,
            const _Float16* __restrict__ Wt1m, const _Float16* __restrict__ Wt1s,
            const _Float16* __restrict__ Wt2,
            const float* __restrict__ b1m, const float* __restrict__ b1s,
            const float* __restrict__ b2,
            _Float16* __restrict__ hB, float* __restrict__ PST,
            float* __restrict__ OP1, float* __restrict__ OP2,
            unsigned* __restrict__ CNTG, int* __restrict__ SCG)
{
  extern __shared__ __align__(16) char lds_c[];
  _Float16* Adh = (_Float16*)lds_c;                 // [112][136]
  _Float16* hT  = (_Float16*)(lds_c + 30464);       // [256][136]
  _Float16* h2  = (_Float16*)(lds_c + 100096);      // [112][264]
  unsigned* cnt32 = (unsigned*)(lds_c + 30464);     // overlay (build only)
  _Float16* Xs  = (_Float16*)(lds_c + 100096);      // overlay (pre-stage2)
  _Float16* hT2 = (_Float16*)(lds_c + 30464);       // overlay (stage 3+)
  float* scr = (float*)lds_c;                       // overlay (pool epilogue)
  __shared__ int scnt[kNPG];
  __shared__ float sdinv[kNPG];
  const int yb = blockIdx.y;
  const float* X = (yb == 0) ? x0 : (yb == 1) ? x1 : x2;
  const int* srcI = (yb == 0) ? src0 : (yb == 1) ? src1 : src2;
  const int* dstI = (yb == 0) ? dst0 : (yb == 1) ? dst1 : dst2;
  const _Float16* W1 = (yb == 0) ? Wt1m : Wt1s;
  const float* bias1 = (yb == 0) ? b1m : b1s;
  const int epg = (yb == 0) ? kEPG : kESG;
  const int g = blockIdx.x, tid = threadIdx.x;
  const int base = g * kNPG;
  const size_t ebase = (size_t)g * epg;
  const int lane = tid & 63, wv = tid >> 6;
  const int l15 = lane & 15, lg = lane >> 4;

  // ---- ISSUE X loads first (7 float4/thread covers 112x128 f32 exactly)
  float4 xreg[7];
#pragma unroll
  for (int t7 = 0; t7 < 7; ++t7) {
    int i = tid + t7 * 512;                  // 0..3583 = 112*32
    int r = i >> 5, cq = (i & 31) * 4;
    int row = min(base + r, kN - 1);
    xreg[t7] = *(const float4*)&X[(size_t)row * 128 + cq];
  }

  // ---- build adjacency (deterministic integer counts) — covers X latency
  for (int i = tid; i < kCntN; i += 512) cnt32[i] = 0u;
  if (tid < kNPG) scnt[tid] = 0;
  __syncthreads();
  for (int e = tid; e < epg; e += 512) {
    int s = srcI[ebase + e] - base;
    int d = dstI[ebase + e] - base;
    atomicAdd(&scnt[d], 1);
    atomicAdd(&cnt32[d * kCntW + (s >> 2)], 1u << (8 * (s & 3)));
  }
  __syncthreads();
  if (tid < kNPG) sdinv[tid] = rsqrtf((float)scnt[tid] + 1.f);
  __syncthreads();
  if (yb == 0) {   // dump counts for enc2 reuse (cnt32 still live here)
    for (int i = tid; i < kCntN; i += 512) CNTG[(size_t)g * 3712 + i] = cnt32[i];
    if (tid < kNPG) SCG[g * 128 + tid] = scnt[tid];
  }
  for (int i = tid; i < 112 * kAhS; i += 512) {
    int d = i / kAhS, s = i - d * kAhS;
    float v = 0.f;
    if (d < 100 && s < 100) {
      unsigned w = cnt32[d * kCntW + (s >> 2)];
      unsigned c = (w >> (8 * (s & 3))) & 0xFFu;
      c += (s == d) ? 1u : 0u;
      v = (float)c * sdinv[s] * sdinv[d];
    }
    Adh[i] = (_Float16)v;
  }
  // ---- Xs write-late: data arrived during build; convert (RNE) + ds_write
#pragma unroll
  for (int t7 = 0; t7 < 7; ++t7) {
    int i = tid + t7 * 512;
    int r = i >> 5, cq = (i & 31) * 4;
    half4v hv;
    hv[0] = (_Float16)xreg[t7].x; hv[1] = (_Float16)xreg[t7].y;
    hv[2] = (_Float16)xreg[t7].z; hv[3] = (_Float16)xreg[t7].w;
    *(half4v*)&Xs[r * kAhS + cq] = hv;
  }
  __syncthreads();   // cnt dead; hT region writable; Xs ready

  // ---- stage 1: GEMM1 (7 m-tiles = 112 rows; N=256, K=128), A from LDS -> hT^T
  {
    f32x4 a1[7][2];
#pragma unroll
    for (int mt = 0; mt < 7; ++mt) {
      a1[mt][0] = (f32x4){0.f, 0.f, 0.f, 0.f};
      a1[mt][1] = (f32x4){0.f, 0.f, 0.f, 0.f};
    }
    const int bc0 = wv * 32 + l15;
#pragma unroll
    for (int ks = 0; ks < 4; ++ks) {
      const int kb = ks * 32 + lg * 8;
      half8 bF[2];
#pragma unroll
      for (int t = 0; t < 2; ++t)
        bF[t] = *(const half8*)&W1[((size_t)(ks * 4 + lg) * 256 + bc0 + t * 16) * 8];
#pragma unroll
      for (int mt = 0; mt < 7; ++mt) {
        half8 aF = *(const half8*)&Xs[(mt * 16 + l15) * kAhS + kb];
#pragma unroll
        for (int t = 0; t < 2; ++t)
          a1[mt][t] = __builtin_amdgcn_mfma_f32_16x16x32_f16(aF, bF[t], a1[mt][t], 0, 0, 0);
      }
    }
#pragma unroll
    for (int mt = 0; mt < 7; ++mt)
#pragma unroll
      for (int t = 0; t < 2; ++t)
#pragma unroll
        for (int q = 0; q < 4; ++q) {
          int col = wv * 32 + t * 16 + l15;
          int j = mt * 16 + lg * 4 + q;             // 0..111
          hT[col * kAhS + j] = (_Float16)a1[mt][t][q];
        }
    for (int i = tid; i < 256 * 16; i += 512) {      // zero-fill j 112..127
      int c = i >> 4, j = 112 + (i & 15);
      hT[c * kAhS + j] = (_Float16)0.f;
    }
  }
  __syncthreads();

  // ---- stage 2: agg256 (M=112, cols wv*32..+31) + bias + relu + stats/segBN
  {
    f32x4 a2[7][2];
#pragma unroll
    for (int mt = 0; mt < 7; ++mt) {
      a2[mt][0] = (f32x4){0.f, 0.f, 0.f, 0.f};
      a2[mt][1] = (f32x4){0.f, 0.f, 0.f, 0.f};
    }
#pragma unroll
    for (int ks = 0; ks < 4; ++ks) {
      const int kb = ks * 32 + lg * 8;
      half8 bF[2];
#pragma unroll
      for (int t = 0; t < 2; ++t)
        bF[t] = *(const half8*)&hT[(wv * 32 + t * 16 + l15) * kAhS + kb];
#pragma unroll
      for (int mt = 0; mt < 7; ++mt) {
        half8 aF = *(const half8*)&Adh[(mt * 16 + l15) * kAhS + kb];
        a2[mt][0] = __builtin_amdgcn_mfma_f32_16x16x32_f16(aF, bF[0], a2[mt][0], 0, 0, 0);
        a2[mt][1] = __builtin_amdgcn_mfma_f32_16x16x32_f16(aF, bF[1], a2[mt][1], 0, 0, 0);
      }
    }
    float bv0 = bias1[wv * 32 + l15];
    float bv1 = bias1[wv * 32 + 16 + l15];
#pragma unroll
    for (int mt = 0; mt < 7; ++mt)
#pragma unroll
      for (int q = 0; q < 4; ++q) {
        a2[mt][0][q] = fmaxf(a2[mt][0][q] + bv0, 0.f);
        a2[mt][1][q] = fmaxf(a2[mt][1][q] + bv1, 0.f);
      }
    float s0 = 0.f, s20 = 0.f, s1 = 0.f, s21 = 0.f;
#pragma unroll
    for (int mt = 0; mt < 7; ++mt)
#pragma unroll
      for (int q = 0; q < 4; ++q) {
        int row = mt * 16 + lg * 4 + q;
        if (row < 100) {
          float v0 = a2[mt][0][q], v1 = a2[mt][1][q];
          s0 += v0; s20 += v0 * v0; s1 += v1; s21 += v1 * v1;
        }
      }
    s0 += __shfl_xor(s0, 16, 64);  s0 += __shfl_xor(s0, 32, 64);
    s20 += __shfl_xor(s20, 16, 64); s20 += __shfl_xor(s20, 32, 64);
    s1 += __shfl_xor(s1, 16, 64);  s1 += __shfl_xor(s1, 32, 64);
    s21 += __shfl_xor(s21, 16, 64); s21 += __shfl_xor(s21, 32, 64);
    if (yb == 0) {
      if (lg == 0) {
        PST[(size_t)g * 512 + wv * 32 + l15] = s0;
        PST[(size_t)g * 512 + 256 + wv * 32 + l15] = s20;
        PST[(size_t)g * 512 + wv * 32 + 16 + l15] = s1;
        PST[(size_t)g * 512 + 256 + wv * 32 + 16 + l15] = s21;
      }
#pragma unroll
      for (int mt = 0; mt < 7; ++mt)
#pragma unroll
        for (int q = 0; q < 4; ++q) {
          int row = mt * 16 + lg * 4 + q;
          if (row < 100) {
            hB[(size_t)(base + row) * 256 + wv * 32 + l15] = (_Float16)a2[mt][0][q];
            hB[(size_t)(base + row) * 256 + wv * 32 + 16 + l15] = (_Float16)a2[mt][1][q];
          }
        }
    } else {
      float m0 = s0 / 100.f, r0 = rsqrtf(s20 / 100.f - m0 * m0 + BN_EPS);
      float m1 = s1 / 100.f, r1 = rsqrtf(s21 / 100.f - m1 * m1 + BN_EPS);
      __syncthreads();                 // Xs reads done (stage 1) -> h2 writable
#pragma unroll
      for (int mt = 0; mt < 7; ++mt)
#pragma unroll
        for (int q = 0; q < 4; ++q) {
          int row = mt * 16 + lg * 4 + q;
          h2[row * kH2S + wv * 32 + l15] = (_Float16)((a2[mt][0][q] - m0) * r0);
          h2[row * kH2S + wv * 32 + 16 + l15] = (_Float16)((a2[mt][1][q] - m1) * r1);
        }
    }
  }
  if (yb == 0) return;   // block-uniform exit (main phase-A done)

  __syncthreads();   // h2 complete; hT reads done -> hT2 region writable

  // ---- stage 3: GEMM2 (M=112 via wave=mt, N=128, K=256) -> hT2^T
  {
    for (int i = tid; i < 128 * 16; i += 512) {          // zero pad rows 112..127
      int c = i >> 4, j = 112 + (i & 15);
      hT2[c * kAhS + j] = (_Float16)0.f;
    }
    const int mt = wv;
    f32x4 a3[8];
#pragma unroll
    for (int nt = 0; nt < 8; ++nt) a3[nt] = (f32x4){0.f, 0.f, 0.f, 0.f};
    if (mt < 7) {
#pragma unroll
      for (int ks = 0; ks < 8; ++ks) {
        const int kb = ks * 32 + lg * 8;
        half8 aF = *(const half8*)&h2[(mt * 16 + l15) * kH2S + kb];
#pragma unroll
        for (int nt = 0; nt < 8; ++nt) {
          half8 bF = *(const half8*)&Wt2[((size_t)(ks * 4 + lg) * 128 + nt * 16 + l15) * 8];
          a3[nt] = __builtin_amdgcn_mfma_f32_16x16x32_f16(aF, bF, a3[nt], 0, 0, 0);
        }
      }
#pragma unroll
      for (int nt = 0; nt < 8; ++nt)
#pragma unroll
        for (int q = 0; q < 4; ++q) {
          int col = nt * 16 + l15;
          int j = mt * 16 + lg * 4 + q;
          hT2[col * kAhS + j] = (_Float16)a3[nt][q];
        }
    }
  }
  __syncthreads();

  // ---- stage 4: agg128 + bias + l2norm + mean-pool
  {
    const int mt = wv;
    f32x4 a4[8];
#pragma unroll
    for (int nt = 0; nt < 8; ++nt) a4[nt] = (f32x4){0.f, 0.f, 0.f, 0.f};
    if (mt < 7) {
#pragma unroll
      for (int ks = 0; ks < 4; ++ks) {
        const int kb = ks * 32 + lg * 8;
        half8 aF = *(const half8*)&Adh[(mt * 16 + l15) * kAhS + kb];
#pragma unroll
        for (int nt = 0; nt < 8; ++nt) {
          half8 bF = *(const half8*)&hT2[(nt * 16 + l15) * kAhS + kb];
          a4[nt] = __builtin_amdgcn_mfma_f32_16x16x32_f16(aF, bF, a4[nt], 0, 0, 0);
        }
      }
#pragma unroll
      for (int nt = 0; nt < 8; ++nt) {
        float bvn = b2[nt * 16 + l15];
#pragma unroll
        for (int q = 0; q < 4; ++q) a4[nt][q] += bvn;
      }
#pragma unroll
      for (int q = 0; q < 4; ++q) {
        float ss = 0.f;
#pragma unroll
        for (int nt = 0; nt < 8; ++nt) ss += a4[nt][q] * a4[nt][q];
        ss += __shfl_xor(ss, 1, 64); ss += __shfl_xor(ss, 2, 64);
        ss += __shfl_xor(ss, 4, 64); ss += __shfl_xor(ss, 8, 64);
        float inv = 1.f / fmaxf(sqrtf(ss), 1e-12f);
#pragma unroll
        for (int nt = 0; nt < 8; ++nt) a4[nt][q] *= inv;
      }
    }
    float ps[8];
#pragma unroll
    for (int nt = 0; nt < 8; ++nt) ps[nt] = 0.f;
    if (mt < 7) {
#pragma unroll
      for (int nt = 0; nt < 8; ++nt)
#pragma unroll
        for (int q = 0; q < 4; ++q) {
          int row = mt * 16 + lg * 4 + q;
          if (row < 100) ps[nt] += a4[nt][q];
        }
    }
#pragma unroll
    for (int nt = 0; nt < 8; ++nt) {
      ps[nt] += __shfl_xor(ps[nt], 16, 64);
      ps[nt] += __shfl_xor(ps[nt], 32, 64);
    }
    __syncthreads();                  // Adh dead -> scr
    if (mt < 7 && lg == 0)
#pragma unroll
      for (int nt = 0; nt < 8; ++nt) scr[wv * 128 + nt * 16 + l15] = ps[nt];
    __syncthreads();
    if (tid < 128) {
      float s = 0.f;
      for (int w2 = 0; w2 < 7; ++w2) s += scr[w2 * 128 + tid];
      float* OP = (yb == 1) ? OP1 : OP2;
      OP[(size_t)g * 128 + tid] = s / 100.f;
    }
  }
}

// ================= phase-2 fused encoder (main): hB -> BN -> GEMM2 -> agg128 =================
__global__ __launch_bounds__(512)
void enc2_k(const _Float16* __restrict__ hB, const float* __restrict__ tr,
            const _Float16* __restrict__ Wt2, const float* __restrict__ b2,
            const unsigned* __restrict__ CNTG, const int* __restrict__ SCG,
            const float* __restrict__ NOI,
            float* __restrict__ OZ, _Float16* __restrict__ Z16,
            float* __restrict__ ZG, float* __restrict__ ZZ)
{
  extern __shared__ __align__(16) char lds_c[];
  _Float16* Adh = (_Float16*)lds_c;                 // [112][136]
  _Float16* hT2 = (_Float16*)(lds_c + 30464);       // [128][136]
  unsigned* cnt32 = (unsigned*)(lds_c + 30464);     // overlay (build only)
  float* scr = (float*)lds_c;                       // overlay (epilogue)
  __shared__ float sdinv[kNPG];
  const int g = blockIdx.x, tid = threadIdx.x;
  const int base = g * kNPG;
  const int lane = tid & 63, wv = tid >> 6;
  const int l15 = lane & 15, lg = lane >> 4;

  for (int i = tid; i < kCntN; i += 512) cnt32[i] = CNTG[(size_t)g * 3712 + i];
  if (tid < kNPG) sdinv[tid] = rsqrtf((float)SCG[g * 128 + tid] + 1.f);
  __syncthreads();
  for (int i = tid; i < 112 * kAhS; i += 512) {
    int d = i / kAhS, s = i - d * kAhS;
    float v = 0.f;
    if (d < 100 && s < 100) {
      unsigned w = cnt32[d * kCntW + (s >> 2)];
      unsigned c = (w >> (8 * (s & 3))) & 0xFFu;
      c += (s == d) ? 1u : 0u;
      v = (float)c * sdinv[s] * sdinv[d];
    }
    Adh[i] = (_Float16)v;
  }
  __syncthreads();   // cnt dead -> hT2 writable

  {
    const int mt = wv;
    const int r = min(base + mt * 16 + l15, kN - 1);
    f32x4 a3[8];
#pragma unroll
    for (int nt = 0; nt < 8; ++nt) a3[nt] = (f32x4){0.f, 0.f, 0.f, 0.f};
#pragma unroll
    for (int ks = 0; ks < 8; ++ks) {
      const int kb = ks * 32 + lg * 8;
      half8 h = *(const half8*)&hB[(size_t)r * 256 + kb];
      half8 aF;
#pragma unroll
      for (int j = 0; j < 8; ++j)
        aF[j] = (_Float16)(((float)h[j] - tr[kb + j]) * tr[256 + kb + j]);
#pragma unroll
      for (int nt = 0; nt < 8; ++nt) {
        half8 bF = *(const half8*)&Wt2[((size_t)(ks * 4 + lg) * 128 + nt * 16 + l15) * 8];
        a3[nt] = __builtin_amdgcn_mfma_f32_16x16x32_f16(aF, bF, a3[nt], 0, 0, 0);
      }
    }
#pragma unroll
    for (int nt = 0; nt < 8; ++nt)
#pragma unroll
      for (int q = 0; q < 4; ++q) {
        int col = nt * 16 + l15;
        int j = mt * 16 + lg * 4 + q;
        hT2[col * kAhS + j] = (_Float16)a3[nt][q];
      }
  }
  __syncthreads();

  {
    const int mt = wv;
    f32x4 a4[8];
#pragma unroll
    for (int nt = 0; nt < 8; ++nt) a4[nt] = (f32x4){0.f, 0.f, 0.f, 0.f};
    if (mt < 7) {
#pragma unroll
      for (int ks = 0; ks < 4; ++ks) {
        const int kb = ks * 32 + lg * 8;
        half8 aF = *(const half8*)&Adh[(mt * 16 + l15) * kAhS + kb];
#pragma unroll
        for (int nt = 0; nt < 8; ++nt) {
          half8 bF = *(const half8*)&hT2[(nt * 16 + l15) * kAhS + kb];
          a4[nt] = __builtin_amdgcn_mfma_f32_16x16x32_f16(aF, bF, a4[nt], 0, 0, 0);
        }
      }
#pragma unroll
      for (int nt = 0; nt < 8; ++nt) {
        float bvn = b2[nt * 16 + l15];
#pragma unroll
        for (int q = 0; q < 4; ++q) a4[nt][q] += bvn;
      }
#pragma unroll
      for (int q = 0; q < 4; ++q) {
        float ss = 0.f;
#pragma unroll
        for (int nt = 0; nt < 8; ++nt) ss += a4[nt][q] * a4[nt][q];
        ss += __shfl_xor(ss, 1, 64); ss += __shfl_xor(ss, 2, 64);
        ss += __shfl_xor(ss, 4, 64); ss += __shfl_xor(ss, 8, 64);
        float inv = 1.f / fmaxf(sqrtf(ss), 1e-12f);
#pragma unroll
        for (int nt = 0; nt < 8; ++nt) a4[nt][q] *= inv;
      }
#pragma unroll
      for (int nt = 0; nt < 8; ++nt)
#pragma unroll
        for (int q = 0; q < 4; ++q) {
          int row = mt * 16 + lg * 4 + q;
          if (row < 100) {
            OZ[(size_t)(base + row) * 128 + nt * 16 + l15] = a4[nt][q];
            Z16[(size_t)(base + row) * 128 + nt * 16 + l15] = (_Float16)a4[nt][q];
          }
        }
    }
    float m1[8], m2[8];
#pragma unroll
    for (int nt = 0; nt < 8; ++nt) { m1[nt] = -INFINITY; m2[nt] = -INFINITY; }
    if (mt < 7) {
#pragma unroll
      for (int nt = 0; nt < 8; ++nt)
#pragma unroll
        for (int q = 0; q < 4; ++q) {
          int row = mt * 16 + lg * 4 + q;
          if (row < 100) {
            float zv = a4[nt][q];
            float nv = NOI[(size_t)(base + row) * 128 + nt * 16 + l15];
            m1[nt] = fmaxf(m1[nt], zv);
            m2[nt] = fmaxf(m2[nt], zv + nv);
          }
        }
#pragma unroll
      for (int nt = 0; nt < 8; ++nt) {
        m1[nt] = fmaxf(m1[nt], __shfl_xor(m1[nt], 16, 64));
        m1[nt] = fmaxf(m1[nt], __shfl_xor(m1[nt], 32, 64));
        m2[nt] = fmaxf(m2[nt], __shfl_xor(m2[nt], 16, 64));
        m2[nt] = fmaxf(m2[nt], __shfl_xor(m2[nt], 32, 64));
      }
    }
    __syncthreads();                  // Adh dead -> scr
    if (mt < 7 && lg == 0)
#pragma unroll
      for (int nt = 0; nt < 8; ++nt) {
        scr[wv * 128 + nt * 16 + l15] = m1[nt];
        scr[1024 + wv * 128 + nt * 16 + l15] = m2[nt];
      }
    __syncthreads();
    if (tid < 128) {
      float a = -INFINITY, b = -INFINITY;
      for (int w2 = 0; w2 < 7; ++w2) {
        a = fmaxf(a, scr[w2 * 128 + tid]);
        b = fmaxf(b, scr[1024 + w2 * 128 + tid]);
      }
      ZG[(size_t)g * 128 + tid] = a;
      ZZ[(size_t)g * 128 + tid] = a;
      ZZ[(size_t)(500 + g) * 128 + tid] = b;
    }
  }
}

// ================= fused decoder: o_xr = sigmoid(relu(z16@W1)@W2) =================
__global__ __launch_bounds__(512)
void dec_fused_k(const _Float16* __restrict__ Z, const _Float16* __restrict__ Wt1,
                 const _Float16* __restrict__ Wt2, float* __restrict__ XR, int M)
{
  __shared__ alignas(16) _Float16 Hrm[64][264];
  const int tid = threadIdx.x;
  const int lane = tid & 63;
  const int l15 = lane & 15, lg = lane >> 4;
  const int wave = tid >> 6;
  const int wm = wave >> 2;
  const int wn = wave & 3;
  const int bm = blockIdx.x * 64;

  f32x4 acc[2][4];
#pragma unroll
  for (int m = 0; m < 2; ++m)
#pragma unroll
    for (int n = 0; n < 4; ++n) acc[m][n] = (f32x4){0.f, 0.f, 0.f, 0.f};
  int arow[2];
#pragma unroll
  for (int m = 0; m < 2; ++m)
    arow[m] = min(bm + wm * 32 + m * 16 + l15, M - 1);
  const int bcol = wn * 64 + l15;
#pragma unroll
  for (int ks = 0; ks < 4; ++ks) {
    const int kb = ks * 32 + lg * 8;
    half8 bF[4];
#pragma unroll
    for (int n = 0; n < 4; ++n)
      bF[n] = *(const half8*)&Wt1[((size_t)(ks * 4 + lg) * 256 + bcol + n * 16) * 8];
    half8 aF[2];
#pragma unroll
    for (int m = 0; m < 2; ++m)
      aF[m] = *(const half8*)&Z[(size_t)arow[m] * 128 + kb];
#pragma unroll
    for (int m = 0; m < 2; ++m)
#pragma unroll
      for (int n = 0; n < 4; ++n)
        acc[m][n] = __builtin_amdgcn_mfma_f32_16x16x32_f16(aF[m], bF[n], acc[m][n], 0, 0, 0);
  }
#pragma unroll
  for (int m = 0; m < 2; ++m)
#pragma unroll
    for (int q = 0; q < 4; ++q) {
      int lrow = wm * 32 + m * 16 + lg * 4 + q;
#pragma unroll
      for (int n = 0; n < 4; ++n)
        Hrm[lrow][wn * 64 + n * 16 + l15] = (_Float16)fmaxf(acc[m][n][q], 0.f);
    }
  __syncthreads();

  const int wm2 = wave & 1, wn2 = wave >> 1;
  f32x4 acc2[2][2];
#pragma unroll
  for (int m = 0; m < 2; ++m)
#pragma unroll
    for (int n = 0; n < 2; ++n) acc2[m][n] = (f32x4){0.f, 0.f, 0.f, 0.f};
#pragma unroll
  for (int ks = 0; ks < 8; ++ks) {
    const int kb = ks * 32 + lg * 8;
    half8 aF[2];
#pragma unroll
    for (int m = 0; m < 2; ++m)
      aF[m] = *(const half8*)&Hrm[wm2 * 32 + m * 16 + l15][kb];
    half8 bF[2];
#pragma unroll
    for (int n = 0; n < 2; ++n)
      bF[n] = *(const half8*)&Wt2[((size_t)(ks * 4 + lg) * 128 + wn2 * 32 + n * 16 + l15) * 8];
#pragma unroll
    for (int m = 0; m < 2; ++m)
#pragma unroll
      for (int n = 0; n < 2; ++n)
        acc2[m][n] = __builtin_amdgcn_mfma_f32_16x16x32_f16(aF[m], bF[n], acc2[m][n], 0, 0, 0);
  }
#pragma unroll
  for (int m = 0; m < 2; ++m)
#pragma unroll
    for (int q = 0; q < 4; ++q) {
      int row = bm + wm2 * 32 + m * 16 + lg * 4 + q;
      if (row >= M) continue;
#pragma unroll
      for (int n = 0; n < 2; ++n) {
        float v = acc2[m][n][q];
        XR[(size_t)row * 128 + wn2 * 32 + n * 16 + l15] = 1.f / (1.f + expf(-v));
      }
    }
}

// ======================= small-M tiled f32 GEMM (M<=1000 paths) =======================
template<int ACT>
__global__ __launch_bounds__(256)
void gemm_k(const float* __restrict__ A, const float* __restrict__ W,
            const float* __restrict__ bias, float* __restrict__ C,
            int M, int K, int Nc)
{
  __shared__ float As[32][136];
  __shared__ float Ws[32][68];
  const int tid = threadIdx.x;
  const int bm = blockIdx.x * 128;
  const int bn = blockIdx.y * 64;
  const int tm = (tid & 15) * 8;
  const int tn = (tid >> 4) * 4;
  float acc[8][4];
#pragma unroll
  for (int i = 0; i < 8; ++i)
#pragma unroll
    for (int j = 0; j < 4; ++j) acc[i][j] = 0.f;

  for (int k0 = 0; k0 < K; k0 += 32) {
#pragma unroll
    for (int l = 0; l < 4; ++l) {
      int idx = tid + l * 256;
      int r = idx >> 3;
      int kq = (idx & 7) << 2;
      int gr = bm + r;
      float4 v = make_float4(0.f, 0.f, 0.f, 0.f);
      if (gr < M) v = *(const float4*)&A[(size_t)gr * K + k0 + kq];
      As[kq + 0][r] = v.x; As[kq + 1][r] = v.y;
      As[kq + 2][r] = v.z; As[kq + 3][r] = v.w;
    }
#pragma unroll
    for (int l = 0; l < 2; ++l) {
      int idx = tid + l * 256;
      int r = idx >> 4;
      int nq = (idx & 15) << 2;
      *(float4*)&Ws[r][nq] = *(const float4*)&W[(size_t)(k0 + r) * Nc + bn + nq];
    }
    __syncthreads();
#pragma unroll
    for (int kk = 0; kk < 32; ++kk) {
      float4 a0 = *(float4*)&As[kk][tm];
      float4 a1 = *(float4*)&As[kk][tm + 4];
      float4 w4 = *(float4*)&Ws[kk][tn];
      float am[8] = {a0.x, a0.y, a0.z, a0.w, a1.x, a1.y, a1.z, a1.w};
      float wn4[4] = {w4.x, w4.y, w4.z, w4.w};
#pragma unroll
      for (int i = 0; i < 8; ++i)
#pragma unroll
        for (int j = 0; j < 4; ++j) acc[i][j] += am[i] * wn4[j];
    }
    __syncthreads();
  }
  float4 bv = make_float4(0.f, 0.f, 0.f, 0.f);
  if (bias) bv = *(const float4*)&bias[bn + tn];
#pragma unroll
  for (int i = 0; i < 8; ++i) {
    int row = bm + tm + i;
    if (row >= M) break;
    float o0 = acc[i][0] + bv.x, o1 = acc[i][1] + bv.y;
    float o2 = acc[i][2] + bv.z, o3 = acc[i][3] + bv.w;
    if (ACT == 1) {
      o0 = fmaxf(o0, 0.f); o1 = fmaxf(o1, 0.f);
      o2 = fmaxf(o2, 0.f); o3 = fmaxf(o3, 0.f);
    } else if (ACT == 2) {
      o0 = 1.f / (1.f + expf(-o0)); o1 = 1.f / (1.f + expf(-o1));
      o2 = 1.f / (1.f + expf(-o2)); o3 = 1.f / (1.f + expf(-o3));
    }
    *(float4*)&C[(size_t)row * Nc + bn + tn] = make_float4(o0, o1, o2, o3);
  }
}

// ============ BN finalize: 4-way parallel fixed-order sum of 500 partials ============
__global__ __launch_bounds__(1024)
void bn_red_k(const float* __restrict__ P, float* __restrict__ stats)
{
  __shared__ float ls[4][512];
  const int col = threadIdx.x & 255;
  const int part = threadIdx.x >> 8;      // 0..3, 125 graphs each
  float s = 0.f, s2 = 0.f;
  for (int b = part * 125; b < part * 125 + 125; ++b) {
    s  += P[(size_t)b * 512 + col];
    s2 += P[(size_t)b * 512 + 256 + col];
  }
  ls[part][col] = s;
  ls[part][256 + col] = s2;
  __syncthreads();
  if (part == 0) {
    float S  = ls[0][col] + ls[1][col] + ls[2][col] + ls[3][col];
    float S2 = ls[0][256 + col] + ls[1][256 + col] + ls[2][256 + col] + ls[3][256 + col];
    float m = S / (float)kN;
    float v = S2 / (float)kN - m * m;
    stats[512 + col] = m;
    stats[768 + col] = rsqrtf(v + BN_EPS);
  }
}

__global__ __launch_bounds__(64)
void bn_cols_k(float* __restrict__ X, int rows, int cols)
{
  const int c = blockIdx.x, t = threadIdx.x;
  float s = 0.f, s2 = 0.f;
  for (int r = t; r < rows; r += 64) {
    float v = X[(size_t)r * cols + c];
    s += v; s2 += v * v;
  }
#pragma unroll
  for (int o = 32; o; o >>= 1) { s += __shfl_xor(s, o, 64); s2 += __shfl_xor(s2, o, 64); }
  float m = s / (float)rows;
  float var = s2 / (float)rows - m * m;
  float rinv = rsqrtf(var + BN_EPS);
  for (int r = t; r < rows; r += 64)
    X[(size_t)r * cols + c] = (X[(size_t)r * cols + c] - m) * rinv;
}

__global__ __launch_bounds__(256)
void l2n_k(const float* __restrict__ X, float* __restrict__ Y, int rows)
{
  const int w = threadIdx.x >> 6, lane = threadIdx.x & 63;
  const int row = blockIdx.x * 4 + w;
  if (row >= rows) return;
  float2 v = *(const float2*)&X[(size_t)row * kH2 + lane * 2];
  float ss = v.x * v.x + v.y * v.y;
#pragma unroll
  for (int o = 32; o; o >>= 1) ss += __shfl_xor(ss, o, 64);
  float inv = 1.f / fmaxf(sqrtf(ss), 1e-12f);
  *(float2*)&Y[(size_t)row * kH2 + lane * 2] = make_float2(v.x * inv, v.y * inv);
}

// =========================================================================
extern "C" void kernel_launch(void* const* d_in, const int* in_sizes, int n_in,
                              void* d_out, int out_size, void* d_ws, size_t ws_size,
                              hipStream_t stream)
{
  const float* x        = (const float*)d_in[0];
  const int*   srcI     = (const int*)d_in[1];
  const int*   dstI     = (const int*)d_in[2];
  const float* pos_x    = (const float*)d_in[4];
  const int*   psrc     = (const int*)d_in[5];
  const int*   pdst     = (const int*)d_in[6];
  const float* neg_x    = (const float*)d_in[8];
  const int*   nsrc     = (const int*)d_in[9];
  const int*   ndst     = (const int*)d_in[10];
  const float* target_x = (const float*)d_in[12];
  const float* noise    = (const float*)d_in[13];
  const float* W_enc1   = (const float*)d_in[14];
  const float* b_enc1   = (const float*)d_in[15];
  const float* W_enc2   = (const float*)d_in[16];
  const float* b_enc2   = (const float*)d_in[17];
  const float* W_dec1   = (const float*)d_in[18];
  const float* W_dec2   = (const float*)d_in[19];
  const float* Wn1      = (const float*)d_in[20];
  const float* bn1      = (const float*)d_in[21];
  const float* Wn2      = (const float*)d_in[22];
  const float* bn2      = (const float*)d_in[23];
  const float* Ws1      = (const float*)d_in[24];
  const float* bs1      = (const float*)d_in[25];
  const float* Wp1      = (const float*)d_in[26];
  const float* bp1      = (const float*)d_in[27];
  const float* Wp2      = (const float*)d_in[28];
  const float* bp2      = (const float*)d_in[29];

  float* out  = (float*)d_out;
  float* o_z   = out;                 // N x 128
  float* o_zg  = out + 6400000;       // 500 x 128
  float* o_xr  = out + 6464000;       // N x 128
  float* o_pos = out + 12864000;      // 500 x 128
  float* o_neg = out + 12928000;
  float* o_zgm = out + 12992000;      // o_zgm||o_zpm contiguous 1000 x 128
  float* o_tz  = out + 13120000;

  // WORKSPACE MAP — r26 layout (audited).
  float* ws = (float*)d_ws;
  _Float16* hB  = (_Float16*)ws;
  float* pstat  = ws + 6400000;
  _Float16* z16 = (_Float16*)(ws + 19200000);
  float* zz    = ws + 22400000;
  float* t1000 = ws + 22520000;
  unsigned* CNTG = (unsigned*)(ws + 22700000);   // 1.856M u32
  int* SCG = (int*)(ws + 24600000);              // 64000 int
  float* t1    = ws + 6400000;        // target-time (pstat dead)
  float* t2    = ws + 6700000;
  _Float16* hWt = (_Float16*)(ws + 25600000);
  float* stats = ws + 25700000;
  if (ws_size < (size_t)(25921024) * sizeof(float)) return;

  _Float16* WtEnc1 = hWt;
  _Float16* WtEnc2 = hWt + 32768;
  _Float16* WtDec1 = hWt + 65536;
  _Float16* WtDec2 = hWt + 98304;
  _Float16* WtS1   = hWt + 131072;

  (void)hipFuncSetAttribute((const void*)enc1_k,
      hipFuncAttributeMaxDynamicSharedMemorySize, kLds1);
  (void)hipFuncSetAttribute((const void*)enc2_k,
      hipFuncAttributeMaxDynamicSharedMemorySize, kLds2);

  auto gg = [](int M, int Nc) {
    return dim3((unsigned)((M + 127) / 128), (unsigned)(Nc / 64), 1);
  };

  // 1. weight prep only (x conversion folded into enc1 staging)
  prep_k<<<640, 256, 0, stream>>>(W_enc1, W_enc2, W_dec1, W_dec2, Ws1, hWt);

  // 2. phase-1 fused encoder (X loads issued first, written to LDS late)
  enc1_k<<<dim3(kB, 3), 512, kLds1, stream>>>(
      x, pos_x, neg_x, srcI, psrc, nsrc, dstI, pdst, ndst,
      WtEnc1, WtS1, WtEnc2, b_enc1, bs1, b_enc2,
      hB, pstat, o_pos, o_neg, CNTG, SCG);

  // 3. BN finalize (4-way parallel)
  bn_red_k<<<1, 1024, 0, stream>>>(pstat, stats);

  // 4. phase-2 fused encoder (main)
  enc2_k<<<kB, 512, kLds2, stream>>>(
      hB, stats + 512, WtEnc2, b_enc2, CNTG, SCG, noise, o_z, z16, o_zg, zz);

  // 5. fused decoder
  dec_fused_k<<<782, 512, 0, stream>>>(z16, WtDec1, WtDec2, o_xr, kN);

  // 6-7. merged projection heads
  gemm_k<1><<<gg(1000, kH2), 256, 0, stream>>>(zz, Wp1, bp1, t1000, 1000, kH2, kH2);
  gemm_k<0><<<gg(1000, kH2), 256, 0, stream>>>(t1000, Wp2, bp2, o_zgm, 1000, kH2, kH2);

  // 8-11. target node encoder
  gemm_k<1><<<gg(kB, kH1), 256, 0, stream>>>(target_x, Wn1, bn1, t1, kB, kF0, kH1);
  bn_cols_k<<<256, 64, 0, stream>>>(t1, kB, kH1);
  gemm_k<0><<<gg(kB, kH2), 256, 0, stream>>>(t1, Wn2, bn2, t2, kB, kH1, kH2);
  l2n_k<<<125, 256, 0, stream>>>(t2, o_tz, kB);

  (void)in_sizes; (void)n_in; (void)out_size;
}